// Round 1
// 532.175 us; speedup vs baseline: 1.0746x; 1.0746x over previous
//
#include <hip/hip_runtime.h>
#include <stdint.h>
#include <math.h>

typedef unsigned short u16;
typedef __attribute__((ext_vector_type(8))) short short8;
typedef __attribute__((ext_vector_type(4))) float fx4;
typedef __attribute__((ext_vector_type(4))) unsigned short u16x4;

#define DEV __device__ __forceinline__

DEV u16 f2bf(float f) {
  unsigned u = __builtin_bit_cast(unsigned, f);
  return (u16)((u + 0x7FFFu + ((u >> 16) & 1u)) >> 16);
}
DEV float bf2f(u16 h) { return __builtin_bit_cast(float, ((unsigned)h) << 16); }

DEV fx4 mfma16(short8 a, short8 b, fx4 c) {
  return __builtin_amdgcn_mfma_f32_16x16x32_bf16(a, b, c, 0, 0, 0);
}

#if __has_builtin(__builtin_amdgcn_exp2f)
DEV float exp2v(float x) { return __builtin_amdgcn_exp2f(x); }
#else
DEV float exp2v(float x) { return exp2f(x); }
#endif

// async global->LDS, 16B per lane. LDS dst = wave-uniform base + lane*16.
#define GLD16(g, l)                                                            \
  __builtin_amdgcn_global_load_lds(                                            \
      (const __attribute__((address_space(1))) void*)(g),                      \
      (__attribute__((address_space(3))) void*)(l), 16, 0, 0)

#define WAIT_ALL() asm volatile("s_waitcnt vmcnt(0) lgkmcnt(0)" ::: "memory")

// ---------------------------------------------------------------------------
// 1) mod = silu(temb) @ w_mod + b_mod   (2x2048 @ 2048x6144)
__global__ __launch_bounds__(512) void k_silu_mod(
    const float* __restrict__ temb, const float* __restrict__ wmod,
    const float* __restrict__ bmod, float* __restrict__ mod) {
  __shared__ float st[4096];
  __shared__ float red[8][2][64];
  int tid = threadIdx.x;
  for (int i = tid; i < 4096; i += 512) {
    float t = temb[i];
    st[i] = t / (1.0f + __expf(-t));
  }
  __syncthreads();
  int j = blockIdx.x * 64 + (tid & 63);
  int ks = tid >> 6;
  float a0 = 0.f, a1 = 0.f;
  for (int d = ks * 256; d < ks * 256 + 256; ++d) {
    float w = wmod[(size_t)d * 6144 + j];
    a0 += st[d] * w;
    a1 += st[2048 + d] * w;
  }
  red[ks][0][tid & 63] = a0;
  red[ks][1][tid & 63] = a1;
  __syncthreads();
  if (tid < 64) {
    float s0 = 0.f, s1 = 0.f;
#pragma unroll
    for (int i = 0; i < 8; ++i) {
      s0 += red[i][0][tid];
      s1 += red[i][1][tid];
    }
    mod[j] = s0 + bmod[j];
    mod[6144 + j] = s1 + bmod[j];
  }
}

// ---------------------------------------------------------------------------
// 2) xm = bf16( rmsnorm(hidden)*w_ln * (1+scale[b]) + shift[b] )
__global__ __launch_bounds__(256) void k_xm(
    const float* __restrict__ x, const float* __restrict__ wln,
    const float* __restrict__ mod, u16* __restrict__ xm) {
  int row = blockIdx.x;
  int b = row >> 11;
  const float* xr = x + (size_t)row * 2048;
  int tid = threadIdx.x;
  float4 v0 = ((const float4*)xr)[tid];
  float4 v1 = ((const float4*)xr)[tid + 256];
  float ss = v0.x * v0.x + v0.y * v0.y + v0.z * v0.z + v0.w * v0.w +
             v1.x * v1.x + v1.y * v1.y + v1.z * v1.z + v1.w * v1.w;
  for (int m = 1; m < 64; m <<= 1) ss += __shfl_xor(ss, m);
  __shared__ float red[4];
  if ((tid & 63) == 0) red[tid >> 6] = ss;
  __syncthreads();
  ss = red[0] + red[1] + red[2] + red[3];
  float r = rsqrtf(ss * (1.0f / 2048.0f) + 1e-5f);
  const float* mb = mod + (size_t)b * 6144;
#pragma unroll
  for (int c = 0; c < 2; ++c) {
    int j0 = (tid + c * 256) * 4;
    float4 xv = c ? v1 : v0;
    float4 sh = *(const float4*)(mb + j0);
    float4 sc = *(const float4*)(mb + 2048 + j0);
    float4 wl = *(const float4*)(wln + j0);
    u16x4 o;
    o.x = f2bf(xv.x * r * wl.x * (1.f + sc.x) + sh.x);
    o.y = f2bf(xv.y * r * wl.y * (1.f + sc.y) + sh.y);
    o.z = f2bf(xv.z * r * wl.z * (1.f + sc.z) + sh.z);
    o.w = f2bf(xv.w * r * wl.w * (1.f + sc.w) + sh.w);
    *(u16x4*)(xm + (size_t)row * 2048 + j0) = o;
  }
}

// ---------------------------------------------------------------------------
// 3) transpose-convert fp32 [K][cols] -> bf16 dst[n][K]
__global__ __launch_bounds__(256) void k_tconv(
    const float* __restrict__ src, u16* __restrict__ dst, int cols, int rows) {
  __shared__ float t[32][33];
  int kb = blockIdx.x * 32, nb = blockIdx.y * 32;
  int tx = threadIdx.x, ty = threadIdx.y;
#pragma unroll
  for (int i = 0; i < 4; ++i)
    t[ty + i * 8][tx] = src[(size_t)(kb + ty + i * 8) * cols + nb + tx];
  __syncthreads();
#pragma unroll
  for (int i = 0; i < 4; ++i)
    dst[(size_t)(nb + ty + i * 8) * rows + kb + tx] = f2bf(t[tx][ty + i * 8]);
}

// ---------------------------------------------------------------------------
// 4) GEMM with XOR-swizzled LDS (slot = chunk ^ ((row>>1)&3); 2-way = free)
template <int EPI>
__global__ __launch_bounds__(256) void k_gemm(
    const u16* __restrict__ A, const u16* __restrict__ Bt, void* __restrict__ Cp,
    const float* __restrict__ hid, const float* __restrict__ mod, int N, int K) {
  __shared__ u16 As[128 * 32];
  __shared__ u16 Bs[128 * 32];
  int tid = threadIdx.x;
  int wave = tid >> 6, lane = tid & 63, quad = lane >> 4, l16 = lane & 15;
  int m0 = blockIdx.y * 128, n0 = blockIdx.x * 128;
  int wm = (wave >> 1) * 64, wn = (wave & 1) * 64;
  fx4 acc[4][4] = {};
  int rowa = tid >> 2;
  int chunk = (tid & 3) ^ ((rowa >> 1) & 3);  // swizzled source chunk
  int cola = chunk * 8;
  const u16* Ag = A + (size_t)(m0 + rowa) * K + cola;
  const u16* Bg = Bt + (size_t)(n0 + rowa) * K + cola;
  u16* AsW = &As[wave * 512];
  u16* BsW = &Bs[wave * 512];
  int sl = (quad ^ ((l16 >> 1) & 3)) * 8;  // swizzled read slot (bytes/2)
  for (int k0 = 0; k0 < K; k0 += 32) {
    GLD16(Ag + k0, AsW);
    GLD16(Ag + k0 + (size_t)64 * K, AsW + 2048);
    GLD16(Bg + k0, BsW);
    GLD16(Bg + k0 + (size_t)64 * K, BsW + 2048);
    __syncthreads();
    short8 af[4], bfr[4];
#pragma unroll
    for (int i = 0; i < 4; ++i) {
      af[i] = *(const short8*)&As[(wm + i * 16 + l16) * 32 + sl];
      bfr[i] = *(const short8*)&Bs[(wn + i * 16 + l16) * 32 + sl];
    }
#pragma unroll
    for (int i = 0; i < 4; ++i)
#pragma unroll
      for (int j = 0; j < 4; ++j) acc[i][j] = mfma16(af[i], bfr[j], acc[i][j]);
    __syncthreads();
  }
#pragma unroll
  for (int i = 0; i < 4; ++i) {
    int row = m0 + wm + i * 16 + quad * 4;
#pragma unroll
    for (int j = 0; j < 4; ++j) {
      int col = n0 + wn + j * 16 + l16;
      if (EPI == 0) {
        u16* C = (u16*)Cp;
#pragma unroll
        for (int r = 0; r < 4; ++r)
          C[(size_t)(row + r) * N + col] = f2bf(acc[i][j][r]);
      } else {
        float* C = (float*)Cp;
        int b = row >> 11;
        float g = mod[(size_t)b * 6144 + 4096 + col];
#pragma unroll
        for (int r = 0; r < 4; ++r)
          C[(size_t)(row + r) * N + col] =
              hid[(size_t)(row + r) * N + col] + g * acc[i][j][r];
      }
    }
  }
}

// ---------------------------------------------------------------------------
// 5) QK rms-norm + mixed RoPE. Q pre-scaled by log2(e)/sqrt(Dh) so the
// attention softmax can run entirely in exp2 domain (bare v_exp_f32).
__global__ __launch_bounds__(192) void k_qknorm(
    const u16* __restrict__ qkv, const float* __restrict__ qn,
    const float* __restrict__ kn, const float* __restrict__ cos1,
    const float* __restrict__ sin1, const float* __restrict__ r3,
    const int* __restrict__ mpos, u16* __restrict__ Q, u16* __restrict__ Kb) {
  int bx = blockIdx.x;
  int b = bx >> 11, l = bx & 2047;
  int tid = threadIdx.x;
  int slot = tid >> 3, sub = tid & 7;
  bool isq = slot < 16;
  int head = isq ? slot : slot - 16;
  const u16* base = qkv + (size_t)bx * 4096 + (isq ? slot * 128 : 2048 + head * 128);
  int d0 = sub * 16;
  float xv[16];
#pragma unroll
  for (int i = 0; i < 16; ++i) xv[i] = bf2f(base[d0 + i]);
  float ss = 0.f;
#pragma unroll
  for (int i = 0; i < 16; ++i) ss += xv[i] * xv[i];
  ss += __shfl_xor(ss, 1);
  ss += __shfl_xor(ss, 2);
  ss += __shfl_xor(ss, 4);
  float r = rsqrtf(ss * (1.0f / 128.0f) + 1e-5f);
  int mp[8];
  {
    bool is64 = (mpos[1] == 0) & (mpos[3] == 0) & (mpos[5] == 0) & (mpos[7] == 0);
#pragma unroll
    for (int i = 0; i < 8; ++i) mp[i] = is64 ? mpos[2 * i] : mpos[i];
  }
  bool infull = false, inimg = false;
  int rel = 0;
#pragma unroll
  for (int s = 0; s < 2; ++s) {
    int off = mp[b * 4 + s * 2], ln = mp[b * 4 + s * 2 + 1];
    int mx = ln > 1 ? ln : 1;
    infull |= (l >= off) && (l < off + mx);
    bool ii = (l >= off + 1) && (l < off + ln);
    inimg |= ii;
    rel += ii ? (l - (off + 1)) : 0;
  }
  bool text = !infull;
  bool img = inimg && (rel < 1024);
  const float* w = isq ? qn : kn;
  float out[16];
  if (text) {
    int dp0 = d0 ^ 64;
    float sgn = (d0 < 64) ? -1.f : 1.f;
#pragma unroll
    for (int i = 0; i < 16; ++i) {
      int d = d0 + i, dp = dp0 + i;
      float c = cos1[(size_t)l * 128 + d];
      float s = sin1[(size_t)l * 128 + d];
      float xp = bf2f(base[dp]);
      out[i] = r * (xv[i] * w[d] * c + sgn * xp * w[dp] * s);
    }
  } else if (img) {
    const float* R = r3 + ((size_t)rel * 64 + (d0 >> 1)) * 4;
#pragma unroll
    for (int p = 0; p < 8; ++p) {
      float a = xv[2 * p] * w[d0 + 2 * p] * r;
      float c2 = xv[2 * p + 1] * w[d0 + 2 * p + 1] * r;
      out[2 * p] = a * R[4 * p + 0] + c2 * R[4 * p + 2];
      out[2 * p + 1] = a * R[4 * p + 1] + c2 * R[4 * p + 3];
    }
  } else {
#pragma unroll
    for (int i = 0; i < 16; ++i) out[i] = xv[i] * w[d0 + i] * r;
  }
  if (isq) {
    u16* dst = Q + ((size_t)(b * 16 + head) * 2048 + l) * 128 + d0;
#pragma unroll
    for (int i = 0; i < 16; ++i)
      dst[i] = f2bf(out[i] * (0.08838834764831845f * 1.4426950408889634f));
  } else {
    u16* dst = Kb + ((size_t)(b * 8 + head) * 2048 + l) * 128 + d0;
#pragma unroll
    for (int i = 0; i < 16; ++i) dst[i] = f2bf(out[i]);
  }
}

// ---------------------------------------------------------------------------
// 6) V^T: qkv[:, 3072+...] -> VT (B,KVH,Dh,L)
__global__ __launch_bounds__(256) void k_vtrans(const u16* __restrict__ qkv,
                                                u16* __restrict__ VT) {
  __shared__ u16 t[64][65];
  int bh = blockIdx.x;
  int l0 = blockIdx.y * 64, d0 = blockIdx.z * 64;
  int b = bh >> 3, kvh = bh & 7;
  int tx = threadIdx.x & 63, tg = threadIdx.x >> 6;
#pragma unroll
  for (int i = 0; i < 16; ++i) {
    int li = tg + i * 4;
    t[li][tx] = qkv[(size_t)(b * 2048 + l0 + li) * 4096 + 3072 + kvh * 128 + d0 + tx];
  }
  __syncthreads();
#pragma unroll
  for (int i = 0; i < 16; ++i) {
    int di = tg + i * 4;
    VT[((size_t)bh * 128 + d0 + di) * 2048 + l0 + tx] = t[tx][di];
  }
}

// ---------------------------------------------------------------------------
// 7) flash attention v2, depth-1 pipelined (T3 minimal 2-phase):
//   grid (L/128, B*H), 512 threads (8 waves x 16 q-rows), BQ=128, BKV=64.
//   Double-buffered K/V staging via global_load_lds; ONE raw s_barrier +
//   vmcnt(0) per KV tile, placed AFTER compute so HBM latency hides under
//   the MFMA+softmax of the current tile. exp2-domain softmax (Q carries
//   log2e), T13 defer-max gate, T5 setprio around MFMA clusters.
//   LDS = 2*16K (Ks) + 2*16K (Vs) + 16K (Ps) = 80 KB -> 2 blocks/CU.
__global__ __launch_bounds__(512, 4) void k_attn(
    const u16* __restrict__ Q, const u16* __restrict__ Kb,
    const u16* __restrict__ VT, u16* __restrict__ O) {
  __shared__ u16 Ks[2][64 * 128];  // kv x dh, swizzled
  __shared__ u16 Vs[2][128 * 64];  // dh x kv, swizzled
  __shared__ u16 Ps[128 * 64];     // q x kv, swizzled (wave-private stripes)
  int tid = threadIdx.x;
  int wave = tid >> 6, lane = tid & 63, quad = lane >> 4, l16 = lane & 15;
  int bh = blockIdx.y;
  int b = bh >> 4, h = bh & 15, kvh = h >> 1;
  int q0 = blockIdx.x * 128;
  const u16* Qb = Q + ((size_t)bh * 2048 + q0 + wave * 16) * 128;
  short8 qf[4];
#pragma unroll
  for (int ks = 0; ks < 4; ++ks)
    qf[ks] = *(const short8*)(Qb + l16 * 128 + ks * 32 + quad * 8);
  const u16* Kg = Kb + (size_t)(b * 8 + kvh) * 2048 * 128;
  const u16* Vg = VT + (size_t)(b * 8 + kvh) * 128 * 2048;
  float mrow[4], lrow[4];
  fx4 of[8] = {};
#pragma unroll
  for (int r = 0; r < 4; ++r) {
    mrow[r] = -INFINITY;
    lrow[r] = 0.f;
  }
  // staging offsets (swizzled global source; LDS dst stays linear)
  size_t kgo[2], vgo[2];
#pragma unroll
  for (int i = 0; i < 2; ++i) {
    int kr = i * 32 + wave * 4 + (lane >> 4);  // local kv row
    kgo[i] = (size_t)kr * 128 + (((lane & 15) ^ (kr & 15)) * 8);
    int vr = i * 64 + wave * 8 + (lane >> 3);  // dh row
    vgo[i] = (size_t)vr * 2048 + (((lane & 7) ^ (vr & 7)) * 8);
  }

  auto STAGE = [&](int t, int buf) {
    size_t ko = (size_t)t * 8192;  // t*64 rows * 128
    size_t vo = (size_t)t * 64;    // t*64 cols
#pragma unroll
    for (int i = 0; i < 2; ++i) {
      GLD16(Kg + ko + kgo[i], &Ks[buf][i * 4096 + wave * 512]);
      GLD16(Vg + vo + vgo[i], &Vs[buf][i * 4096 + wave * 512]);
    }
  };

  auto COMPUTE = [&](int buf) {
    fx4 sf[4] = {};
    __builtin_amdgcn_s_setprio(1);
#pragma unroll
    for (int ct = 0; ct < 4; ++ct) {
#pragma unroll
      for (int ks = 0; ks < 4; ++ks) {
        short8 kf = *(const short8*)&Ks[buf][(ct * 16 + l16) * 128 +
                                            (((ks * 4 + quad) ^ l16) * 8)];
        sf[ct] = mfma16(qf[ks], kf, sf[ct]);
      }
    }
    __builtin_amdgcn_s_setprio(0);
    float cmv[4];
#pragma unroll
    for (int r = 0; r < 4; ++r) {
      float cm = fmaxf(fmaxf(sf[0][r], sf[1][r]), fmaxf(sf[2][r], sf[3][r]));
      cm = fmaxf(cm, __shfl_xor(cm, 1));
      cm = fmaxf(cm, __shfl_xor(cm, 2));
      cm = fmaxf(cm, __shfl_xor(cm, 4));
      cm = fmaxf(cm, __shfl_xor(cm, 8));
      cmv[r] = cm;
    }
    bool need = false;
#pragma unroll
    for (int r = 0; r < 4; ++r) need |= (cmv[r] > mrow[r] + 8.0f);
    if (__any(need)) {  // T13: skip rescale while max growth <= 8 (log2)
#pragma unroll
      for (int r = 0; r < 4; ++r) {
        float mn = fmaxf(mrow[r], cmv[r]);
        float al = exp2v(mrow[r] - mn);
        mrow[r] = mn;
        lrow[r] *= al;
#pragma unroll
        for (int c2 = 0; c2 < 8; ++c2) of[c2][r] *= al;
      }
    }
    int hb = l16 >> 3;
#pragma unroll
    for (int r = 0; r < 4; ++r) {
      float p0 = exp2v(sf[0][r] - mrow[r]);
      float p1 = exp2v(sf[1][r] - mrow[r]);
      float p2 = exp2v(sf[2][r] - mrow[r]);
      float p3 = exp2v(sf[3][r] - mrow[r]);
      float rs = (p0 + p1) + (p2 + p3);
      rs += __shfl_xor(rs, 1);
      rs += __shfl_xor(rs, 2);
      rs += __shfl_xor(rs, 4);
      rs += __shfl_xor(rs, 8);
      lrow[r] += rs;
      int prow = wave * 16 + quad * 4 + r;
      int pb = prow * 64, px = prow & 7, lo = l16 & 7;
      Ps[pb + ((0 + hb) ^ px) * 8 + lo] = f2bf(p0);
      Ps[pb + ((2 + hb) ^ px) * 8 + lo] = f2bf(p1);
      Ps[pb + ((4 + hb) ^ px) * 8 + lo] = f2bf(p2);
      Ps[pb + ((6 + hb) ^ px) * 8 + lo] = f2bf(p3);
    }
    __builtin_amdgcn_s_setprio(1);
#pragma unroll
    for (int ks2 = 0; ks2 < 2; ++ks2) {
      int rsl = (((ks2 * 4 + quad) ^ (l16 & 7)) * 8);
      short8 pa = *(const short8*)&Ps[(wave * 16 + l16) * 64 + rsl];
#pragma unroll
      for (int c2 = 0; c2 < 8; ++c2) {
        short8 vb = *(const short8*)&Vs[buf][(c2 * 16 + l16) * 64 + rsl];
        of[c2] = mfma16(pa, vb, of[c2]);
      }
    }
    __builtin_amdgcn_s_setprio(0);
  };

  STAGE(0, 0);
  WAIT_ALL();
  __builtin_amdgcn_s_barrier();
  int cur = 0;
  for (int t = 0; t < 31; ++t) {
    STAGE(t + 1, cur ^ 1);  // prefetch next tile; latency hides under compute
    COMPUTE(cur);
    WAIT_ALL();             // single drain per tile, AFTER compute
    __builtin_amdgcn_s_barrier();
    cur ^= 1;
  }
  COMPUTE(cur);

#pragma unroll
  for (int r = 0; r < 4; ++r) {
    float inv = 1.0f / lrow[r];
    int qrow = q0 + wave * 16 + quad * 4 + r;
#pragma unroll
    for (int c2 = 0; c2 < 8; ++c2)
      O[((size_t)b * 2048 + qrow) * 2048 + h * 128 + c2 * 16 + l16] =
          f2bf(of[c2][r] * inv);
  }
}

// ---------------------------------------------------------------------------
extern "C" void kernel_launch(void* const* d_in, const int* in_sizes, int n_in,
                              void* d_out, int out_size, void* d_ws, size_t ws_size,
                              hipStream_t stream) {
  (void)in_sizes; (void)n_in; (void)out_size; (void)ws_size;
  const float* hid  = (const float*)d_in[0];
  const float* temb = (const float*)d_in[1];
  const float* wln  = (const float*)d_in[2];
  const float* wmod = (const float*)d_in[3];
  const float* bmod = (const float*)d_in[4];
  const float* wq   = (const float*)d_in[5];
  const float* wk   = (const float*)d_in[6];
  const float* wv   = (const float*)d_in[7];
  const float* wo   = (const float*)d_in[8];
  const float* qn   = (const float*)d_in[9];
  const float* kn   = (const float*)d_in[10];
  const float* cos1 = (const float*)d_in[11];
  const float* sin1 = (const float*)d_in[12];
  const float* r3   = (const float*)d_in[13];
  const int*   mpos = (const int*)d_in[14];

  char* ws = (char*)d_ws;
  float* mod = (float*)(ws + 0);                 //  49,152 B
  u16* xm  = (u16*)(ws + 49152);                 //  16 MiB
  u16* wT  = (u16*)(ws + 16826368);              //  16 MiB (wq|wk|wv)^T bf16
  u16* woT = wT;                                 //  overlay after QKV GEMM
  u16* qkv = (u16*)(ws + 33603584);              //  32 MiB bf16 (B*L, 4096)
  u16* Qb  = (u16*)(ws + 67158016);              //  16 MiB (B,H,L,Dh)
  u16* Kv  = (u16*)(ws + 83935232);              //   8 MiB (B,KVH,L,Dh)
  u16* VT  = (u16*)(ws + 92323840);              //   8 MiB (B,KVH,Dh,L)
  u16* Ob  = qkv;                                //  overlay (qkv dead by then)

  dim3 b32(32, 8);
  k_silu_mod<<<96, 512, 0, stream>>>(temb, wmod, bmod, mod);
  k_tconv<<<dim3(64, 64), b32, 0, stream>>>(wq, wT, 2048, 2048);
  k_tconv<<<dim3(64, 32), b32, 0, stream>>>(wk, wT + (size_t)2048 * 2048, 1024, 2048);
  k_tconv<<<dim3(64, 32), b32, 0, stream>>>(wv, wT + (size_t)3072 * 2048, 1024, 2048);
  k_xm<<<4096, 256, 0, stream>>>(hid, wln, mod, xm);
  k_gemm<0><<<dim3(32, 32), 256, 0, stream>>>(xm, wT, qkv, nullptr, nullptr, 4096, 2048);
  k_tconv<<<dim3(64, 64), b32, 0, stream>>>(wo, woT, 2048, 2048);
  k_qknorm<<<4096, 192, 0, stream>>>(qkv, qn, kn, cos1, sin1, r3, mpos, Qb, Kv);
  k_vtrans<<<dim3(16, 32, 2), 256, 0, stream>>>(qkv, VT);
  k_attn<<<dim3(16, 32), 512, 0, stream>>>(Qb, Kv, VT, Ob);
  k_gemm<1><<<dim3(16, 32), 256, 0, stream>>>(Ob, woT, d_out, hid, mod, 2048, 2048);
}

// Round 2
// 491.570 us; speedup vs baseline: 1.1633x; 1.0826x over previous
//
#include <hip/hip_runtime.h>
#include <stdint.h>
#include <math.h>

typedef unsigned short u16;
typedef __attribute__((ext_vector_type(8))) short short8;
typedef __attribute__((ext_vector_type(4))) float fx4;
typedef __attribute__((ext_vector_type(4))) unsigned short u16x4;

#define DEV __device__ __forceinline__

DEV u16 f2bf(float f) {
  unsigned u = __builtin_bit_cast(unsigned, f);
  return (u16)((u + 0x7FFFu + ((u >> 16) & 1u)) >> 16);
}
DEV float bf2f(u16 h) { return __builtin_bit_cast(float, ((unsigned)h) << 16); }

DEV fx4 mfma16(short8 a, short8 b, fx4 c) {
  return __builtin_amdgcn_mfma_f32_16x16x32_bf16(a, b, c, 0, 0, 0);
}

#if __has_builtin(__builtin_amdgcn_exp2f)
DEV float exp2v(float x) { return __builtin_amdgcn_exp2f(x); }
#else
DEV float exp2v(float x) { return exp2f(x); }
#endif

// async global->LDS, 16B per lane. LDS dst = wave-uniform base + lane*16.
#define GLD16(g, l)                                                            \
  __builtin_amdgcn_global_load_lds(                                            \
      (const __attribute__((address_space(1))) void*)(g),                      \
      (__attribute__((address_space(3))) void*)(l), 16, 0, 0)

#define WAIT_ALL() asm volatile("s_waitcnt vmcnt(0) lgkmcnt(0)" ::: "memory")

// ---------------------------------------------------------------------------
// 1) mod = silu(temb) @ w_mod + b_mod   (2x2048 @ 2048x6144)
__global__ __launch_bounds__(512) void k_silu_mod(
    const float* __restrict__ temb, const float* __restrict__ wmod,
    const float* __restrict__ bmod, float* __restrict__ mod) {
  __shared__ float st[4096];
  __shared__ float red[8][2][64];
  int tid = threadIdx.x;
  for (int i = tid; i < 4096; i += 512) {
    float t = temb[i];
    st[i] = t / (1.0f + __expf(-t));
  }
  __syncthreads();
  int j = blockIdx.x * 64 + (tid & 63);
  int ks = tid >> 6;
  float a0 = 0.f, a1 = 0.f;
  for (int d = ks * 256; d < ks * 256 + 256; ++d) {
    float w = wmod[(size_t)d * 6144 + j];
    a0 += st[d] * w;
    a1 += st[2048 + d] * w;
  }
  red[ks][0][tid & 63] = a0;
  red[ks][1][tid & 63] = a1;
  __syncthreads();
  if (tid < 64) {
    float s0 = 0.f, s1 = 0.f;
#pragma unroll
    for (int i = 0; i < 8; ++i) {
      s0 += red[i][0][tid];
      s1 += red[i][1][tid];
    }
    mod[j] = s0 + bmod[j];
    mod[6144 + j] = s1 + bmod[j];
  }
}

// ---------------------------------------------------------------------------
// 2) xm = bf16( rmsnorm(hidden)*w_ln * (1+scale[b]) + shift[b] )
__global__ __launch_bounds__(256) void k_xm(
    const float* __restrict__ x, const float* __restrict__ wln,
    const float* __restrict__ mod, u16* __restrict__ xm) {
  int row = blockIdx.x;
  int b = row >> 11;
  const float* xr = x + (size_t)row * 2048;
  int tid = threadIdx.x;
  float4 v0 = ((const float4*)xr)[tid];
  float4 v1 = ((const float4*)xr)[tid + 256];
  float ss = v0.x * v0.x + v0.y * v0.y + v0.z * v0.z + v0.w * v0.w +
             v1.x * v1.x + v1.y * v1.y + v1.z * v1.z + v1.w * v1.w;
  for (int m = 1; m < 64; m <<= 1) ss += __shfl_xor(ss, m);
  __shared__ float red[4];
  if ((tid & 63) == 0) red[tid >> 6] = ss;
  __syncthreads();
  ss = red[0] + red[1] + red[2] + red[3];
  float r = rsqrtf(ss * (1.0f / 2048.0f) + 1e-5f);
  const float* mb = mod + (size_t)b * 6144;
#pragma unroll
  for (int c = 0; c < 2; ++c) {
    int j0 = (tid + c * 256) * 4;
    float4 xv = c ? v1 : v0;
    float4 sh = *(const float4*)(mb + j0);
    float4 sc = *(const float4*)(mb + 2048 + j0);
    float4 wl = *(const float4*)(wln + j0);
    u16x4 o;
    o.x = f2bf(xv.x * r * wl.x * (1.f + sc.x) + sh.x);
    o.y = f2bf(xv.y * r * wl.y * (1.f + sc.y) + sh.y);
    o.z = f2bf(xv.z * r * wl.z * (1.f + sc.z) + sh.z);
    o.w = f2bf(xv.w * r * wl.w * (1.f + sc.w) + sh.w);
    *(u16x4*)(xm + (size_t)row * 2048 + j0) = o;
  }
}

// ---------------------------------------------------------------------------
// 3) transpose-convert fp32 [K][cols] -> bf16 dst[n][K]
__global__ __launch_bounds__(256) void k_tconv(
    const float* __restrict__ src, u16* __restrict__ dst, int cols, int rows) {
  __shared__ float t[32][33];
  int kb = blockIdx.x * 32, nb = blockIdx.y * 32;
  int tx = threadIdx.x, ty = threadIdx.y;
#pragma unroll
  for (int i = 0; i < 4; ++i)
    t[ty + i * 8][tx] = src[(size_t)(kb + ty + i * 8) * cols + nb + tx];
  __syncthreads();
#pragma unroll
  for (int i = 0; i < 4; ++i)
    dst[(size_t)(nb + ty + i * 8) * rows + kb + tx] = f2bf(t[tx][ty + i * 8]);
}

// ---------------------------------------------------------------------------
// 4) GEMM with XOR-swizzled LDS (slot = chunk ^ ((row>>1)&3); 2-way = free)
template <int EPI>
__global__ __launch_bounds__(256) void k_gemm(
    const u16* __restrict__ A, const u16* __restrict__ Bt, void* __restrict__ Cp,
    const float* __restrict__ hid, const float* __restrict__ mod, int N, int K) {
  __shared__ u16 As[128 * 32];
  __shared__ u16 Bs[128 * 32];
  int tid = threadIdx.x;
  int wave = tid >> 6, lane = tid & 63, quad = lane >> 4, l16 = lane & 15;
  int m0 = blockIdx.y * 128, n0 = blockIdx.x * 128;
  int wm = (wave >> 1) * 64, wn = (wave & 1) * 64;
  fx4 acc[4][4] = {};
  int rowa = tid >> 2;
  int chunk = (tid & 3) ^ ((rowa >> 1) & 3);  // swizzled source chunk
  int cola = chunk * 8;
  const u16* Ag = A + (size_t)(m0 + rowa) * K + cola;
  const u16* Bg = Bt + (size_t)(n0 + rowa) * K + cola;
  u16* AsW = &As[wave * 512];
  u16* BsW = &Bs[wave * 512];
  int sl = (quad ^ ((l16 >> 1) & 3)) * 8;  // swizzled read slot (bytes/2)
  for (int k0 = 0; k0 < K; k0 += 32) {
    GLD16(Ag + k0, AsW);
    GLD16(Ag + k0 + (size_t)64 * K, AsW + 2048);
    GLD16(Bg + k0, BsW);
    GLD16(Bg + k0 + (size_t)64 * K, BsW + 2048);
    __syncthreads();
    short8 af[4], bfr[4];
#pragma unroll
    for (int i = 0; i < 4; ++i) {
      af[i] = *(const short8*)&As[(wm + i * 16 + l16) * 32 + sl];
      bfr[i] = *(const short8*)&Bs[(wn + i * 16 + l16) * 32 + sl];
    }
#pragma unroll
    for (int i = 0; i < 4; ++i)
#pragma unroll
      for (int j = 0; j < 4; ++j) acc[i][j] = mfma16(af[i], bfr[j], acc[i][j]);
    __syncthreads();
  }
#pragma unroll
  for (int i = 0; i < 4; ++i) {
    int row = m0 + wm + i * 16 + quad * 4;
#pragma unroll
    for (int j = 0; j < 4; ++j) {
      int col = n0 + wn + j * 16 + l16;
      if (EPI == 0) {
        u16* C = (u16*)Cp;
#pragma unroll
        for (int r = 0; r < 4; ++r)
          C[(size_t)(row + r) * N + col] = f2bf(acc[i][j][r]);
      } else {
        float* C = (float*)Cp;
        int b = row >> 11;
        float g = mod[(size_t)b * 6144 + 4096 + col];
#pragma unroll
        for (int r = 0; r < 4; ++r)
          C[(size_t)(row + r) * N + col] =
              hid[(size_t)(row + r) * N + col] + g * acc[i][j][r];
      }
    }
  }
}

// ---------------------------------------------------------------------------
// 5) QK rms-norm + mixed RoPE. Q pre-scaled by log2(e)/sqrt(Dh) so the
// attention softmax can run entirely in exp2 domain (bare v_exp_f32).
__global__ __launch_bounds__(192) void k_qknorm(
    const u16* __restrict__ qkv, const float* __restrict__ qn,
    const float* __restrict__ kn, const float* __restrict__ cos1,
    const float* __restrict__ sin1, const float* __restrict__ r3,
    const int* __restrict__ mpos, u16* __restrict__ Q, u16* __restrict__ Kb) {
  int bx = blockIdx.x;
  int b = bx >> 11, l = bx & 2047;
  int tid = threadIdx.x;
  int slot = tid >> 3, sub = tid & 7;
  bool isq = slot < 16;
  int head = isq ? slot : slot - 16;
  const u16* base = qkv + (size_t)bx * 4096 + (isq ? slot * 128 : 2048 + head * 128);
  int d0 = sub * 16;
  float xv[16];
#pragma unroll
  for (int i = 0; i < 16; ++i) xv[i] = bf2f(base[d0 + i]);
  float ss = 0.f;
#pragma unroll
  for (int i = 0; i < 16; ++i) ss += xv[i] * xv[i];
  ss += __shfl_xor(ss, 1);
  ss += __shfl_xor(ss, 2);
  ss += __shfl_xor(ss, 4);
  float r = rsqrtf(ss * (1.0f / 128.0f) + 1e-5f);
  int mp[8];
  {
    bool is64 = (mpos[1] == 0) & (mpos[3] == 0) & (mpos[5] == 0) & (mpos[7] == 0);
#pragma unroll
    for (int i = 0; i < 8; ++i) mp[i] = is64 ? mpos[2 * i] : mpos[i];
  }
  bool infull = false, inimg = false;
  int rel = 0;
#pragma unroll
  for (int s = 0; s < 2; ++s) {
    int off = mp[b * 4 + s * 2], ln = mp[b * 4 + s * 2 + 1];
    int mx = ln > 1 ? ln : 1;
    infull |= (l >= off) && (l < off + mx);
    bool ii = (l >= off + 1) && (l < off + ln);
    inimg |= ii;
    rel += ii ? (l - (off + 1)) : 0;
  }
  bool text = !infull;
  bool img = inimg && (rel < 1024);
  const float* w = isq ? qn : kn;
  float out[16];
  if (text) {
    int dp0 = d0 ^ 64;
    float sgn = (d0 < 64) ? -1.f : 1.f;
#pragma unroll
    for (int i = 0; i < 16; ++i) {
      int d = d0 + i, dp = dp0 + i;
      float c = cos1[(size_t)l * 128 + d];
      float s = sin1[(size_t)l * 128 + d];
      float xp = bf2f(base[dp]);
      out[i] = r * (xv[i] * w[d] * c + sgn * xp * w[dp] * s);
    }
  } else if (img) {
    const float* R = r3 + ((size_t)rel * 64 + (d0 >> 1)) * 4;
#pragma unroll
    for (int p = 0; p < 8; ++p) {
      float a = xv[2 * p] * w[d0 + 2 * p] * r;
      float c2 = xv[2 * p + 1] * w[d0 + 2 * p + 1] * r;
      out[2 * p] = a * R[4 * p + 0] + c2 * R[4 * p + 2];
      out[2 * p + 1] = a * R[4 * p + 1] + c2 * R[4 * p + 3];
    }
  } else {
#pragma unroll
    for (int i = 0; i < 16; ++i) out[i] = xv[i] * w[d0 + i] * r;
  }
  if (isq) {
    u16* dst = Q + ((size_t)(b * 16 + head) * 2048 + l) * 128 + d0;
#pragma unroll
    for (int i = 0; i < 16; ++i)
      dst[i] = f2bf(out[i] * (0.08838834764831845f * 1.4426950408889634f));
  } else {
    u16* dst = Kb + ((size_t)(b * 8 + head) * 2048 + l) * 128 + d0;
#pragma unroll
    for (int i = 0; i < 16; ++i) dst[i] = f2bf(out[i]);
  }
}

// ---------------------------------------------------------------------------
// 6) V^T: qkv[:, 3072+...] -> VT (B,KVH,Dh,L)
__global__ __launch_bounds__(256) void k_vtrans(const u16* __restrict__ qkv,
                                                u16* __restrict__ VT) {
  __shared__ u16 t[64][65];
  int bh = blockIdx.x;
  int l0 = blockIdx.y * 64, d0 = blockIdx.z * 64;
  int b = bh >> 3, kvh = bh & 7;
  int tx = threadIdx.x & 63, tg = threadIdx.x >> 6;
#pragma unroll
  for (int i = 0; i < 16; ++i) {
    int li = tg + i * 4;
    t[li][tx] = qkv[(size_t)(b * 2048 + l0 + li) * 4096 + 3072 + kvh * 128 + d0 + tx];
  }
  __syncthreads();
#pragma unroll
  for (int i = 0; i < 16; ++i) {
    int di = tg + i * 4;
    VT[((size_t)bh * 128 + d0 + di) * 2048 + l0 + tx] = t[tx][di];
  }
}

// ---------------------------------------------------------------------------
// 7) flash attention v2, depth-1 pipelined, shuffle-free softmax common path:
//   - per-lane partial row-sum (lpart), cross-lane reduced ONCE at the end
//   - row-max cross-lane reduce only when the defer-max gate trips
//   grid (L/128, B*H), 512 threads (8 waves x 16 q-rows), BQ=128, BKV=64.
//   LDS = 2*16K (Ks) + 2*16K (Vs) + 16K (Ps) = 80 KB -> 2 blocks/CU.
__global__ __launch_bounds__(512, 4) void k_attn(
    const u16* __restrict__ Q, const u16* __restrict__ Kb,
    const u16* __restrict__ VT, u16* __restrict__ O) {
  __shared__ u16 Ks[2][64 * 128];  // kv x dh, swizzled
  __shared__ u16 Vs[2][128 * 64];  // dh x kv, swizzled
  __shared__ u16 Ps[128 * 64];     // q x kv, swizzled (wave-private stripes)
  int tid = threadIdx.x;
  int wave = tid >> 6, lane = tid & 63, quad = lane >> 4, l16 = lane & 15;
  int bh = blockIdx.y;
  int b = bh >> 4, h = bh & 15, kvh = h >> 1;
  int q0 = blockIdx.x * 128;
  const u16* Qb = Q + ((size_t)bh * 2048 + q0 + wave * 16) * 128;
  short8 qf[4];
#pragma unroll
  for (int ks = 0; ks < 4; ++ks)
    qf[ks] = *(const short8*)(Qb + l16 * 128 + ks * 32 + quad * 8);
  const u16* Kg = Kb + (size_t)(b * 8 + kvh) * 2048 * 128;
  const u16* Vg = VT + (size_t)(b * 8 + kvh) * 128 * 2048;
  float mrow[4], lpart[4];
  fx4 of[8] = {};
#pragma unroll
  for (int r = 0; r < 4; ++r) {
    mrow[r] = -INFINITY;
    lpart[r] = 0.f;
  }
  // staging offsets (swizzled global source; LDS dst stays linear)
  size_t kgo[2], vgo[2];
#pragma unroll
  for (int i = 0; i < 2; ++i) {
    int kr = i * 32 + wave * 4 + (lane >> 4);  // local kv row
    kgo[i] = (size_t)kr * 128 + (((lane & 15) ^ (kr & 15)) * 8);
    int vr = i * 64 + wave * 8 + (lane >> 3);  // dh row
    vgo[i] = (size_t)vr * 2048 + (((lane & 7) ^ (vr & 7)) * 8);
  }

  auto STAGE = [&](int t, int buf) {
    size_t ko = (size_t)t * 8192;  // t*64 rows * 128
    size_t vo = (size_t)t * 64;    // t*64 cols
#pragma unroll
    for (int i = 0; i < 2; ++i) {
      GLD16(Kg + ko + kgo[i], &Ks[buf][i * 4096 + wave * 512]);
      GLD16(Vg + vo + vgo[i], &Vs[buf][i * 4096 + wave * 512]);
    }
  };

  auto COMPUTE = [&](int buf) {
    fx4 sf[4] = {};
    __builtin_amdgcn_s_setprio(1);
#pragma unroll
    for (int ct = 0; ct < 4; ++ct) {
#pragma unroll
      for (int ks = 0; ks < 4; ++ks) {
        short8 kf = *(const short8*)&Ks[buf][(ct * 16 + l16) * 128 +
                                            (((ks * 4 + quad) ^ l16) * 8)];
        sf[ct] = mfma16(qf[ks], kf, sf[ct]);
      }
    }
    __builtin_amdgcn_s_setprio(0);
    // per-lane local max; cross-lane reduce only when gate trips (rare)
    float cmv[4];
    bool need = false;
#pragma unroll
    for (int r = 0; r < 4; ++r) {
      cmv[r] = fmaxf(fmaxf(sf[0][r], sf[1][r]), fmaxf(sf[2][r], sf[3][r]));
      need |= (cmv[r] > mrow[r] + 8.0f);
    }
    if (__any(need)) {  // T13 defer-max: P bounded by 2^8
#pragma unroll
      for (int r = 0; r < 4; ++r) {
        float cm = cmv[r];
        cm = fmaxf(cm, __shfl_xor(cm, 1));
        cm = fmaxf(cm, __shfl_xor(cm, 2));
        cm = fmaxf(cm, __shfl_xor(cm, 4));
        cm = fmaxf(cm, __shfl_xor(cm, 8));
        float mn = fmaxf(mrow[r], cm);
        float al = exp2v(mrow[r] - mn);
        mrow[r] = mn;
        lpart[r] *= al;
#pragma unroll
        for (int c2 = 0; c2 < 8; ++c2) of[c2][r] *= al;
      }
    }
    int hb = l16 >> 3;
#pragma unroll
    for (int r = 0; r < 4; ++r) {
      float p0 = exp2v(sf[0][r] - mrow[r]);
      float p1 = exp2v(sf[1][r] - mrow[r]);
      float p2 = exp2v(sf[2][r] - mrow[r]);
      float p3 = exp2v(sf[3][r] - mrow[r]);
      lpart[r] += (p0 + p1) + (p2 + p3);  // per-lane partial; no shuffles
      int prow = wave * 16 + quad * 4 + r;
      int pb = prow * 64, px = prow & 7, lo = l16 & 7;
      Ps[pb + ((0 + hb) ^ px) * 8 + lo] = f2bf(p0);
      Ps[pb + ((2 + hb) ^ px) * 8 + lo] = f2bf(p1);
      Ps[pb + ((4 + hb) ^ px) * 8 + lo] = f2bf(p2);
      Ps[pb + ((6 + hb) ^ px) * 8 + lo] = f2bf(p3);
    }
    __builtin_amdgcn_s_setprio(1);
#pragma unroll
    for (int ks2 = 0; ks2 < 2; ++ks2) {
      int rsl = (((ks2 * 4 + quad) ^ (l16 & 7)) * 8);
      short8 pa = *(const short8*)&Ps[(wave * 16 + l16) * 64 + rsl];
#pragma unroll
      for (int c2 = 0; c2 < 8; ++c2) {
        short8 vb = *(const short8*)&Vs[buf][(c2 * 16 + l16) * 64 + rsl];
        of[c2] = mfma16(pa, vb, of[c2]);
      }
    }
    __builtin_amdgcn_s_setprio(0);
  };

  STAGE(0, 0);
  WAIT_ALL();
  __builtin_amdgcn_s_barrier();
  int cur = 0;
  for (int t = 0; t < 31; ++t) {
    STAGE(t + 1, cur ^ 1);  // prefetch next tile; latency hides under compute
    COMPUTE(cur);
    WAIT_ALL();             // single drain per tile, AFTER compute
    __builtin_amdgcn_s_barrier();
    cur ^= 1;
  }
  COMPUTE(cur);

  // deferred cross-lane row-sum (once, not per tile)
#pragma unroll
  for (int r = 0; r < 4; ++r) {
    float ls = lpart[r];
    ls += __shfl_xor(ls, 1);
    ls += __shfl_xor(ls, 2);
    ls += __shfl_xor(ls, 4);
    ls += __shfl_xor(ls, 8);
    float inv = 1.0f / ls;
    int qrow = q0 + wave * 16 + quad * 4 + r;
#pragma unroll
    for (int c2 = 0; c2 < 8; ++c2)
      O[((size_t)b * 2048 + qrow) * 2048 + h * 128 + c2 * 16 + l16] =
          f2bf(of[c2][r] * inv);
  }
}

// ---------------------------------------------------------------------------
extern "C" void kernel_launch(void* const* d_in, const int* in_sizes, int n_in,
                              void* d_out, int out_size, void* d_ws, size_t ws_size,
                              hipStream_t stream) {
  (void)in_sizes; (void)n_in; (void)out_size; (void)ws_size;
  const float* hid  = (const float*)d_in[0];
  const float* temb = (const float*)d_in[1];
  const float* wln  = (const float*)d_in[2];
  const float* wmod = (const float*)d_in[3];
  const float* bmod = (const float*)d_in[4];
  const float* wq   = (const float*)d_in[5];
  const float* wk   = (const float*)d_in[6];
  const float* wv   = (const float*)d_in[7];
  const float* wo   = (const float*)d_in[8];
  const float* qn   = (const float*)d_in[9];
  const float* kn   = (const float*)d_in[10];
  const float* cos1 = (const float*)d_in[11];
  const float* sin1 = (const float*)d_in[12];
  const float* r3   = (const float*)d_in[13];
  const int*   mpos = (const int*)d_in[14];

  char* ws = (char*)d_ws;
  float* mod = (float*)(ws + 0);                 //  49,152 B
  u16* xm  = (u16*)(ws + 49152);                 //  16 MiB
  u16* wT  = (u16*)(ws + 16826368);              //  16 MiB (wq|wk|wv)^T bf16
  u16* woT = wT;                                 //  overlay after QKV GEMM
  u16* qkv = (u16*)(ws + 33603584);              //  32 MiB bf16 (B*L, 4096)
  u16* Qb  = (u16*)(ws + 67158016);              //  16 MiB (B,H,L,Dh)
  u16* Kv  = (u16*)(ws + 83935232);              //   8 MiB (B,KVH,L,Dh)
  u16* VT  = (u16*)(ws + 92323840);              //   8 MiB (B,KVH,Dh,L)
  u16* Ob  = qkv;                                //  overlay (qkv dead by then)

  dim3 b32(32, 8);
  k_silu_mod<<<96, 512, 0, stream>>>(temb, wmod, bmod, mod);
  k_tconv<<<dim3(64, 64), b32, 0, stream>>>(wq, wT, 2048, 2048);
  k_tconv<<<dim3(64, 32), b32, 0, stream>>>(wk, wT + (size_t)2048 * 2048, 1024, 2048);
  k_tconv<<<dim3(64, 32), b32, 0, stream>>>(wv, wT + (size_t)3072 * 2048, 1024, 2048);
  k_xm<<<4096, 256, 0, stream>>>(hid, wln, mod, xm);
  k_gemm<0><<<dim3(32, 32), 256, 0, stream>>>(xm, wT, qkv, nullptr, nullptr, 4096, 2048);
  k_tconv<<<dim3(64, 64), b32, 0, stream>>>(wo, woT, 2048, 2048);
  k_qknorm<<<4096, 192, 0, stream>>>(qkv, qn, kn, cos1, sin1, r3, mpos, Qb, Kv);
  k_vtrans<<<dim3(16, 32, 2), 256, 0, stream>>>(qkv, VT);
  k_attn<<<dim3(16, 32), 512, 0, stream>>>(Qb, Kv, VT, Ob);
  k_gemm<1><<<dim3(16, 32), 256, 0, stream>>>(Ob, woT, d_out, hid, mod, 2048, 2048);
}

// Round 3
// 487.427 us; speedup vs baseline: 1.1732x; 1.0085x over previous
//
#include <hip/hip_runtime.h>
#include <stdint.h>
#include <math.h>

typedef unsigned short u16;
typedef __attribute__((ext_vector_type(8))) short short8;
typedef __attribute__((ext_vector_type(4))) float fx4;
typedef __attribute__((ext_vector_type(4))) unsigned short u16x4;

#define DEV __device__ __forceinline__

DEV u16 f2bf(float f) {
  unsigned u = __builtin_bit_cast(unsigned, f);
  return (u16)((u + 0x7FFFu + ((u >> 16) & 1u)) >> 16);
}
DEV float bf2f(u16 h) { return __builtin_bit_cast(float, ((unsigned)h) << 16); }

DEV fx4 mfma16(short8 a, short8 b, fx4 c) {
  return __builtin_amdgcn_mfma_f32_16x16x32_bf16(a, b, c, 0, 0, 0);
}

#if __has_builtin(__builtin_amdgcn_exp2f)
DEV float exp2v(float x) { return __builtin_amdgcn_exp2f(x); }
#else
DEV float exp2v(float x) { return exp2f(x); }
#endif

// async global->LDS, 16B per lane. LDS dst = wave-uniform base + lane*16.
#define GLD16(g, l)                                                            \
  __builtin_amdgcn_global_load_lds(                                            \
      (const __attribute__((address_space(1))) void*)(g),                      \
      (__attribute__((address_space(3))) void*)(l), 16, 0, 0)

#define WAIT_ALL() asm volatile("s_waitcnt vmcnt(0) lgkmcnt(0)" ::: "memory")

// ---------------------------------------------------------------------------
// 1) mod = silu(temb) @ w_mod + b_mod   (2x2048 @ 2048x6144)
__global__ __launch_bounds__(512) void k_silu_mod(
    const float* __restrict__ temb, const float* __restrict__ wmod,
    const float* __restrict__ bmod, float* __restrict__ mod) {
  __shared__ float st[4096];
  __shared__ float red[8][2][64];
  int tid = threadIdx.x;
  for (int i = tid; i < 4096; i += 512) {
    float t = temb[i];
    st[i] = t / (1.0f + __expf(-t));
  }
  __syncthreads();
  int j = blockIdx.x * 64 + (tid & 63);
  int ks = tid >> 6;
  float a0 = 0.f, a1 = 0.f;
  for (int d = ks * 256; d < ks * 256 + 256; ++d) {
    float w = wmod[(size_t)d * 6144 + j];
    a0 += st[d] * w;
    a1 += st[2048 + d] * w;
  }
  red[ks][0][tid & 63] = a0;
  red[ks][1][tid & 63] = a1;
  __syncthreads();
  if (tid < 64) {
    float s0 = 0.f, s1 = 0.f;
#pragma unroll
    for (int i = 0; i < 8; ++i) {
      s0 += red[i][0][tid];
      s1 += red[i][1][tid];
    }
    mod[j] = s0 + bmod[j];
    mod[6144 + j] = s1 + bmod[j];
  }
}

// ---------------------------------------------------------------------------
// 2) xm = bf16( rmsnorm(hidden)*w_ln * (1+scale[b]) + shift[b] )
__global__ __launch_bounds__(256) void k_xm(
    const float* __restrict__ x, const float* __restrict__ wln,
    const float* __restrict__ mod, u16* __restrict__ xm) {
  int row = blockIdx.x;
  int b = row >> 11;
  const float* xr = x + (size_t)row * 2048;
  int tid = threadIdx.x;
  float4 v0 = ((const float4*)xr)[tid];
  float4 v1 = ((const float4*)xr)[tid + 256];
  float ss = v0.x * v0.x + v0.y * v0.y + v0.z * v0.z + v0.w * v0.w +
             v1.x * v1.x + v1.y * v1.y + v1.z * v1.z + v1.w * v1.w;
  for (int m = 1; m < 64; m <<= 1) ss += __shfl_xor(ss, m);
  __shared__ float red[4];
  if ((tid & 63) == 0) red[tid >> 6] = ss;
  __syncthreads();
  ss = red[0] + red[1] + red[2] + red[3];
  float r = rsqrtf(ss * (1.0f / 2048.0f) + 1e-5f);
  const float* mb = mod + (size_t)b * 6144;
#pragma unroll
  for (int c = 0; c < 2; ++c) {
    int j0 = (tid + c * 256) * 4;
    float4 xv = c ? v1 : v0;
    float4 sh = *(const float4*)(mb + j0);
    float4 sc = *(const float4*)(mb + 2048 + j0);
    float4 wl = *(const float4*)(wln + j0);
    u16x4 o;
    o.x = f2bf(xv.x * r * wl.x * (1.f + sc.x) + sh.x);
    o.y = f2bf(xv.y * r * wl.y * (1.f + sc.y) + sh.y);
    o.z = f2bf(xv.z * r * wl.z * (1.f + sc.z) + sh.z);
    o.w = f2bf(xv.w * r * wl.w * (1.f + sc.w) + sh.w);
    *(u16x4*)(xm + (size_t)row * 2048 + j0) = o;
  }
}

// ---------------------------------------------------------------------------
// 3) transpose-convert fp32 [K][cols] -> bf16 dst[n][K]
__global__ __launch_bounds__(256) void k_tconv(
    const float* __restrict__ src, u16* __restrict__ dst, int cols, int rows) {
  __shared__ float t[32][33];
  int kb = blockIdx.x * 32, nb = blockIdx.y * 32;
  int tx = threadIdx.x, ty = threadIdx.y;
#pragma unroll
  for (int i = 0; i < 4; ++i)
    t[ty + i * 8][tx] = src[(size_t)(kb + ty + i * 8) * cols + nb + tx];
  __syncthreads();
#pragma unroll
  for (int i = 0; i < 4; ++i)
    dst[(size_t)(nb + ty + i * 8) * rows + kb + tx] = f2bf(t[tx][ty + i * 8]);
}

// ---------------------------------------------------------------------------
// 4) GEMM, depth-1 pipelined (T3 minimal 2-phase) + bijective XCD swizzle.
//   Double-buffered 128x32 LDS tiles staged via global_load_lds; prefetch of
//   K-step k+1 issued BEFORE compute of k; single vmcnt(0)+s_barrier drain
//   AFTER compute so HBM latency hides under 16 MFMAs. XCD-chunk block
//   swizzle gives each XCD a contiguous band of A-panel rows (L2-resident).
template <int EPI>
__global__ __launch_bounds__(256) void k_gemm(
    const u16* __restrict__ A, const u16* __restrict__ Bt, void* __restrict__ Cp,
    const float* __restrict__ hid, const float* __restrict__ mod, int N, int K) {
  __shared__ u16 As[2][128 * 32];
  __shared__ u16 Bs[2][128 * 32];
  int tid = threadIdx.x;
  int wave = tid >> 6, lane = tid & 63, quad = lane >> 4, l16 = lane & 15;
  // bijective XCD-chunk swizzle (both grids have nwg % 8 == 0)
  int gx = gridDim.x;
  int nwg = gx * gridDim.y;
  int lin = blockIdx.y * gx + blockIdx.x;
  int cpx = nwg >> 3;
  int swz = (lin & 7) * cpx + (lin >> 3);
  int m0 = (swz / gx) * 128, n0 = (swz % gx) * 128;
  int wm = (wave >> 1) * 64, wn = (wave & 1) * 64;
  fx4 acc[4][4] = {};
  int rowa = tid >> 2;
  int chunk = (tid & 3) ^ ((rowa >> 1) & 3);  // swizzled source chunk
  int cola = chunk * 8;
  const u16* Ag = A + (size_t)(m0 + rowa) * K + cola;
  const u16* Bg = Bt + (size_t)(n0 + rowa) * K + cola;
  int sl = (quad ^ ((l16 >> 1) & 3)) * 8;  // swizzled read slot (bytes/2)

  auto STAGE = [&](int k0, int buf) {
    u16* AsW = &As[buf][wave * 512];
    u16* BsW = &Bs[buf][wave * 512];
    GLD16(Ag + k0, AsW);
    GLD16(Ag + k0 + (size_t)64 * K, AsW + 2048);
    GLD16(Bg + k0, BsW);
    GLD16(Bg + k0 + (size_t)64 * K, BsW + 2048);
  };
  auto COMPUTE = [&](int buf) {
    short8 af[4], bfr[4];
#pragma unroll
    for (int i = 0; i < 4; ++i) {
      af[i] = *(const short8*)&As[buf][(wm + i * 16 + l16) * 32 + sl];
      bfr[i] = *(const short8*)&Bs[buf][(wn + i * 16 + l16) * 32 + sl];
    }
#pragma unroll
    for (int i = 0; i < 4; ++i)
#pragma unroll
      for (int j = 0; j < 4; ++j) acc[i][j] = mfma16(af[i], bfr[j], acc[i][j]);
  };

  STAGE(0, 0);
  WAIT_ALL();
  __builtin_amdgcn_s_barrier();
  int cur = 0;
  for (int k0 = 32; k0 < K; k0 += 32) {
    STAGE(k0, cur ^ 1);  // prefetch next K-step; latency hides under compute
    COMPUTE(cur);
    WAIT_ALL();          // single drain per step, AFTER compute
    __builtin_amdgcn_s_barrier();
    cur ^= 1;
  }
  COMPUTE(cur);

#pragma unroll
  for (int i = 0; i < 4; ++i) {
    int row = m0 + wm + i * 16 + quad * 4;
#pragma unroll
    for (int j = 0; j < 4; ++j) {
      int col = n0 + wn + j * 16 + l16;
      if (EPI == 0) {
        u16* C = (u16*)Cp;
#pragma unroll
        for (int r = 0; r < 4; ++r)
          C[(size_t)(row + r) * N + col] = f2bf(acc[i][j][r]);
      } else {
        float* C = (float*)Cp;
        int b = row >> 11;
        float g = mod[(size_t)b * 6144 + 4096 + col];
#pragma unroll
        for (int r = 0; r < 4; ++r)
          C[(size_t)(row + r) * N + col] =
              hid[(size_t)(row + r) * N + col] + g * acc[i][j][r];
      }
    }
  }
}

// ---------------------------------------------------------------------------
// 5) QK rms-norm + mixed RoPE. Q pre-scaled by log2(e)/sqrt(Dh) so the
// attention softmax can run entirely in exp2 domain (bare v_exp_f32).
__global__ __launch_bounds__(192) void k_qknorm(
    const u16* __restrict__ qkv, const float* __restrict__ qn,
    const float* __restrict__ kn, const float* __restrict__ cos1,
    const float* __restrict__ sin1, const float* __restrict__ r3,
    const int* __restrict__ mpos, u16* __restrict__ Q, u16* __restrict__ Kb) {
  int bx = blockIdx.x;
  int b = bx >> 11, l = bx & 2047;
  int tid = threadIdx.x;
  int slot = tid >> 3, sub = tid & 7;
  bool isq = slot < 16;
  int head = isq ? slot : slot - 16;
  const u16* base = qkv + (size_t)bx * 4096 + (isq ? slot * 128 : 2048 + head * 128);
  int d0 = sub * 16;
  float xv[16];
#pragma unroll
  for (int i = 0; i < 16; ++i) xv[i] = bf2f(base[d0 + i]);
  float ss = 0.f;
#pragma unroll
  for (int i = 0; i < 16; ++i) ss += xv[i] * xv[i];
  ss += __shfl_xor(ss, 1);
  ss += __shfl_xor(ss, 2);
  ss += __shfl_xor(ss, 4);
  float r = rsqrtf(ss * (1.0f / 128.0f) + 1e-5f);
  int mp[8];
  {
    bool is64 = (mpos[1] == 0) & (mpos[3] == 0) & (mpos[5] == 0) & (mpos[7] == 0);
#pragma unroll
    for (int i = 0; i < 8; ++i) mp[i] = is64 ? mpos[2 * i] : mpos[i];
  }
  bool infull = false, inimg = false;
  int rel = 0;
#pragma unroll
  for (int s = 0; s < 2; ++s) {
    int off = mp[b * 4 + s * 2], ln = mp[b * 4 + s * 2 + 1];
    int mx = ln > 1 ? ln : 1;
    infull |= (l >= off) && (l < off + mx);
    bool ii = (l >= off + 1) && (l < off + ln);
    inimg |= ii;
    rel += ii ? (l - (off + 1)) : 0;
  }
  bool text = !infull;
  bool img = inimg && (rel < 1024);
  const float* w = isq ? qn : kn;
  float out[16];
  if (text) {
    int dp0 = d0 ^ 64;
    float sgn = (d0 < 64) ? -1.f : 1.f;
#pragma unroll
    for (int i = 0; i < 16; ++i) {
      int d = d0 + i, dp = dp0 + i;
      float c = cos1[(size_t)l * 128 + d];
      float s = sin1[(size_t)l * 128 + d];
      float xp = bf2f(base[dp]);
      out[i] = r * (xv[i] * w[d] * c + sgn * xp * w[dp] * s);
    }
  } else if (img) {
    const float* R = r3 + ((size_t)rel * 64 + (d0 >> 1)) * 4;
#pragma unroll
    for (int p = 0; p < 8; ++p) {
      float a = xv[2 * p] * w[d0 + 2 * p] * r;
      float c2 = xv[2 * p + 1] * w[d0 + 2 * p + 1] * r;
      out[2 * p] = a * R[4 * p + 0] + c2 * R[4 * p + 2];
      out[2 * p + 1] = a * R[4 * p + 1] + c2 * R[4 * p + 3];
    }
  } else {
#pragma unroll
    for (int i = 0; i < 16; ++i) out[i] = xv[i] * w[d0 + i] * r;
  }
  if (isq) {
    u16* dst = Q + ((size_t)(b * 16 + head) * 2048 + l) * 128 + d0;
#pragma unroll
    for (int i = 0; i < 16; ++i)
      dst[i] = f2bf(out[i] * (0.08838834764831845f * 1.4426950408889634f));
  } else {
    u16* dst = Kb + ((size_t)(b * 8 + head) * 2048 + l) * 128 + d0;
#pragma unroll
    for (int i = 0; i < 16; ++i) dst[i] = f2bf(out[i]);
  }
}

// ---------------------------------------------------------------------------
// 6) V^T: qkv[:, 3072+...] -> VT (B,KVH,Dh,L)
__global__ __launch_bounds__(256) void k_vtrans(const u16* __restrict__ qkv,
                                                u16* __restrict__ VT) {
  __shared__ u16 t[64][65];
  int bh = blockIdx.x;
  int l0 = blockIdx.y * 64, d0 = blockIdx.z * 64;
  int b = bh >> 3, kvh = bh & 7;
  int tx = threadIdx.x & 63, tg = threadIdx.x >> 6;
#pragma unroll
  for (int i = 0; i < 16; ++i) {
    int li = tg + i * 4;
    t[li][tx] = qkv[(size_t)(b * 2048 + l0 + li) * 4096 + 3072 + kvh * 128 + d0 + tx];
  }
  __syncthreads();
#pragma unroll
  for (int i = 0; i < 16; ++i) {
    int di = tg + i * 4;
    VT[((size_t)bh * 128 + d0 + di) * 2048 + l0 + tx] = t[tx][di];
  }
}

// ---------------------------------------------------------------------------
// 7) flash attention v2, depth-1 pipelined, shuffle-free softmax common path:
//   - per-lane partial row-sum (lpart), cross-lane reduced ONCE at the end
//   - row-max cross-lane reduce only when the defer-max gate trips
//   grid (L/128, B*H), 512 threads (8 waves x 16 q-rows), BQ=128, BKV=64.
//   LDS = 2*16K (Ks) + 2*16K (Vs) + 16K (Ps) = 80 KB -> 2 blocks/CU.
__global__ __launch_bounds__(512, 4) void k_attn(
    const u16* __restrict__ Q, const u16* __restrict__ Kb,
    const u16* __restrict__ VT, u16* __restrict__ O) {
  __shared__ u16 Ks[2][64 * 128];  // kv x dh, swizzled
  __shared__ u16 Vs[2][128 * 64];  // dh x kv, swizzled
  __shared__ u16 Ps[128 * 64];     // q x kv, swizzled (wave-private stripes)
  int tid = threadIdx.x;
  int wave = tid >> 6, lane = tid & 63, quad = lane >> 4, l16 = lane & 15;
  int bh = blockIdx.y;
  int b = bh >> 4, h = bh & 15, kvh = h >> 1;
  int q0 = blockIdx.x * 128;
  const u16* Qb = Q + ((size_t)bh * 2048 + q0 + wave * 16) * 128;
  short8 qf[4];
#pragma unroll
  for (int ks = 0; ks < 4; ++ks)
    qf[ks] = *(const short8*)(Qb + l16 * 128 + ks * 32 + quad * 8);
  const u16* Kg = Kb + (size_t)(b * 8 + kvh) * 2048 * 128;
  const u16* Vg = VT + (size_t)(b * 8 + kvh) * 128 * 2048;
  float mrow[4], lpart[4];
  fx4 of[8] = {};
#pragma unroll
  for (int r = 0; r < 4; ++r) {
    mrow[r] = -INFINITY;
    lpart[r] = 0.f;
  }
  // staging offsets (swizzled global source; LDS dst stays linear)
  size_t kgo[2], vgo[2];
#pragma unroll
  for (int i = 0; i < 2; ++i) {
    int kr = i * 32 + wave * 4 + (lane >> 4);  // local kv row
    kgo[i] = (size_t)kr * 128 + (((lane & 15) ^ (kr & 15)) * 8);
    int vr = i * 64 + wave * 8 + (lane >> 3);  // dh row
    vgo[i] = (size_t)vr * 2048 + (((lane & 7) ^ (vr & 7)) * 8);
  }

  auto STAGE = [&](int t, int buf) {
    size_t ko = (size_t)t * 8192;  // t*64 rows * 128
    size_t vo = (size_t)t * 64;    // t*64 cols
#pragma unroll
    for (int i = 0; i < 2; ++i) {
      GLD16(Kg + ko + kgo[i], &Ks[buf][i * 4096 + wave * 512]);
      GLD16(Vg + vo + vgo[i], &Vs[buf][i * 4096 + wave * 512]);
    }
  };

  auto COMPUTE = [&](int buf) {
    fx4 sf[4] = {};
    __builtin_amdgcn_s_setprio(1);
#pragma unroll
    for (int ct = 0; ct < 4; ++ct) {
#pragma unroll
      for (int ks = 0; ks < 4; ++ks) {
        short8 kf = *(const short8*)&Ks[buf][(ct * 16 + l16) * 128 +
                                            (((ks * 4 + quad) ^ l16) * 8)];
        sf[ct] = mfma16(qf[ks], kf, sf[ct]);
      }
    }
    __builtin_amdgcn_s_setprio(0);
    // per-lane local max; cross-lane reduce only when gate trips (rare)
    float cmv[4];
    bool need = false;
#pragma unroll
    for (int r = 0; r < 4; ++r) {
      cmv[r] = fmaxf(fmaxf(sf[0][r], sf[1][r]), fmaxf(sf[2][r], sf[3][r]));
      need |= (cmv[r] > mrow[r] + 8.0f);
    }
    if (__any(need)) {  // T13 defer-max: P bounded by 2^8
#pragma unroll
      for (int r = 0; r < 4; ++r) {
        float cm = cmv[r];
        cm = fmaxf(cm, __shfl_xor(cm, 1));
        cm = fmaxf(cm, __shfl_xor(cm, 2));
        cm = fmaxf(cm, __shfl_xor(cm, 4));
        cm = fmaxf(cm, __shfl_xor(cm, 8));
        float mn = fmaxf(mrow[r], cm);
        float al = exp2v(mrow[r] - mn);
        mrow[r] = mn;
        lpart[r] *= al;
#pragma unroll
        for (int c2 = 0; c2 < 8; ++c2) of[c2][r] *= al;
      }
    }
    int hb = l16 >> 3;
#pragma unroll
    for (int r = 0; r < 4; ++r) {
      float p0 = exp2v(sf[0][r] - mrow[r]);
      float p1 = exp2v(sf[1][r] - mrow[r]);
      float p2 = exp2v(sf[2][r] - mrow[r]);
      float p3 = exp2v(sf[3][r] - mrow[r]);
      lpart[r] += (p0 + p1) + (p2 + p3);  // per-lane partial; no shuffles
      int prow = wave * 16 + quad * 4 + r;
      int pb = prow * 64, px = prow & 7, lo = l16 & 7;
      Ps[pb + ((0 + hb) ^ px) * 8 + lo] = f2bf(p0);
      Ps[pb + ((2 + hb) ^ px) * 8 + lo] = f2bf(p1);
      Ps[pb + ((4 + hb) ^ px) * 8 + lo] = f2bf(p2);
      Ps[pb + ((6 + hb) ^ px) * 8 + lo] = f2bf(p3);
    }
    __builtin_amdgcn_s_setprio(1);
#pragma unroll
    for (int ks2 = 0; ks2 < 2; ++ks2) {
      int rsl = (((ks2 * 4 + quad) ^ (l16 & 7)) * 8);
      short8 pa = *(const short8*)&Ps[(wave * 16 + l16) * 64 + rsl];
#pragma unroll
      for (int c2 = 0; c2 < 8; ++c2) {
        short8 vb = *(const short8*)&Vs[buf][(c2 * 16 + l16) * 64 + rsl];
        of[c2] = mfma16(pa, vb, of[c2]);
      }
    }
    __builtin_amdgcn_s_setprio(0);
  };

  STAGE(0, 0);
  WAIT_ALL();
  __builtin_amdgcn_s_barrier();
  int cur = 0;
  for (int t = 0; t < 31; ++t) {
    STAGE(t + 1, cur ^ 1);  // prefetch next tile; latency hides under compute
    COMPUTE(cur);
    WAIT_ALL();             // single drain per tile, AFTER compute
    __builtin_amdgcn_s_barrier();
    cur ^= 1;
  }
  COMPUTE(cur);

  // deferred cross-lane row-sum (once, not per tile)
#pragma unroll
  for (int r = 0; r < 4; ++r) {
    float ls = lpart[r];
    ls += __shfl_xor(ls, 1);
    ls += __shfl_xor(ls, 2);
    ls += __shfl_xor(ls, 4);
    ls += __shfl_xor(ls, 8);
    float inv = 1.0f / ls;
    int qrow = q0 + wave * 16 + quad * 4 + r;
#pragma unroll
    for (int c2 = 0; c2 < 8; ++c2)
      O[((size_t)b * 2048 + qrow) * 2048 + h * 128 + c2 * 16 + l16] =
          f2bf(of[c2][r] * inv);
  }
}

// ---------------------------------------------------------------------------
extern "C" void kernel_launch(void* const* d_in, const int* in_sizes, int n_in,
                              void* d_out, int out_size, void* d_ws, size_t ws_size,
                              hipStream_t stream) {
  (void)in_sizes; (void)n_in; (void)out_size; (void)ws_size;
  const float* hid  = (const float*)d_in[0];
  const float* temb = (const float*)d_in[1];
  const float* wln  = (const float*)d_in[2];
  const float* wmod = (const float*)d_in[3];
  const float* bmod = (const float*)d_in[4];
  const float* wq   = (const float*)d_in[5];
  const float* wk   = (const float*)d_in[6];
  const float* wv   = (const float*)d_in[7];
  const float* wo   = (const float*)d_in[8];
  const float* qn   = (const float*)d_in[9];
  const float* kn   = (const float*)d_in[10];
  const float* cos1 = (const float*)d_in[11];
  const float* sin1 = (const float*)d_in[12];
  const float* r3   = (const float*)d_in[13];
  const int*   mpos = (const int*)d_in[14];

  char* ws = (char*)d_ws;
  float* mod = (float*)(ws + 0);                 //  49,152 B
  u16* xm  = (u16*)(ws + 49152);                 //  16 MiB
  u16* wT  = (u16*)(ws + 16826368);              //  16 MiB (wq|wk|wv)^T bf16
  u16* woT = wT;                                 //  overlay after QKV GEMM
  u16* qkv = (u16*)(ws + 33603584);              //  32 MiB bf16 (B*L, 4096)
  u16* Qb  = (u16*)(ws + 67158016);              //  16 MiB (B,H,L,Dh)
  u16* Kv  = (u16*)(ws + 83935232);              //   8 MiB (B,KVH,L,Dh)
  u16* VT  = (u16*)(ws + 92323840);              //   8 MiB (B,KVH,Dh,L)
  u16* Ob  = qkv;                                //  overlay (qkv dead by then)

  dim3 b32(32, 8);
  k_silu_mod<<<96, 512, 0, stream>>>(temb, wmod, bmod, mod);
  k_tconv<<<dim3(64, 64), b32, 0, stream>>>(wq, wT, 2048, 2048);
  k_tconv<<<dim3(64, 32), b32, 0, stream>>>(wk, wT + (size_t)2048 * 2048, 1024, 2048);
  k_tconv<<<dim3(64, 32), b32, 0, stream>>>(wv, wT + (size_t)3072 * 2048, 1024, 2048);
  k_xm<<<4096, 256, 0, stream>>>(hid, wln, mod, xm);
  k_gemm<0><<<dim3(32, 32), 256, 0, stream>>>(xm, wT, qkv, nullptr, nullptr, 4096, 2048);
  k_tconv<<<dim3(64, 64), b32, 0, stream>>>(wo, woT, 2048, 2048);
  k_qknorm<<<4096, 192, 0, stream>>>(qkv, qn, kn, cos1, sin1, r3, mpos, Qb, Kv);
  k_vtrans<<<dim3(16, 32, 2), 256, 0, stream>>>(qkv, VT);
  k_attn<<<dim3(16, 32), 512, 0, stream>>>(Qb, Kv, VT, Ob);
  k_gemm<1><<<dim3(16, 32), 256, 0, stream>>>(Ob, woT, d_out, hid, mod, 2048, 2048);
}

// Round 5
// 475.517 us; speedup vs baseline: 1.2026x; 1.0250x over previous
//
#include <hip/hip_runtime.h>
#include <stdint.h>
#include <math.h>

typedef unsigned short u16;
typedef __attribute__((ext_vector_type(8))) short short8;
typedef __attribute__((ext_vector_type(4))) float fx4;
typedef __attribute__((ext_vector_type(4))) unsigned short u16x4;

#define DEV __device__ __forceinline__

DEV u16 f2bf(float f) {
  unsigned u = __builtin_bit_cast(unsigned, f);
  return (u16)((u + 0x7FFFu + ((u >> 16) & 1u)) >> 16);
}
DEV float bf2f(u16 h) { return __builtin_bit_cast(float, ((unsigned)h) << 16); }

DEV fx4 mfma16(short8 a, short8 b, fx4 c) {
  return __builtin_amdgcn_mfma_f32_16x16x32_bf16(a, b, c, 0, 0, 0);
}

#if __has_builtin(__builtin_amdgcn_exp2f)
DEV float exp2v(float x) { return __builtin_amdgcn_exp2f(x); }
#else
DEV float exp2v(float x) { return exp2f(x); }
#endif

// async global->LDS, 16B per lane. LDS dst = wave-uniform base + lane*16.
#define GLD16(g, l)                                                            \
  __builtin_amdgcn_global_load_lds(                                            \
      (const __attribute__((address_space(1))) void*)(g),                      \
      (__attribute__((address_space(3))) void*)(l), 16, 0, 0)

#define WAIT_ALL() asm volatile("s_waitcnt vmcnt(0) lgkmcnt(0)" ::: "memory")
#define WAIT_VM4() asm volatile("s_waitcnt vmcnt(4)" ::: "memory")
#define WAIT_VM0() asm volatile("s_waitcnt vmcnt(0)" ::: "memory")

// ---------------------------------------------------------------------------
// 1) mod = silu(temb) @ w_mod + b_mod   (2x2048 @ 2048x6144)
__global__ __launch_bounds__(512) void k_silu_mod(
    const float* __restrict__ temb, const float* __restrict__ wmod,
    const float* __restrict__ bmod, float* __restrict__ mod) {
  __shared__ float st[4096];
  __shared__ float red[8][2][64];
  int tid = threadIdx.x;
  for (int i = tid; i < 4096; i += 512) {
    float t = temb[i];
    st[i] = t / (1.0f + __expf(-t));
  }
  __syncthreads();
  int j = blockIdx.x * 64 + (tid & 63);
  int ks = tid >> 6;
  float a0 = 0.f, a1 = 0.f;
  for (int d = ks * 256; d < ks * 256 + 256; ++d) {
    float w = wmod[(size_t)d * 6144 + j];
    a0 += st[d] * w;
    a1 += st[2048 + d] * w;
  }
  red[ks][0][tid & 63] = a0;
  red[ks][1][tid & 63] = a1;
  __syncthreads();
  if (tid < 64) {
    float s0 = 0.f, s1 = 0.f;
#pragma unroll
    for (int i = 0; i < 8; ++i) {
      s0 += red[i][0][tid];
      s1 += red[i][1][tid];
    }
    mod[j] = s0 + bmod[j];
    mod[6144 + j] = s1 + bmod[j];
  }
}

// ---------------------------------------------------------------------------
// 2) xm = bf16( rmsnorm(hidden)*w_ln * (1+scale[b]) + shift[b] )
__global__ __launch_bounds__(256) void k_xm(
    const float* __restrict__ x, const float* __restrict__ wln,
    const float* __restrict__ mod, u16* __restrict__ xm) {
  int row = blockIdx.x;
  int b = row >> 11;
  const float* xr = x + (size_t)row * 2048;
  int tid = threadIdx.x;
  float4 v0 = ((const float4*)xr)[tid];
  float4 v1 = ((const float4*)xr)[tid + 256];
  float ss = v0.x * v0.x + v0.y * v0.y + v0.z * v0.z + v0.w * v0.w +
             v1.x * v1.x + v1.y * v1.y + v1.z * v1.z + v1.w * v1.w;
  for (int m = 1; m < 64; m <<= 1) ss += __shfl_xor(ss, m);
  __shared__ float red[4];
  if ((tid & 63) == 0) red[tid >> 6] = ss;
  __syncthreads();
  ss = red[0] + red[1] + red[2] + red[3];
  float r = rsqrtf(ss * (1.0f / 2048.0f) + 1e-5f);
  const float* mb = mod + (size_t)b * 6144;
#pragma unroll
  for (int c = 0; c < 2; ++c) {
    int j0 = (tid + c * 256) * 4;
    float4 xv = c ? v1 : v0;
    float4 sh = *(const float4*)(mb + j0);
    float4 sc = *(const float4*)(mb + 2048 + j0);
    float4 wl = *(const float4*)(wln + j0);
    u16x4 o;
    o.x = f2bf(xv.x * r * wl.x * (1.f + sc.x) + sh.x);
    o.y = f2bf(xv.y * r * wl.y * (1.f + sc.y) + sh.y);
    o.z = f2bf(xv.z * r * wl.z * (1.f + sc.z) + sh.z);
    o.w = f2bf(xv.w * r * wl.w * (1.f + sc.w) + sh.w);
    *(u16x4*)(xm + (size_t)row * 2048 + j0) = o;
  }
}

// ---------------------------------------------------------------------------
// 3) transpose-convert fp32 [K][cols] -> bf16 dst[n][K]
__global__ __launch_bounds__(256) void k_tconv(
    const float* __restrict__ src, u16* __restrict__ dst, int cols, int rows) {
  __shared__ float t[32][33];
  int kb = blockIdx.x * 32, nb = blockIdx.y * 32;
  int tx = threadIdx.x, ty = threadIdx.y;
#pragma unroll
  for (int i = 0; i < 4; ++i)
    t[ty + i * 8][tx] = src[(size_t)(kb + ty + i * 8) * cols + nb + tx];
  __syncthreads();
#pragma unroll
  for (int i = 0; i < 4; ++i)
    dst[(size_t)(nb + ty + i * 8) * rows + kb + tx] = f2bf(t[tx][ty + i * 8]);
}

// ---------------------------------------------------------------------------
// 4a) 256x256-tile GEMM for the QKV projection (C = bf16).
//   8 waves (2M x 4N), per-wave 128x64 output (acc[8][4]).
//   3-buffer LDS (96 KB), counted vmcnt(4): tile t's loads issued 2 compute
//   phases before use; ONE s_barrier per K-step (the barrier at iter t also
//   proves all waves finished COMPUTE(t-1), so buf (t-1)%3 == (t+2)%3 is
//   free to overwrite). Grid (N/256, M/256) = 256 blocks = 1/CU exactly.
__global__ __launch_bounds__(512, 1) void k_gemm256(
    const u16* __restrict__ A, const u16* __restrict__ Bt, u16* __restrict__ C,
    int N, int K) {
  __shared__ u16 As[3][256 * 32];
  __shared__ u16 Bs[3][256 * 32];
  int tid = threadIdx.x;
  int wave = tid >> 6, lane = tid & 63, quad = lane >> 4, l16 = lane & 15;
  // bijective XCD-chunk swizzle (nwg = 256, % 8 == 0)
  int gx = gridDim.x;
  int nwg = gx * gridDim.y;
  int lin = blockIdx.y * gx + blockIdx.x;
  int cpx = nwg >> 3;
  int swz = (lin & 7) * cpx + (lin >> 3);
  int m0 = (swz / gx) * 256, n0 = (swz % gx) * 256;
  int wm = (wave >> 2) * 128, wn = (wave & 3) * 64;
  fx4 acc[8][4] = {};
  int rowa = tid >> 2;                         // 0..127
  int chunk = (tid & 3) ^ ((rowa >> 1) & 3);   // swizzled source chunk
  int cola = chunk * 8;
  const u16* Ag = A + (size_t)(m0 + rowa) * K + cola;
  const u16* Bg = Bt + (size_t)(n0 + rowa) * K + cola;
  int sl = (quad ^ ((l16 >> 1) & 3)) * 8;      // swizzled read slot

  auto STAGE = [&](int k0, int buf) {
    u16* AsW = &As[buf][wave * 512];
    u16* BsW = &Bs[buf][wave * 512];
    GLD16(Ag + k0, AsW);
    GLD16(Ag + k0 + (size_t)128 * K, AsW + 4096);
    GLD16(Bg + k0, BsW);
    GLD16(Bg + k0 + (size_t)128 * K, BsW + 4096);
  };
  auto COMPUTE = [&](int buf) {
    short8 af[8], bfr[4];
#pragma unroll
    for (int i = 0; i < 8; ++i)
      af[i] = *(const short8*)&As[buf][(wm + i * 16 + l16) * 32 + sl];
#pragma unroll
    for (int j = 0; j < 4; ++j)
      bfr[j] = *(const short8*)&Bs[buf][(wn + j * 16 + l16) * 32 + sl];
#pragma unroll
    for (int i = 0; i < 8; ++i)
#pragma unroll
      for (int j = 0; j < 4; ++j) acc[i][j] = mfma16(af[i], bfr[j], acc[i][j]);
  };

  STAGE(0, 0);
  STAGE(32, 1);
  for (int t = 0; t < 62; ++t) {
    WAIT_VM4();                       // own tile-t loads done (4 newer stay in flight)
    __builtin_amdgcn_s_barrier();     // tile t in LDS everywhere; buf (t+2)%3 free
    STAGE((t + 2) * 32, (t + 2) % 3);
    COMPUTE(t % 3);
  }
  WAIT_VM4();                         // t = 62: tiles 62,63 outstanding -> wait 62
  __builtin_amdgcn_s_barrier();
  COMPUTE(2);                         // 62 % 3
  WAIT_VM0();                         // drain tile 63
  __builtin_amdgcn_s_barrier();
  COMPUTE(0);                         // 63 % 3

#pragma unroll
  for (int i = 0; i < 8; ++i) {
    int row = m0 + wm + i * 16 + quad * 4;
#pragma unroll
    for (int j = 0; j < 4; ++j) {
      int col = n0 + wn + j * 16 + l16;
#pragma unroll
      for (int r = 0; r < 4; ++r)
        C[(size_t)(row + r) * N + col] = f2bf(acc[i][j][r]);
    }
  }
}

// ---------------------------------------------------------------------------
// 4b) 128x128-tile GEMM with fused residual epilogue (used for the WO GEMM,
//   where the 256 tile would leave half the CUs idle). 3-buffer LDS (48 KB),
//   counted vmcnt(4), one barrier per K-step — same schedule as k_gemm256.
__global__ __launch_bounds__(256) void k_gemm(
    const u16* __restrict__ A, const u16* __restrict__ Bt, float* __restrict__ C,
    const float* __restrict__ hid, const float* __restrict__ mod, int N, int K) {
  __shared__ u16 As[3][128 * 32];
  __shared__ u16 Bs[3][128 * 32];
  int tid = threadIdx.x;
  int wave = tid >> 6, lane = tid & 63, quad = lane >> 4, l16 = lane & 15;
  int gx = gridDim.x;
  int nwg = gx * gridDim.y;
  int lin = blockIdx.y * gx + blockIdx.x;
  int cpx = nwg >> 3;
  int swz = (lin & 7) * cpx + (lin >> 3);
  int m0 = (swz / gx) * 128, n0 = (swz % gx) * 128;
  int wm = (wave >> 1) * 64, wn = (wave & 1) * 64;
  fx4 acc[4][4] = {};
  int rowa = tid >> 2;
  int chunk = (tid & 3) ^ ((rowa >> 1) & 3);
  int cola = chunk * 8;
  const u16* Ag = A + (size_t)(m0 + rowa) * K + cola;
  const u16* Bg = Bt + (size_t)(n0 + rowa) * K + cola;
  int sl = (quad ^ ((l16 >> 1) & 3)) * 8;

  auto STAGE = [&](int k0, int buf) {
    u16* AsW = &As[buf][wave * 512];
    u16* BsW = &Bs[buf][wave * 512];
    GLD16(Ag + k0, AsW);
    GLD16(Ag + k0 + (size_t)64 * K, AsW + 2048);
    GLD16(Bg + k0, BsW);
    GLD16(Bg + k0 + (size_t)64 * K, BsW + 2048);
  };
  auto COMPUTE = [&](int buf) {
    short8 af[4], bfr[4];
#pragma unroll
    for (int i = 0; i < 4; ++i) {
      af[i] = *(const short8*)&As[buf][(wm + i * 16 + l16) * 32 + sl];
      bfr[i] = *(const short8*)&Bs[buf][(wn + i * 16 + l16) * 32 + sl];
    }
#pragma unroll
    for (int i = 0; i < 4; ++i)
#pragma unroll
      for (int j = 0; j < 4; ++j) acc[i][j] = mfma16(af[i], bfr[j], acc[i][j]);
  };

  STAGE(0, 0);
  STAGE(32, 1);
  int nk = K >> 5;  // 64
  for (int t = 0; t < nk - 2; ++t) {
    WAIT_VM4();
    __builtin_amdgcn_s_barrier();
    STAGE((t + 2) * 32, (t + 2) % 3);
    COMPUTE(t % 3);
  }
  WAIT_VM4();
  __builtin_amdgcn_s_barrier();
  COMPUTE((nk - 2) % 3);
  WAIT_VM0();
  __builtin_amdgcn_s_barrier();
  COMPUTE((nk - 1) % 3);

#pragma unroll
  for (int i = 0; i < 4; ++i) {
    int row = m0 + wm + i * 16 + quad * 4;
#pragma unroll
    for (int j = 0; j < 4; ++j) {
      int col = n0 + wn + j * 16 + l16;
      int b = row >> 11;
      float g = mod[(size_t)b * 6144 + 4096 + col];
#pragma unroll
      for (int r = 0; r < 4; ++r)
        C[(size_t)(row + r) * N + col] =
            hid[(size_t)(row + r) * N + col] + g * acc[i][j][r];
    }
  }
}

// ---------------------------------------------------------------------------
// 5) QK rms-norm + mixed RoPE. Q pre-scaled by log2(e)/sqrt(Dh) so the
// attention softmax can run entirely in exp2 domain (bare v_exp_f32).
__global__ __launch_bounds__(192) void k_qknorm(
    const u16* __restrict__ qkv, const float* __restrict__ qn,
    const float* __restrict__ kn, const float* __restrict__ cos1,
    const float* __restrict__ sin1, const float* __restrict__ r3,
    const int* __restrict__ mpos, u16* __restrict__ Q, u16* __restrict__ Kb) {
  int bx = blockIdx.x;
  int b = bx >> 11, l = bx & 2047;
  int tid = threadIdx.x;
  int slot = tid >> 3, sub = tid & 7;
  bool isq = slot < 16;
  int head = isq ? slot : slot - 16;
  const u16* base = qkv + (size_t)bx * 4096 + (isq ? slot * 128 : 2048 + head * 128);
  int d0 = sub * 16;
  float xv[16];
#pragma unroll
  for (int i = 0; i < 16; ++i) xv[i] = bf2f(base[d0 + i]);
  float ss = 0.f;
#pragma unroll
  for (int i = 0; i < 16; ++i) ss += xv[i] * xv[i];
  ss += __shfl_xor(ss, 1);
  ss += __shfl_xor(ss, 2);
  ss += __shfl_xor(ss, 4);
  float r = rsqrtf(ss * (1.0f / 128.0f) + 1e-5f);
  int mp[8];
  {
    bool is64 = (mpos[1] == 0) & (mpos[3] == 0) & (mpos[5] == 0) & (mpos[7] == 0);
#pragma unroll
    for (int i = 0; i < 8; ++i) mp[i] = is64 ? mpos[2 * i] : mpos[i];
  }
  bool infull = false, inimg = false;
  int rel = 0;
#pragma unroll
  for (int s = 0; s < 2; ++s) {
    int off = mp[b * 4 + s * 2], ln = mp[b * 4 + s * 2 + 1];
    int mx = ln > 1 ? ln : 1;
    infull |= (l >= off) && (l < off + mx);
    bool ii = (l >= off + 1) && (l < off + ln);
    inimg |= ii;
    rel += ii ? (l - (off + 1)) : 0;
  }
  bool text = !infull;
  bool img = inimg && (rel < 1024);
  const float* w = isq ? qn : kn;
  float out[16];
  if (text) {
    int dp0 = d0 ^ 64;
    float sgn = (d0 < 64) ? -1.f : 1.f;
#pragma unroll
    for (int i = 0; i < 16; ++i) {
      int d = d0 + i, dp = dp0 + i;
      float c = cos1[(size_t)l * 128 + d];
      float s = sin1[(size_t)l * 128 + d];
      float xp = bf2f(base[dp]);
      out[i] = r * (xv[i] * w[d] * c + sgn * xp * w[dp] * s);
    }
  } else if (img) {
    const float* R = r3 + ((size_t)rel * 64 + (d0 >> 1)) * 4;
#pragma unroll
    for (int p = 0; p < 8; ++p) {
      float a = xv[2 * p] * w[d0 + 2 * p] * r;
      float c2 = xv[2 * p + 1] * w[d0 + 2 * p + 1] * r;
      out[2 * p] = a * R[4 * p + 0] + c2 * R[4 * p + 2];
      out[2 * p + 1] = a * R[4 * p + 1] + c2 * R[4 * p + 3];
    }
  } else {
#pragma unroll
    for (int i = 0; i < 16; ++i) out[i] = xv[i] * w[d0 + i] * r;
  }
  if (isq) {
    u16* dst = Q + ((size_t)(b * 16 + head) * 2048 + l) * 128 + d0;
#pragma unroll
    for (int i = 0; i < 16; ++i)
      dst[i] = f2bf(out[i] * (0.08838834764831845f * 1.4426950408889634f));
  } else {
    u16* dst = Kb + ((size_t)(b * 8 + head) * 2048 + l) * 128 + d0;
#pragma unroll
    for (int i = 0; i < 16; ++i) dst[i] = f2bf(out[i]);
  }
}

// ---------------------------------------------------------------------------
// 6) V^T: qkv[:, 3072+...] -> VT (B,KVH,Dh,L)
__global__ __launch_bounds__(256) void k_vtrans(const u16* __restrict__ qkv,
                                                u16* __restrict__ VT) {
  __shared__ u16 t[64][65];
  int bh = blockIdx.x;
  int l0 = blockIdx.y * 64, d0 = blockIdx.z * 64;
  int b = bh >> 3, kvh = bh & 7;
  int tx = threadIdx.x & 63, tg = threadIdx.x >> 6;
#pragma unroll
  for (int i = 0; i < 16; ++i) {
    int li = tg + i * 4;
    t[li][tx] = qkv[(size_t)(b * 2048 + l0 + li) * 4096 + 3072 + kvh * 128 + d0 + tx];
  }
  __syncthreads();
#pragma unroll
  for (int i = 0; i < 16; ++i) {
    int di = tg + i * 4;
    VT[((size_t)bh * 128 + d0 + di) * 2048 + l0 + tx] = t[tx][di];
  }
}

// ---------------------------------------------------------------------------
// 7) flash attention v2, depth-1 pipelined, shuffle-free softmax common path:
//   - per-lane partial row-sum (lpart), cross-lane reduced ONCE at the end
//   - row-max cross-lane reduce only when the defer-max gate trips
//   grid (L/128, B*H), 512 threads (8 waves x 16 q-rows), BQ=128, BKV=64.
//   LDS = 2*16K (Ks) + 2*16K (Vs) + 16K (Ps) = 80 KB -> 2 blocks/CU.
__global__ __launch_bounds__(512, 4) void k_attn(
    const u16* __restrict__ Q, const u16* __restrict__ Kb,
    const u16* __restrict__ VT, u16* __restrict__ O) {
  __shared__ u16 Ks[2][64 * 128];  // kv x dh, swizzled
  __shared__ u16 Vs[2][128 * 64];  // dh x kv, swizzled
  __shared__ u16 Ps[128 * 64];     // q x kv, swizzled (wave-private stripes)
  int tid = threadIdx.x;
  int wave = tid >> 6, lane = tid & 63, quad = lane >> 4, l16 = lane & 15;
  int bh = blockIdx.y;
  int b = bh >> 4, h = bh & 15, kvh = h >> 1;
  int q0 = blockIdx.x * 128;
  const u16* Qb = Q + ((size_t)bh * 2048 + q0 + wave * 16) * 128;
  short8 qf[4];
#pragma unroll
  for (int ks = 0; ks < 4; ++ks)
    qf[ks] = *(const short8*)(Qb + l16 * 128 + ks * 32 + quad * 8);
  const u16* Kg = Kb + (size_t)(b * 8 + kvh) * 2048 * 128;
  const u16* Vg = VT + (size_t)(b * 8 + kvh) * 128 * 2048;
  float mrow[4], lpart[4];
  fx4 of[8] = {};
#pragma unroll
  for (int r = 0; r < 4; ++r) {
    mrow[r] = -INFINITY;
    lpart[r] = 0.f;
  }
  // staging offsets (swizzled global source; LDS dst stays linear)
  size_t kgo[2], vgo[2];
#pragma unroll
  for (int i = 0; i < 2; ++i) {
    int kr = i * 32 + wave * 4 + (lane >> 4);  // local kv row
    kgo[i] = (size_t)kr * 128 + (((lane & 15) ^ (kr & 15)) * 8);
    int vr = i * 64 + wave * 8 + (lane >> 3);  // dh row
    vgo[i] = (size_t)vr * 2048 + (((lane & 7) ^ (vr & 7)) * 8);
  }

  auto STAGE = [&](int t, int buf) {
    size_t ko = (size_t)t * 8192;  // t*64 rows * 128
    size_t vo = (size_t)t * 64;    // t*64 cols
#pragma unroll
    for (int i = 0; i < 2; ++i) {
      GLD16(Kg + ko + kgo[i], &Ks[buf][i * 4096 + wave * 512]);
      GLD16(Vg + vo + vgo[i], &Vs[buf][i * 4096 + wave * 512]);
    }
  };

  auto COMPUTE = [&](int buf) {
    fx4 sf[4] = {};
    __builtin_amdgcn_s_setprio(1);
#pragma unroll
    for (int ct = 0; ct < 4; ++ct) {
#pragma unroll
      for (int ks = 0; ks < 4; ++ks) {
        short8 kf = *(const short8*)&Ks[buf][(ct * 16 + l16) * 128 +
                                            (((ks * 4 + quad) ^ l16) * 8)];
        sf[ct] = mfma16(qf[ks], kf, sf[ct]);
      }
    }
    __builtin_amdgcn_s_setprio(0);
    // per-lane local max; cross-lane reduce only when gate trips (rare)
    float cmv[4];
    bool need = false;
#pragma unroll
    for (int r = 0; r < 4; ++r) {
      cmv[r] = fmaxf(fmaxf(sf[0][r], sf[1][r]), fmaxf(sf[2][r], sf[3][r]));
      need |= (cmv[r] > mrow[r] + 8.0f);
    }
    if (__any(need)) {  // T13 defer-max: P bounded by 2^8
#pragma unroll
      for (int r = 0; r < 4; ++r) {
        float cm = cmv[r];
        cm = fmaxf(cm, __shfl_xor(cm, 1));
        cm = fmaxf(cm, __shfl_xor(cm, 2));
        cm = fmaxf(cm, __shfl_xor(cm, 4));
        cm = fmaxf(cm, __shfl_xor(cm, 8));
        float mn = fmaxf(mrow[r], cm);
        float al = exp2v(mrow[r] - mn);
        mrow[r] = mn;
        lpart[r] *= al;
#pragma unroll
        for (int c2 = 0; c2 < 8; ++c2) of[c2][r] *= al;
      }
    }
    int hb = l16 >> 3;
#pragma unroll
    for (int r = 0; r < 4; ++r) {
      float p0 = exp2v(sf[0][r] - mrow[r]);
      float p1 = exp2v(sf[1][r] - mrow[r]);
      float p2 = exp2v(sf[2][r] - mrow[r]);
      float p3 = exp2v(sf[3][r] - mrow[r]);
      lpart[r] += (p0 + p1) + (p2 + p3);  // per-lane partial; no shuffles
      int prow = wave * 16 + quad * 4 + r;
      int pb = prow * 64, px = prow & 7, lo = l16 & 7;
      Ps[pb + ((0 + hb) ^ px) * 8 + lo] = f2bf(p0);
      Ps[pb + ((2 + hb) ^ px) * 8 + lo] = f2bf(p1);
      Ps[pb + ((4 + hb) ^ px) * 8 + lo] = f2bf(p2);
      Ps[pb + ((6 + hb) ^ px) * 8 + lo] = f2bf(p3);
    }
    __builtin_amdgcn_s_setprio(1);
#pragma unroll
    for (int ks2 = 0; ks2 < 2; ++ks2) {
      int rsl = (((ks2 * 4 + quad) ^ (l16 & 7)) * 8);
      short8 pa = *(const short8*)&Ps[(wave * 16 + l16) * 64 + rsl];
#pragma unroll
      for (int c2 = 0; c2 < 8; ++c2) {
        short8 vb = *(const short8*)&Vs[buf][(c2 * 16 + l16) * 64 + rsl];
        of[c2] = mfma16(pa, vb, of[c2]);
      }
    }
    __builtin_amdgcn_s_setprio(0);
  };

  STAGE(0, 0);
  WAIT_ALL();
  __builtin_amdgcn_s_barrier();
  int cur = 0;
  for (int t = 0; t < 31; ++t) {
    STAGE(t + 1, cur ^ 1);  // prefetch next tile; latency hides under compute
    COMPUTE(cur);
    WAIT_ALL();             // single drain per tile, AFTER compute
    __builtin_amdgcn_s_barrier();
    cur ^= 1;
  }
  COMPUTE(cur);

  // deferred cross-lane row-sum (once, not per tile)
#pragma unroll
  for (int r = 0; r < 4; ++r) {
    float ls = lpart[r];
    ls += __shfl_xor(ls, 1);
    ls += __shfl_xor(ls, 2);
    ls += __shfl_xor(ls, 4);
    ls += __shfl_xor(ls, 8);
    float inv = 1.0f / ls;
    int qrow = q0 + wave * 16 + quad * 4 + r;
#pragma unroll
    for (int c2 = 0; c2 < 8; ++c2)
      O[((size_t)b * 2048 + qrow) * 2048 + h * 128 + c2 * 16 + l16] =
          f2bf(of[c2][r] * inv);
  }
}

// ---------------------------------------------------------------------------
extern "C" void kernel_launch(void* const* d_in, const int* in_sizes, int n_in,
                              void* d_out, int out_size, void* d_ws, size_t ws_size,
                              hipStream_t stream) {
  (void)in_sizes; (void)n_in; (void)out_size; (void)ws_size;
  const float* hid  = (const float*)d_in[0];
  const float* temb = (const float*)d_in[1];
  const float* wln  = (const float*)d_in[2];
  const float* wmod = (const float*)d_in[3];
  const float* bmod = (const float*)d_in[4];
  const float* wq   = (const float*)d_in[5];
  const float* wk   = (const float*)d_in[6];
  const float* wv   = (const float*)d_in[7];
  const float* wo   = (const float*)d_in[8];
  const float* qn   = (const float*)d_in[9];
  const float* kn   = (const float*)d_in[10];
  const float* cos1 = (const float*)d_in[11];
  const float* sin1 = (const float*)d_in[12];
  const float* r3   = (const float*)d_in[13];
  const int*   mpos = (const int*)d_in[14];

  char* ws = (char*)d_ws;
  float* mod = (float*)(ws + 0);                 //  49,152 B
  u16* xm  = (u16*)(ws + 49152);                 //  16 MiB
  u16* wT  = (u16*)(ws + 16826368);              //  16 MiB (wq|wk|wv)^T bf16
  u16* woT = wT;                                 //  overlay after QKV GEMM
  u16* qkv = (u16*)(ws + 33603584);              //  32 MiB bf16 (B*L, 4096)
  u16* Qb  = (u16*)(ws + 67158016);              //  16 MiB (B,H,L,Dh)
  u16* Kv  = (u16*)(ws + 83935232);              //   8 MiB (B,KVH,L,Dh)
  u16* VT  = (u16*)(ws + 92323840);              //   8 MiB (B,KVH,Dh,L)
  u16* Ob  = qkv;                                //  overlay (qkv dead by then)

  dim3 b32(32, 8);
  k_silu_mod<<<96, 512, 0, stream>>>(temb, wmod, bmod, mod);
  k_tconv<<<dim3(64, 64), b32, 0, stream>>>(wq, wT, 2048, 2048);
  k_tconv<<<dim3(64, 32), b32, 0, stream>>>(wk, wT + (size_t)2048 * 2048, 1024, 2048);
  k_tconv<<<dim3(64, 32), b32, 0, stream>>>(wv, wT + (size_t)3072 * 2048, 1024, 2048);
  k_xm<<<4096, 256, 0, stream>>>(hid, wln, mod, xm);
  k_gemm256<<<dim3(16, 16), 512, 0, stream>>>(xm, wT, qkv, 4096, 2048);
  k_tconv<<<dim3(64, 64), b32, 0, stream>>>(wo, woT, 2048, 2048);
  k_qknorm<<<4096, 192, 0, stream>>>(qkv, qn, kn, cos1, sin1, r3, mpos, Qb, Kv);
  k_vtrans<<<dim3(16, 32, 2), 256, 0, stream>>>(qkv, VT);
  k_attn<<<dim3(16, 32), 512, 0, stream>>>(Qb, Kv, VT, Ob);
  k_gemm<<<dim3(16, 32), 256, 0, stream>>>(Ob, woT, (float*)d_out, hid, mod, 2048, 2048);
}

// Round 6
// 471.129 us; speedup vs baseline: 1.2138x; 1.0093x over previous
//
#include <hip/hip_runtime.h>
#include <hip/hip_bf16.h>
#include <stdint.h>
#include <math.h>

typedef unsigned short u16;
typedef __attribute__((ext_vector_type(8))) short short8;
typedef __attribute__((ext_vector_type(4))) float fx4;
typedef __attribute__((ext_vector_type(4))) unsigned short u16x4;

#define DEV __device__ __forceinline__

DEV u16 f2bf(float f) {  // hardware v_cvt_pk_bf16_f32 (RTNE)
  return __builtin_bit_cast(u16, __float2bfloat16(f));
}
DEV float bf2f(u16 h) { return __builtin_bit_cast(float, ((unsigned)h) << 16); }

DEV fx4 mfma16(short8 a, short8 b, fx4 c) {
  return __builtin_amdgcn_mfma_f32_16x16x32_bf16(a, b, c, 0, 0, 0);
}

#if __has_builtin(__builtin_amdgcn_exp2f)
DEV float exp2v(float x) { return __builtin_amdgcn_exp2f(x); }
#else
DEV float exp2v(float x) { return exp2f(x); }
#endif

// async global->LDS, 16B per lane. LDS dst = wave-uniform base + lane*16.
#define GLD16(g, l)                                                            \
  __builtin_amdgcn_global_load_lds(                                            \
      (const __attribute__((address_space(1))) void*)(g),                      \
      (__attribute__((address_space(3))) void*)(l), 16, 0, 0)

#define WAIT_ALL() asm volatile("s_waitcnt vmcnt(0) lgkmcnt(0)" ::: "memory")
#define WAIT_VM4() asm volatile("s_waitcnt vmcnt(4)" ::: "memory")
#define WAIT_VM0() asm volatile("s_waitcnt vmcnt(0)" ::: "memory")

// ---------------------------------------------------------------------------
// 1) mod = silu(temb) @ w_mod + b_mod   (2x2048 @ 2048x6144)
__global__ __launch_bounds__(512) void k_silu_mod(
    const float* __restrict__ temb, const float* __restrict__ wmod,
    const float* __restrict__ bmod, float* __restrict__ mod) {
  __shared__ float st[4096];
  __shared__ float red[8][2][64];
  int tid = threadIdx.x;
  for (int i = tid; i < 4096; i += 512) {
    float t = temb[i];
    st[i] = t / (1.0f + __expf(-t));
  }
  __syncthreads();
  int j = blockIdx.x * 64 + (tid & 63);
  int ks = tid >> 6;
  float a0 = 0.f, a1 = 0.f;
  for (int d = ks * 256; d < ks * 256 + 256; ++d) {
    float w = wmod[(size_t)d * 6144 + j];
    a0 += st[d] * w;
    a1 += st[2048 + d] * w;
  }
  red[ks][0][tid & 63] = a0;
  red[ks][1][tid & 63] = a1;
  __syncthreads();
  if (tid < 64) {
    float s0 = 0.f, s1 = 0.f;
#pragma unroll
    for (int i = 0; i < 8; ++i) {
      s0 += red[i][0][tid];
      s1 += red[i][1][tid];
    }
    mod[j] = s0 + bmod[j];
    mod[6144 + j] = s1 + bmod[j];
  }
}

// ---------------------------------------------------------------------------
// 2) xm = bf16( rmsnorm(hidden)*w_ln * (1+scale[b]) + shift[b] )
__global__ __launch_bounds__(256) void k_xm(
    const float* __restrict__ x, const float* __restrict__ wln,
    const float* __restrict__ mod, u16* __restrict__ xm) {
  int row = blockIdx.x;
  int b = row >> 11;
  const float* xr = x + (size_t)row * 2048;
  int tid = threadIdx.x;
  float4 v0 = ((const float4*)xr)[tid];
  float4 v1 = ((const float4*)xr)[tid + 256];
  float ss = v0.x * v0.x + v0.y * v0.y + v0.z * v0.z + v0.w * v0.w +
             v1.x * v1.x + v1.y * v1.y + v1.z * v1.z + v1.w * v1.w;
  for (int m = 1; m < 64; m <<= 1) ss += __shfl_xor(ss, m);
  __shared__ float red[4];
  if ((tid & 63) == 0) red[tid >> 6] = ss;
  __syncthreads();
  ss = red[0] + red[1] + red[2] + red[3];
  float r = rsqrtf(ss * (1.0f / 2048.0f) + 1e-5f);
  const float* mb = mod + (size_t)b * 6144;
#pragma unroll
  for (int c = 0; c < 2; ++c) {
    int j0 = (tid + c * 256) * 4;
    float4 xv = c ? v1 : v0;
    float4 sh = *(const float4*)(mb + j0);
    float4 sc = *(const float4*)(mb + 2048 + j0);
    float4 wl = *(const float4*)(wln + j0);
    u16x4 o;
    o.x = f2bf(xv.x * r * wl.x * (1.f + sc.x) + sh.x);
    o.y = f2bf(xv.y * r * wl.y * (1.f + sc.y) + sh.y);
    o.z = f2bf(xv.z * r * wl.z * (1.f + sc.z) + sh.z);
    o.w = f2bf(xv.w * r * wl.w * (1.f + sc.w) + sh.w);
    *(u16x4*)(xm + (size_t)row * 2048 + j0) = o;
  }
}

// ---------------------------------------------------------------------------
// 3) transpose-convert fp32 [K][cols] -> bf16 dst[n][K]; vectorized u16x4 store
__global__ __launch_bounds__(256) void k_tconv(
    const float* __restrict__ src, u16* __restrict__ dst, int cols, int rows) {
  __shared__ float t[32][33];
  int kb = blockIdx.x * 32, nb = blockIdx.y * 32;
  int tx = threadIdx.x, ty = threadIdx.y;
#pragma unroll
  for (int i = 0; i < 4; ++i)
    t[ty + i * 8][tx] = src[(size_t)(kb + ty + i * 8) * cols + nb + tx];
  __syncthreads();
  int nl = ty * 4 + (tx >> 3);  // 0..31 output row (n)
  int k4 = (tx & 7) * 4;        // 0..28 k quad
  u16x4 v;
#pragma unroll
  for (int j = 0; j < 4; ++j) v[j] = f2bf(t[k4 + j][nl]);
  *(u16x4*)(dst + (size_t)(nb + nl) * rows + kb + k4) = v;
}

// ---------------------------------------------------------------------------
// 4a) 256x256-tile GEMM for the QKV projection (C = bf16).
//   8 waves (2M x 4N), 3-buffer LDS (96 KB), counted vmcnt(4), one barrier
//   per K-step. Grid (N/256, M/256) = 256 blocks = 1/CU exactly.
__global__ __launch_bounds__(512, 1) void k_gemm256(
    const u16* __restrict__ A, const u16* __restrict__ Bt, u16* __restrict__ C,
    int N, int K) {
  __shared__ u16 As[3][256 * 32];
  __shared__ u16 Bs[3][256 * 32];
  int tid = threadIdx.x;
  int wave = tid >> 6, lane = tid & 63, quad = lane >> 4, l16 = lane & 15;
  int gx = gridDim.x;
  int nwg = gx * gridDim.y;
  int lin = blockIdx.y * gx + blockIdx.x;
  int cpx = nwg >> 3;
  int swz = (lin & 7) * cpx + (lin >> 3);
  int m0 = (swz / gx) * 256, n0 = (swz % gx) * 256;
  int wm = (wave >> 2) * 128, wn = (wave & 3) * 64;
  fx4 acc[8][4] = {};
  int rowa = tid >> 2;                         // 0..127
  int chunk = (tid & 3) ^ ((rowa >> 1) & 3);   // swizzled source chunk
  int cola = chunk * 8;
  const u16* Ag = A + (size_t)(m0 + rowa) * K + cola;
  const u16* Bg = Bt + (size_t)(n0 + rowa) * K + cola;
  int sl = (quad ^ ((l16 >> 1) & 3)) * 8;      // swizzled read slot

  auto STAGE = [&](int k0, int buf) {
    u16* AsW = &As[buf][wave * 512];
    u16* BsW = &Bs[buf][wave * 512];
    GLD16(Ag + k0, AsW);
    GLD16(Ag + k0 + (size_t)128 * K, AsW + 4096);
    GLD16(Bg + k0, BsW);
    GLD16(Bg + k0 + (size_t)128 * K, BsW + 4096);
  };
  auto COMPUTE = [&](int buf) {
    short8 af[8], bfr[4];
#pragma unroll
    for (int i = 0; i < 8; ++i)
      af[i] = *(const short8*)&As[buf][(wm + i * 16 + l16) * 32 + sl];
#pragma unroll
    for (int j = 0; j < 4; ++j)
      bfr[j] = *(const short8*)&Bs[buf][(wn + j * 16 + l16) * 32 + sl];
#pragma unroll
    for (int i = 0; i < 8; ++i)
#pragma unroll
      for (int j = 0; j < 4; ++j) acc[i][j] = mfma16(af[i], bfr[j], acc[i][j]);
  };

  STAGE(0, 0);
  STAGE(32, 1);
  for (int t = 0; t < 62; ++t) {
    WAIT_VM4();
    __builtin_amdgcn_s_barrier();
    STAGE((t + 2) * 32, (t + 2) % 3);
    COMPUTE(t % 3);
  }
  WAIT_VM4();
  __builtin_amdgcn_s_barrier();
  COMPUTE(2);
  WAIT_VM0();
  __builtin_amdgcn_s_barrier();
  COMPUTE(0);

#pragma unroll
  for (int i = 0; i < 8; ++i) {
    int row = m0 + wm + i * 16 + quad * 4;
#pragma unroll
    for (int j = 0; j < 4; ++j) {
      int col = n0 + wn + j * 16 + l16;
#pragma unroll
      for (int r = 0; r < 4; ++r)
        C[(size_t)(row + r) * N + col] = f2bf(acc[i][j][r]);
    }
  }
}

// ---------------------------------------------------------------------------
// 4b) 128x128-tile GEMM with fused residual epilogue (WO GEMM).
//   3-buffer LDS (48 KB), counted vmcnt(4), one barrier per K-step.
__global__ __launch_bounds__(256) void k_gemm(
    const u16* __restrict__ A, const u16* __restrict__ Bt, float* __restrict__ C,
    const float* __restrict__ hid, const float* __restrict__ mod, int N, int K) {
  __shared__ u16 As[3][128 * 32];
  __shared__ u16 Bs[3][128 * 32];
  int tid = threadIdx.x;
  int wave = tid >> 6, lane = tid & 63, quad = lane >> 4, l16 = lane & 15;
  int gx = gridDim.x;
  int nwg = gx * gridDim.y;
  int lin = blockIdx.y * gx + blockIdx.x;
  int cpx = nwg >> 3;
  int swz = (lin & 7) * cpx + (lin >> 3);
  int m0 = (swz / gx) * 128, n0 = (swz % gx) * 128;
  int wm = (wave >> 1) * 64, wn = (wave & 1) * 64;
  fx4 acc[4][4] = {};
  int rowa = tid >> 2;
  int chunk = (tid & 3) ^ ((rowa >> 1) & 3);
  int cola = chunk * 8;
  const u16* Ag = A + (size_t)(m0 + rowa) * K + cola;
  const u16* Bg = Bt + (size_t)(n0 + rowa) * K + cola;
  int sl = (quad ^ ((l16 >> 1) & 3)) * 8;

  auto STAGE = [&](int k0, int buf) {
    u16* AsW = &As[buf][wave * 512];
    u16* BsW = &Bs[buf][wave * 512];
    GLD16(Ag + k0, AsW);
    GLD16(Ag + k0 + (size_t)64 * K, AsW + 2048);
    GLD16(Bg + k0, BsW);
    GLD16(Bg + k0 + (size_t)64 * K, BsW + 2048);
  };
  auto COMPUTE = [&](int buf) {
    short8 af[4], bfr[4];
#pragma unroll
    for (int i = 0; i < 4; ++i) {
      af[i] = *(const short8*)&As[buf][(wm + i * 16 + l16) * 32 + sl];
      bfr[i] = *(const short8*)&Bs[buf][(wn + i * 16 + l16) * 32 + sl];
    }
#pragma unroll
    for (int i = 0; i < 4; ++i)
#pragma unroll
      for (int j = 0; j < 4; ++j) acc[i][j] = mfma16(af[i], bfr[j], acc[i][j]);
  };

  STAGE(0, 0);
  STAGE(32, 1);
  int nk = K >> 5;  // 64
  for (int t = 0; t < nk - 2; ++t) {
    WAIT_VM4();
    __builtin_amdgcn_s_barrier();
    STAGE((t + 2) * 32, (t + 2) % 3);
    COMPUTE(t % 3);
  }
  WAIT_VM4();
  __builtin_amdgcn_s_barrier();
  COMPUTE((nk - 2) % 3);
  WAIT_VM0();
  __builtin_amdgcn_s_barrier();
  COMPUTE((nk - 1) % 3);

#pragma unroll
  for (int i = 0; i < 4; ++i) {
    int row = m0 + wm + i * 16 + quad * 4;
#pragma unroll
    for (int j = 0; j < 4; ++j) {
      int col = n0 + wn + j * 16 + l16;
      int b = row >> 11;
      float g = mod[(size_t)b * 6144 + 4096 + col];
#pragma unroll
      for (int r = 0; r < 4; ++r)
        C[(size_t)(row + r) * N + col] =
            hid[(size_t)(row + r) * N + col] + g * acc[i][j][r];
    }
  }
}

// ---------------------------------------------------------------------------
// 5) QK rms-norm + mixed RoPE — fully vectorized loads/stores (G13).
// Q pre-scaled by log2(e)/sqrt(Dh) for exp2-domain softmax.
__global__ __launch_bounds__(192) void k_qknorm(
    const u16* __restrict__ qkv, const float* __restrict__ qn,
    const float* __restrict__ kn, const float* __restrict__ cos1,
    const float* __restrict__ sin1, const float* __restrict__ r3,
    const int* __restrict__ mpos, u16* __restrict__ Q, u16* __restrict__ Kb) {
  int bx = blockIdx.x;
  int b = bx >> 11, l = bx & 2047;
  int tid = threadIdx.x;
  int slot = tid >> 3, sub = tid & 7;
  bool isq = slot < 16;
  int head = isq ? slot : slot - 16;
  const u16* base = qkv + (size_t)bx * 4096 + (isq ? slot * 128 : 2048 + head * 128);
  int d0 = sub * 16;
  short8 sx0 = *(const short8*)(base + d0);
  short8 sx1 = *(const short8*)(base + d0 + 8);
  float xv[16];
#pragma unroll
  for (int i = 0; i < 8; ++i) {
    xv[i] = bf2f((u16)sx0[i]);
    xv[8 + i] = bf2f((u16)sx1[i]);
  }
  float ss = 0.f;
#pragma unroll
  for (int i = 0; i < 16; ++i) ss += xv[i] * xv[i];
  ss += __shfl_xor(ss, 1);
  ss += __shfl_xor(ss, 2);
  ss += __shfl_xor(ss, 4);
  float r = rsqrtf(ss * (1.0f / 128.0f) + 1e-5f);
  int mp[8];
  {
    bool is64 = (mpos[1] == 0) & (mpos[3] == 0) & (mpos[5] == 0) & (mpos[7] == 0);
#pragma unroll
    for (int i = 0; i < 8; ++i) mp[i] = is64 ? mpos[2 * i] : mpos[i];
  }
  bool infull = false, inimg = false;
  int rel = 0;
#pragma unroll
  for (int s = 0; s < 2; ++s) {
    int off = mp[b * 4 + s * 2], ln = mp[b * 4 + s * 2 + 1];
    int mx = ln > 1 ? ln : 1;
    infull |= (l >= off) && (l < off + mx);
    bool ii = (l >= off + 1) && (l < off + ln);
    inimg |= ii;
    rel += ii ? (l - (off + 1)) : 0;
  }
  bool text = !infull;
  bool img = inimg && (rel < 1024);
  const float* w = isq ? qn : kn;
  fx4 wv[4];
#pragma unroll
  for (int q = 0; q < 4; ++q) wv[q] = *(const fx4*)(w + d0 + q * 4);
  float out[16];
  if (text) {
    int dp0 = d0 ^ 64;
    float sgn = (d0 < 64) ? -1.f : 1.f;
    short8 sp0 = *(const short8*)(base + dp0);
    short8 sp1 = *(const short8*)(base + dp0 + 8);
    fx4 cv[4], sv[4], wp[4];
#pragma unroll
    for (int q = 0; q < 4; ++q) {
      cv[q] = *(const fx4*)(cos1 + (size_t)l * 128 + d0 + q * 4);
      sv[q] = *(const fx4*)(sin1 + (size_t)l * 128 + d0 + q * 4);
      wp[q] = *(const fx4*)(w + dp0 + q * 4);
    }
#pragma unroll
    for (int i = 0; i < 16; ++i) {
      float xp = bf2f((u16)(i < 8 ? sp0[i & 7] : sp1[i & 7]));
      out[i] = r * (xv[i] * wv[i >> 2][i & 3] * cv[i >> 2][i & 3] +
                    sgn * xp * wp[i >> 2][i & 3] * sv[i >> 2][i & 3]);
    }
  } else if (img) {
    const fx4* Rv = (const fx4*)(r3 + ((size_t)rel * 64 + (d0 >> 1)) * 4);
#pragma unroll
    for (int p = 0; p < 8; ++p) {
      fx4 R = Rv[p];
      float a = xv[2 * p] * wv[(2 * p) >> 2][(2 * p) & 3] * r;
      float c2 = xv[2 * p + 1] * wv[(2 * p + 1) >> 2][(2 * p + 1) & 3] * r;
      out[2 * p] = a * R[0] + c2 * R[2];
      out[2 * p + 1] = a * R[1] + c2 * R[3];
    }
  } else {
#pragma unroll
    for (int i = 0; i < 16; ++i) out[i] = xv[i] * wv[i >> 2][i & 3] * r;
  }
  float qs = isq ? (0.08838834764831845f * 1.4426950408889634f) : 1.0f;
  short8 o0, o1;
#pragma unroll
  for (int i = 0; i < 8; ++i) {
    o0[i] = (short)f2bf(out[i] * qs);
    o1[i] = (short)f2bf(out[8 + i] * qs);
  }
  u16* dst = isq ? (Q + ((size_t)(b * 16 + head) * 2048 + l) * 128 + d0)
                 : (Kb + ((size_t)(b * 8 + head) * 2048 + l) * 128 + d0);
  *(short8*)dst = o0;
  *(short8*)(dst + 8) = o1;
}

// ---------------------------------------------------------------------------
// 6) V^T: qkv[:, 3072+...] -> VT (B,KVH,Dh,L); u16x4 vectorized both sides
__global__ __launch_bounds__(256) void k_vtrans(const u16* __restrict__ qkv,
                                                u16* __restrict__ VT) {
  __shared__ u16 t[64][65];
  int bh = blockIdx.x;
  int l0 = blockIdx.y * 64, d0 = blockIdx.z * 64;
  int b = bh >> 3, kvh = bh & 7;
  int tid = threadIdx.x;
  int lr = tid >> 4;        // 0..15
  int c4 = (tid & 15) * 4;  // 0..60
#pragma unroll
  for (int i = 0; i < 4; ++i) {
    int li = lr + i * 16;
    *(u16x4*)&t[li][c4] = *(const u16x4*)(
        qkv + (size_t)(b * 2048 + l0 + li) * 4096 + 3072 + kvh * 128 + d0 + c4);
  }
  __syncthreads();
#pragma unroll
  for (int i = 0; i < 4; ++i) {
    int di = lr + i * 16;
    u16x4 v;
    v[0] = t[c4 + 0][di];
    v[1] = t[c4 + 1][di];
    v[2] = t[c4 + 2][di];
    v[3] = t[c4 + 3][di];
    *(u16x4*)(VT + ((size_t)bh * 128 + d0 + di) * 2048 + l0 + c4) = v;
  }
}

// ---------------------------------------------------------------------------
// 7) flash attention v2, depth-1 pipelined, shuffle-free softmax common path.
__global__ __launch_bounds__(512, 4) void k_attn(
    const u16* __restrict__ Q, const u16* __restrict__ Kb,
    const u16* __restrict__ VT, u16* __restrict__ O) {
  __shared__ u16 Ks[2][64 * 128];  // kv x dh, swizzled
  __shared__ u16 Vs[2][128 * 64];  // dh x kv, swizzled
  __shared__ u16 Ps[128 * 64];     // q x kv, swizzled (wave-private stripes)
  int tid = threadIdx.x;
  int wave = tid >> 6, lane = tid & 63, quad = lane >> 4, l16 = lane & 15;
  int bh = blockIdx.y;
  int b = bh >> 4, h = bh & 15, kvh = h >> 1;
  int q0 = blockIdx.x * 128;
  const u16* Qb = Q + ((size_t)bh * 2048 + q0 + wave * 16) * 128;
  short8 qf[4];
#pragma unroll
  for (int ks = 0; ks < 4; ++ks)
    qf[ks] = *(const short8*)(Qb + l16 * 128 + ks * 32 + quad * 8);
  const u16* Kg = Kb + (size_t)(b * 8 + kvh) * 2048 * 128;
  const u16* Vg = VT + (size_t)(b * 8 + kvh) * 128 * 2048;
  float mrow[4], lpart[4];
  fx4 of[8] = {};
#pragma unroll
  for (int r = 0; r < 4; ++r) {
    mrow[r] = -INFINITY;
    lpart[r] = 0.f;
  }
  size_t kgo[2], vgo[2];
#pragma unroll
  for (int i = 0; i < 2; ++i) {
    int kr = i * 32 + wave * 4 + (lane >> 4);
    kgo[i] = (size_t)kr * 128 + (((lane & 15) ^ (kr & 15)) * 8);
    int vr = i * 64 + wave * 8 + (lane >> 3);
    vgo[i] = (size_t)vr * 2048 + (((lane & 7) ^ (vr & 7)) * 8);
  }

  auto STAGE = [&](int t, int buf) {
    size_t ko = (size_t)t * 8192;
    size_t vo = (size_t)t * 64;
#pragma unroll
    for (int i = 0; i < 2; ++i) {
      GLD16(Kg + ko + kgo[i], &Ks[buf][i * 4096 + wave * 512]);
      GLD16(Vg + vo + vgo[i], &Vs[buf][i * 4096 + wave * 512]);
    }
  };

  auto COMPUTE = [&](int buf) {
    fx4 sf[4] = {};
    __builtin_amdgcn_s_setprio(1);
#pragma unroll
    for (int ct = 0; ct < 4; ++ct) {
#pragma unroll
      for (int ks = 0; ks < 4; ++ks) {
        short8 kf = *(const short8*)&Ks[buf][(ct * 16 + l16) * 128 +
                                            (((ks * 4 + quad) ^ l16) * 8)];
        sf[ct] = mfma16(qf[ks], kf, sf[ct]);
      }
    }
    __builtin_amdgcn_s_setprio(0);
    float cmv[4];
    bool need = false;
#pragma unroll
    for (int r = 0; r < 4; ++r) {
      cmv[r] = fmaxf(fmaxf(sf[0][r], sf[1][r]), fmaxf(sf[2][r], sf[3][r]));
      need |= (cmv[r] > mrow[r] + 8.0f);
    }
    if (__any(need)) {  // T13 defer-max: P bounded by 2^8
#pragma unroll
      for (int r = 0; r < 4; ++r) {
        float cm = cmv[r];
        cm = fmaxf(cm, __shfl_xor(cm, 1));
        cm = fmaxf(cm, __shfl_xor(cm, 2));
        cm = fmaxf(cm, __shfl_xor(cm, 4));
        cm = fmaxf(cm, __shfl_xor(cm, 8));
        float mn = fmaxf(mrow[r], cm);
        float al = exp2v(mrow[r] - mn);
        mrow[r] = mn;
        lpart[r] *= al;
#pragma unroll
        for (int c2 = 0; c2 < 8; ++c2) of[c2][r] *= al;
      }
    }
    int hb = l16 >> 3;
#pragma unroll
    for (int r = 0; r < 4; ++r) {
      float p0 = exp2v(sf[0][r] - mrow[r]);
      float p1 = exp2v(sf[1][r] - mrow[r]);
      float p2 = exp2v(sf[2][r] - mrow[r]);
      float p3 = exp2v(sf[3][r] - mrow[r]);
      lpart[r] += (p0 + p1) + (p2 + p3);
      int prow = wave * 16 + quad * 4 + r;
      int pb = prow * 64, px = prow & 7, lo = l16 & 7;
      Ps[pb + ((0 + hb) ^ px) * 8 + lo] = f2bf(p0);
      Ps[pb + ((2 + hb) ^ px) * 8 + lo] = f2bf(p1);
      Ps[pb + ((4 + hb) ^ px) * 8 + lo] = f2bf(p2);
      Ps[pb + ((6 + hb) ^ px) * 8 + lo] = f2bf(p3);
    }
    __builtin_amdgcn_s_setprio(1);
#pragma unroll
    for (int ks2 = 0; ks2 < 2; ++ks2) {
      int rsl = (((ks2 * 4 + quad) ^ (l16 & 7)) * 8);
      short8 pa = *(const short8*)&Ps[(wave * 16 + l16) * 64 + rsl];
#pragma unroll
      for (int c2 = 0; c2 < 8; ++c2) {
        short8 vb = *(const short8*)&Vs[buf][(c2 * 16 + l16) * 64 + rsl];
        of[c2] = mfma16(pa, vb, of[c2]);
      }
    }
    __builtin_amdgcn_s_setprio(0);
  };

  STAGE(0, 0);
  WAIT_ALL();
  __builtin_amdgcn_s_barrier();
  int cur = 0;
  for (int t = 0; t < 31; ++t) {
    STAGE(t + 1, cur ^ 1);
    COMPUTE(cur);
    WAIT_ALL();
    __builtin_amdgcn_s_barrier();
    cur ^= 1;
  }
  COMPUTE(cur);

#pragma unroll
  for (int r = 0; r < 4; ++r) {
    float ls = lpart[r];
    ls += __shfl_xor(ls, 1);
    ls += __shfl_xor(ls, 2);
    ls += __shfl_xor(ls, 4);
    ls += __shfl_xor(ls, 8);
    float inv = 1.0f / ls;
    int qrow = q0 + wave * 16 + quad * 4 + r;
#pragma unroll
    for (int c2 = 0; c2 < 8; ++c2)
      O[((size_t)b * 2048 + qrow) * 2048 + h * 128 + c2 * 16 + l16] =
          f2bf(of[c2][r] * inv);
  }
}

// ---------------------------------------------------------------------------
extern "C" void kernel_launch(void* const* d_in, const int* in_sizes, int n_in,
                              void* d_out, int out_size, void* d_ws, size_t ws_size,
                              hipStream_t stream) {
  (void)in_sizes; (void)n_in; (void)out_size; (void)ws_size;
  const float* hid  = (const float*)d_in[0];
  const float* temb = (const float*)d_in[1];
  const float* wln  = (const float*)d_in[2];
  const float* wmod = (const float*)d_in[3];
  const float* bmod = (const float*)d_in[4];
  const float* wq   = (const float*)d_in[5];
  const float* wk   = (const float*)d_in[6];
  const float* wv   = (const float*)d_in[7];
  const float* wo   = (const float*)d_in[8];
  const float* qn   = (const float*)d_in[9];
  const float* kn   = (const float*)d_in[10];
  const float* cos1 = (const float*)d_in[11];
  const float* sin1 = (const float*)d_in[12];
  const float* r3   = (const float*)d_in[13];
  const int*   mpos = (const int*)d_in[14];

  char* ws = (char*)d_ws;
  float* mod = (float*)(ws + 0);                 //  49,152 B
  u16* xm  = (u16*)(ws + 49152);                 //  16 MiB
  u16* wT  = (u16*)(ws + 16826368);              //  16 MiB (wq|wk|wv)^T bf16
  u16* woT = wT;                                 //  overlay after QKV GEMM
  u16* qkv = (u16*)(ws + 33603584);              //  32 MiB bf16 (B*L, 4096)
  u16* Qb  = (u16*)(ws + 67158016);              //  16 MiB (B,H,L,Dh)
  u16* Kv  = (u16*)(ws + 83935232);              //   8 MiB (B,KVH,L,Dh)
  u16* VT  = (u16*)(ws + 92323840);              //   8 MiB (B,KVH,Dh,L)
  u16* Ob  = qkv;                                //  overlay (qkv dead by then)

  dim3 b32(32, 8);
  k_silu_mod<<<96, 512, 0, stream>>>(temb, wmod, bmod, mod);
  k_tconv<<<dim3(64, 64), b32, 0, stream>>>(wq, wT, 2048, 2048);
  k_tconv<<<dim3(64, 32), b32, 0, stream>>>(wk, wT + (size_t)2048 * 2048, 1024, 2048);
  k_tconv<<<dim3(64, 32), b32, 0, stream>>>(wv, wT + (size_t)3072 * 2048, 1024, 2048);
  k_xm<<<4096, 256, 0, stream>>>(hid, wln, mod, xm);
  k_gemm256<<<dim3(16, 16), 512, 0, stream>>>(xm, wT, qkv, 4096, 2048);
  k_tconv<<<dim3(64, 64), b32, 0, stream>>>(wo, woT, 2048, 2048);
  k_qknorm<<<4096, 192, 0, stream>>>(qkv, qn, kn, cos1, sin1, r3, mpos, Qb, Kv);
  k_vtrans<<<dim3(16, 32, 2), 256, 0, stream>>>(qkv, VT);
  k_attn<<<dim3(16, 32), 512, 0, stream>>>(Qb, Kv, VT, Ob);
  k_gemm<<<dim3(16, 32), 256, 0, stream>>>(Ob, woT, (float*)d_out, hid, mod, 2048, 2048);
}

// Round 7
// 468.842 us; speedup vs baseline: 1.2197x; 1.0049x over previous
//
#include <hip/hip_runtime.h>
#include <hip/hip_bf16.h>
#include <stdint.h>
#include <math.h>

typedef unsigned short u16;
typedef __attribute__((ext_vector_type(8))) short short8;
typedef __attribute__((ext_vector_type(4))) float fx4;
typedef __attribute__((ext_vector_type(4))) unsigned short u16x4;

#define DEV __device__ __forceinline__

DEV u16 f2bf(float f) {  // hardware v_cvt bf16 (RTNE)
  return __builtin_bit_cast(u16, __float2bfloat16(f));
}
DEV float bf2f(u16 h) { return __builtin_bit_cast(float, ((unsigned)h) << 16); }

DEV fx4 mfma16(short8 a, short8 b, fx4 c) {
  return __builtin_amdgcn_mfma_f32_16x16x32_bf16(a, b, c, 0, 0, 0);
}

#if __has_builtin(__builtin_amdgcn_exp2f)
DEV float exp2v(float x) { return __builtin_amdgcn_exp2f(x); }
#else
DEV float exp2v(float x) { return exp2f(x); }
#endif

// async global->LDS, 16B per lane. LDS dst = wave-uniform base + lane*16.
#define GLD16(g, l)                                                            \
  __builtin_amdgcn_global_load_lds(                                            \
      (const __attribute__((address_space(1))) void*)(g),                      \
      (__attribute__((address_space(3))) void*)(l), 16, 0, 0)

#define WAIT_ALL() asm volatile("s_waitcnt vmcnt(0) lgkmcnt(0)" ::: "memory")
#define WAIT_VM4() asm volatile("s_waitcnt vmcnt(4)" ::: "memory")
#define WAIT_VM0() asm volatile("s_waitcnt vmcnt(0)" ::: "memory")

// ---------------------------------------------------------------------------
// 1) k_pre: fused [silu_mod | tconv wq | tconv wk | tconv wv]
//   role by blockIdx.x: [0,96) silu; [96,4192) dual-tile transpose-convert.
//   No cross-role dependencies. 512 threads.
__global__ __launch_bounds__(512) void k_pre(
    const float* __restrict__ temb, const float* __restrict__ wmod,
    const float* __restrict__ bmod, float* __restrict__ mod,
    const float* __restrict__ wq, const float* __restrict__ wk,
    const float* __restrict__ wv, u16* __restrict__ wT) {
  __shared__ float st[4096];
  __shared__ float red[8][2][64];
  __shared__ float t2[2][32][33];
  int bid = blockIdx.x;
  int tid = threadIdx.x;
  if (bid < 96) {
    // ---- silu_mod: mod = silu(temb) @ w_mod + b_mod ----
    for (int i = tid; i < 4096; i += 512) {
      float t = temb[i];
      st[i] = t / (1.0f + __expf(-t));
    }
    __syncthreads();
    int j = bid * 64 + (tid & 63);
    int ks = tid >> 6;
    float a0 = 0.f, a1 = 0.f;
    for (int d = ks * 256; d < ks * 256 + 256; ++d) {
      float w = wmod[(size_t)d * 6144 + j];
      a0 += st[d] * w;
      a1 += st[2048 + d] * w;
    }
    red[ks][0][tid & 63] = a0;
    red[ks][1][tid & 63] = a1;
    __syncthreads();
    if (tid < 64) {
      float s0 = 0.f, s1 = 0.f;
#pragma unroll
      for (int i = 0; i < 8; ++i) {
        s0 += red[i][0][tid];
        s1 += red[i][1][tid];
      }
      mod[j] = s0 + bmod[j];
      mod[6144 + j] = s1 + bmod[j];
    }
  } else {
    // ---- dual-tile tconv: fp32 [K][cols] -> bf16 dst[n][2048] ----
    int half = tid >> 8;
    int sub = tid & 255;
    int tx = sub & 31, ty = sub >> 5;
    int tt = (bid - 96) * 2 + half;  // 0..8191
    const float* src;
    u16* dst;
    int cols, kb, nb;
    if (tt < 4096) {
      src = wq; dst = wT; cols = 2048;
      kb = (tt & 63) * 32; nb = (tt >> 6) * 32;
    } else if (tt < 6144) {
      int u = tt - 4096;
      src = wk; dst = wT + (size_t)2048 * 2048; cols = 1024;
      kb = (u & 63) * 32; nb = (u >> 6) * 32;
    } else {
      int u = tt - 6144;
      src = wv; dst = wT + (size_t)3072 * 2048; cols = 1024;
      kb = (u & 63) * 32; nb = (u >> 6) * 32;
    }
    float (*t)[33] = t2[half];
#pragma unroll
    for (int i = 0; i < 4; ++i)
      t[ty + i * 8][tx] = src[(size_t)(kb + ty + i * 8) * cols + nb + tx];
    __syncthreads();
    int nl = ty * 4 + (tx >> 3);
    int k4 = (tx & 7) * 4;
    u16x4 v;
#pragma unroll
    for (int j = 0; j < 4; ++j) v[j] = f2bf(t[k4 + j][nl]);
    *(u16x4*)(dst + (size_t)(nb + nl) * 2048 + kb + k4) = v;
  }
}

// ---------------------------------------------------------------------------
// 2) xm = bf16( rmsnorm(hidden)*w_ln * (1+scale[b]) + shift[b] )
__global__ __launch_bounds__(256) void k_xm(
    const float* __restrict__ x, const float* __restrict__ wln,
    const float* __restrict__ mod, u16* __restrict__ xm) {
  int row = blockIdx.x;
  int b = row >> 11;
  const float* xr = x + (size_t)row * 2048;
  int tid = threadIdx.x;
  float4 v0 = ((const float4*)xr)[tid];
  float4 v1 = ((const float4*)xr)[tid + 256];
  float ss = v0.x * v0.x + v0.y * v0.y + v0.z * v0.z + v0.w * v0.w +
             v1.x * v1.x + v1.y * v1.y + v1.z * v1.z + v1.w * v1.w;
  for (int m = 1; m < 64; m <<= 1) ss += __shfl_xor(ss, m);
  __shared__ float red[4];
  if ((tid & 63) == 0) red[tid >> 6] = ss;
  __syncthreads();
  ss = red[0] + red[1] + red[2] + red[3];
  float r = rsqrtf(ss * (1.0f / 2048.0f) + 1e-5f);
  const float* mb = mod + (size_t)b * 6144;
#pragma unroll
  for (int c = 0; c < 2; ++c) {
    int j0 = (tid + c * 256) * 4;
    float4 xv = c ? v1 : v0;
    float4 sh = *(const float4*)(mb + j0);
    float4 sc = *(const float4*)(mb + 2048 + j0);
    float4 wl = *(const float4*)(wln + j0);
    u16x4 o;
    o.x = f2bf(xv.x * r * wl.x * (1.f + sc.x) + sh.x);
    o.y = f2bf(xv.y * r * wl.y * (1.f + sc.y) + sh.y);
    o.z = f2bf(xv.z * r * wl.z * (1.f + sc.z) + sh.z);
    o.w = f2bf(xv.w * r * wl.w * (1.f + sc.w) + sh.w);
    *(u16x4*)(xm + (size_t)row * 2048 + j0) = o;
  }
}

// ---------------------------------------------------------------------------
// 3) 256x256-tile GEMM for the QKV projection (C = bf16).
//   8 waves (2M x 4N), 3-buffer LDS (96 KB), counted vmcnt(4), one barrier
//   per K-step. Grid (N/256, M/256) = 256 blocks = 1/CU exactly.
__global__ __launch_bounds__(512, 1) void k_gemm256(
    const u16* __restrict__ A, const u16* __restrict__ Bt, u16* __restrict__ C,
    int N, int K) {
  __shared__ u16 As[3][256 * 32];
  __shared__ u16 Bs[3][256 * 32];
  int tid = threadIdx.x;
  int wave = tid >> 6, lane = tid & 63, quad = lane >> 4, l16 = lane & 15;
  int gx = gridDim.x;
  int nwg = gx * gridDim.y;
  int lin = blockIdx.y * gx + blockIdx.x;
  int cpx = nwg >> 3;
  int swz = (lin & 7) * cpx + (lin >> 3);
  int m0 = (swz / gx) * 256, n0 = (swz % gx) * 256;
  int wm = (wave >> 2) * 128, wn = (wave & 3) * 64;
  fx4 acc[8][4] = {};
  int rowa = tid >> 2;
  int chunk = (tid & 3) ^ ((rowa >> 1) & 3);
  int cola = chunk * 8;
  const u16* Ag = A + (size_t)(m0 + rowa) * K + cola;
  const u16* Bg = Bt + (size_t)(n0 + rowa) * K + cola;
  int sl = (quad ^ ((l16 >> 1) & 3)) * 8;

  auto STAGE = [&](int k0, int buf) {
    u16* AsW = &As[buf][wave * 512];
    u16* BsW = &Bs[buf][wave * 512];
    GLD16(Ag + k0, AsW);
    GLD16(Ag + k0 + (size_t)128 * K, AsW + 4096);
    GLD16(Bg + k0, BsW);
    GLD16(Bg + k0 + (size_t)128 * K, BsW + 4096);
  };
  auto COMPUTE = [&](int buf) {
    short8 af[8], bfr[4];
#pragma unroll
    for (int i = 0; i < 8; ++i)
      af[i] = *(const short8*)&As[buf][(wm + i * 16 + l16) * 32 + sl];
#pragma unroll
    for (int j = 0; j < 4; ++j)
      bfr[j] = *(const short8*)&Bs[buf][(wn + j * 16 + l16) * 32 + sl];
#pragma unroll
    for (int i = 0; i < 8; ++i)
#pragma unroll
      for (int j = 0; j < 4; ++j) acc[i][j] = mfma16(af[i], bfr[j], acc[i][j]);
  };

  STAGE(0, 0);
  STAGE(32, 1);
  for (int t = 0; t < 62; ++t) {
    WAIT_VM4();
    __builtin_amdgcn_s_barrier();
    STAGE((t + 2) * 32, (t + 2) % 3);
    COMPUTE(t % 3);
  }
  WAIT_VM4();
  __builtin_amdgcn_s_barrier();
  COMPUTE(2);
  WAIT_VM0();
  __builtin_amdgcn_s_barrier();
  COMPUTE(0);

#pragma unroll
  for (int i = 0; i < 8; ++i) {
    int row = m0 + wm + i * 16 + quad * 4;
#pragma unroll
    for (int j = 0; j < 4; ++j) {
      int col = n0 + wn + j * 16 + l16;
#pragma unroll
      for (int r = 0; r < 4; ++r)
        C[(size_t)(row + r) * N + col] = f2bf(acc[i][j][r]);
    }
  }
}

// ---------------------------------------------------------------------------
// 4) k_mid: fused [tconv wo | qknorm | vtrans], role by blockIdx.x.
//   All roles depend only on completion of k_gemm256 (frees wT for woT).
//   256 threads.
__global__ __launch_bounds__(256) void k_mid(
    const float* __restrict__ wo, u16* __restrict__ woT,
    const u16* __restrict__ qkv, const float* __restrict__ qn,
    const float* __restrict__ kn, const float* __restrict__ cos1,
    const float* __restrict__ sin1, const float* __restrict__ r3,
    const int* __restrict__ mpos, u16* __restrict__ Q, u16* __restrict__ Kb,
    u16* __restrict__ VT) {
  __shared__ float tc[32][33];
  __shared__ u16 tv[64][65];
  int bid = blockIdx.x;
  int tid = threadIdx.x;
  if (bid < 4096) {
    // ---- tconv wo -> woT ----
    int kb = (bid & 63) * 32, nb = (bid >> 6) * 32;
    int tx = tid & 31, ty = tid >> 5;
#pragma unroll
    for (int i = 0; i < 4; ++i)
      tc[ty + i * 8][tx] = wo[(size_t)(kb + ty + i * 8) * 2048 + nb + tx];
    __syncthreads();
    int nl = ty * 4 + (tx >> 3);
    int k4 = (tx & 7) * 4;
    u16x4 v;
#pragma unroll
    for (int j = 0; j < 4; ++j) v[j] = f2bf(tc[k4 + j][nl]);
    *(u16x4*)(woT + (size_t)(nb + nl) * 2048 + kb + k4) = v;
  } else if (bid < 8192) {
    // ---- qknorm + mixed RoPE (Q pre-scaled by log2e/sqrt(Dh)) ----
    int bx = bid - 4096;
    int b = bx >> 11, l = bx & 2047;
    int slot = tid >> 3, sub = tid & 7;
    if (slot >= 24) return;
    bool isq = slot < 16;
    int head = isq ? slot : slot - 16;
    const u16* base =
        qkv + (size_t)bx * 4096 + (isq ? slot * 128 : 2048 + head * 128);
    int d0 = sub * 16;
    short8 sx0 = *(const short8*)(base + d0);
    short8 sx1 = *(const short8*)(base + d0 + 8);
    float xv[16];
#pragma unroll
    for (int i = 0; i < 8; ++i) {
      xv[i] = bf2f((u16)sx0[i]);
      xv[8 + i] = bf2f((u16)sx1[i]);
    }
    float ss = 0.f;
#pragma unroll
    for (int i = 0; i < 16; ++i) ss += xv[i] * xv[i];
    ss += __shfl_xor(ss, 1);
    ss += __shfl_xor(ss, 2);
    ss += __shfl_xor(ss, 4);
    float r = rsqrtf(ss * (1.0f / 128.0f) + 1e-5f);
    int mp[8];
    {
      bool is64 =
          (mpos[1] == 0) & (mpos[3] == 0) & (mpos[5] == 0) & (mpos[7] == 0);
#pragma unroll
      for (int i = 0; i < 8; ++i) mp[i] = is64 ? mpos[2 * i] : mpos[i];
    }
    bool infull = false, inimg = false;
    int rel = 0;
#pragma unroll
    for (int s = 0; s < 2; ++s) {
      int off = mp[b * 4 + s * 2], ln = mp[b * 4 + s * 2 + 1];
      int mx = ln > 1 ? ln : 1;
      infull |= (l >= off) && (l < off + mx);
      bool ii = (l >= off + 1) && (l < off + ln);
      inimg |= ii;
      rel += ii ? (l - (off + 1)) : 0;
    }
    bool text = !infull;
    bool img = inimg && (rel < 1024);
    const float* w = isq ? qn : kn;
    fx4 wv4[4];
#pragma unroll
    for (int q = 0; q < 4; ++q) wv4[q] = *(const fx4*)(w + d0 + q * 4);
    float out[16];
    if (text) {
      int dp0 = d0 ^ 64;
      float sgn = (d0 < 64) ? -1.f : 1.f;
      short8 sp0 = *(const short8*)(base + dp0);
      short8 sp1 = *(const short8*)(base + dp0 + 8);
      fx4 cv[4], sv[4], wp[4];
#pragma unroll
      for (int q = 0; q < 4; ++q) {
        cv[q] = *(const fx4*)(cos1 + (size_t)l * 128 + d0 + q * 4);
        sv[q] = *(const fx4*)(sin1 + (size_t)l * 128 + d0 + q * 4);
        wp[q] = *(const fx4*)(w + dp0 + q * 4);
      }
#pragma unroll
      for (int i = 0; i < 16; ++i) {
        float xp = bf2f((u16)(i < 8 ? sp0[i & 7] : sp1[i & 7]));
        out[i] = r * (xv[i] * wv4[i >> 2][i & 3] * cv[i >> 2][i & 3] +
                      sgn * xp * wp[i >> 2][i & 3] * sv[i >> 2][i & 3]);
      }
    } else if (img) {
      const fx4* Rv = (const fx4*)(r3 + ((size_t)rel * 64 + (d0 >> 1)) * 4);
#pragma unroll
      for (int p = 0; p < 8; ++p) {
        fx4 R = Rv[p];
        float a = xv[2 * p] * wv4[(2 * p) >> 2][(2 * p) & 3] * r;
        float c2 = xv[2 * p + 1] * wv4[(2 * p + 1) >> 2][(2 * p + 1) & 3] * r;
        out[2 * p] = a * R[0] + c2 * R[2];
        out[2 * p + 1] = a * R[1] + c2 * R[3];
      }
    } else {
#pragma unroll
      for (int i = 0; i < 16; ++i) out[i] = xv[i] * wv4[i >> 2][i & 3] * r;
    }
    float qs = isq ? (0.08838834764831845f * 1.4426950408889634f) : 1.0f;
    short8 o0, o1;
#pragma unroll
    for (int i = 0; i < 8; ++i) {
      o0[i] = (short)f2bf(out[i] * qs);
      o1[i] = (short)f2bf(out[8 + i] * qs);
    }
    u16* dst = isq ? (Q + ((size_t)(b * 16 + head) * 2048 + l) * 128 + d0)
                   : (Kb + ((size_t)(b * 8 + head) * 2048 + l) * 128 + d0);
    *(short8*)dst = o0;
    *(short8*)(dst + 8) = o1;
  } else {
    // ---- vtrans: qkv V-section -> VT (B,KVH,Dh,L) ----
    int v = bid - 8192;
    int bh = v & 15;
    int l0 = ((v >> 4) & 31) * 64, d0 = (v >> 9) * 64;
    int b = bh >> 3, kvh = bh & 7;
    int lr = tid >> 4;
    int c4 = (tid & 15) * 4;
#pragma unroll
    for (int i = 0; i < 4; ++i) {
      int li = lr + i * 16;
      *(u16x4*)&tv[li][c4] = *(const u16x4*)(
          qkv + (size_t)(b * 2048 + l0 + li) * 4096 + 3072 + kvh * 128 + d0 + c4);
    }
    __syncthreads();
#pragma unroll
    for (int i = 0; i < 4; ++i) {
      int di = lr + i * 16;
      u16x4 vv;
      vv[0] = tv[c4 + 0][di];
      vv[1] = tv[c4 + 1][di];
      vv[2] = tv[c4 + 2][di];
      vv[3] = tv[c4 + 3][di];
      *(u16x4*)(VT + ((size_t)bh * 128 + d0 + di) * 2048 + l0 + c4) = vv;
    }
  }
}

// ---------------------------------------------------------------------------
// 5) flash attention v2, depth-1 pipelined, shuffle-free softmax common path,
//   bijective XCD-chunk block swizzle (each XCD gets 4 contiguous bh groups:
//   working set ~4MB = L2-resident K/V).
__global__ __launch_bounds__(512, 4) void k_attn(
    const u16* __restrict__ Q, const u16* __restrict__ Kb,
    const u16* __restrict__ VT, u16* __restrict__ O) {
  __shared__ u16 Ks[2][64 * 128];
  __shared__ u16 Vs[2][128 * 64];
  __shared__ u16 Ps[128 * 64];
  int tid = threadIdx.x;
  int wave = tid >> 6, lane = tid & 63, quad = lane >> 4, l16 = lane & 15;
  int lin = blockIdx.y * gridDim.x + blockIdx.x;  // 512 blocks
  int vb = (lin & 7) * 64 + (lin >> 3);           // bijective XCD chunk
  int q0 = (vb & 15) * 128;
  int bh = vb >> 4;
  int b = bh >> 4, h = bh & 15, kvh = h >> 1;
  const u16* Qb = Q + ((size_t)bh * 2048 + q0 + wave * 16) * 128;
  short8 qf[4];
#pragma unroll
  for (int ks = 0; ks < 4; ++ks)
    qf[ks] = *(const short8*)(Qb + l16 * 128 + ks * 32 + quad * 8);
  const u16* Kg = Kb + (size_t)(b * 8 + kvh) * 2048 * 128;
  const u16* Vg = VT + (size_t)(b * 8 + kvh) * 128 * 2048;
  float mrow[4], lpart[4];
  fx4 of[8] = {};
#pragma unroll
  for (int r = 0; r < 4; ++r) {
    mrow[r] = -INFINITY;
    lpart[r] = 0.f;
  }
  size_t kgo[2], vgo[2];
#pragma unroll
  for (int i = 0; i < 2; ++i) {
    int kr = i * 32 + wave * 4 + (lane >> 4);
    kgo[i] = (size_t)kr * 128 + (((lane & 15) ^ (kr & 15)) * 8);
    int vr = i * 64 + wave * 8 + (lane >> 3);
    vgo[i] = (size_t)vr * 2048 + (((lane & 7) ^ (vr & 7)) * 8);
  }

  auto STAGE = [&](int t, int buf) {
    size_t ko = (size_t)t * 8192;
    size_t vo = (size_t)t * 64;
#pragma unroll
    for (int i = 0; i < 2; ++i) {
      GLD16(Kg + ko + kgo[i], &Ks[buf][i * 4096 + wave * 512]);
      GLD16(Vg + vo + vgo[i], &Vs[buf][i * 4096 + wave * 512]);
    }
  };

  auto COMPUTE = [&](int buf) {
    fx4 sf[4] = {};
    __builtin_amdgcn_s_setprio(1);
#pragma unroll
    for (int ct = 0; ct < 4; ++ct) {
#pragma unroll
      for (int ks = 0; ks < 4; ++ks) {
        short8 kf = *(const short8*)&Ks[buf][(ct * 16 + l16) * 128 +
                                            (((ks * 4 + quad) ^ l16) * 8)];
        sf[ct] = mfma16(qf[ks], kf, sf[ct]);
      }
    }
    __builtin_amdgcn_s_setprio(0);
    float cmv[4];
    bool need = false;
#pragma unroll
    for (int r = 0; r < 4; ++r) {
      cmv[r] = fmaxf(fmaxf(sf[0][r], sf[1][r]), fmaxf(sf[2][r], sf[3][r]));
      need |= (cmv[r] > mrow[r] + 8.0f);
    }
    if (__any(need)) {  // T13 defer-max: P bounded by 2^8
#pragma unroll
      for (int r = 0; r < 4; ++r) {
        float cm = cmv[r];
        cm = fmaxf(cm, __shfl_xor(cm, 1));
        cm = fmaxf(cm, __shfl_xor(cm, 2));
        cm = fmaxf(cm, __shfl_xor(cm, 4));
        cm = fmaxf(cm, __shfl_xor(cm, 8));
        float mn = fmaxf(mrow[r], cm);
        float al = exp2v(mrow[r] - mn);
        mrow[r] = mn;
        lpart[r] *= al;
#pragma unroll
        for (int c2 = 0; c2 < 8; ++c2) of[c2][r] *= al;
      }
    }
    int hb = l16 >> 3;
#pragma unroll
    for (int r = 0; r < 4; ++r) {
      float p0 = exp2v(sf[0][r] - mrow[r]);
      float p1 = exp2v(sf[1][r] - mrow[r]);
      float p2 = exp2v(sf[2][r] - mrow[r]);
      float p3 = exp2v(sf[3][r] - mrow[r]);
      lpart[r] += (p0 + p1) + (p2 + p3);
      int prow = wave * 16 + quad * 4 + r;
      int pb = prow * 64, px = prow & 7, lo = l16 & 7;
      Ps[pb + ((0 + hb) ^ px) * 8 + lo] = f2bf(p0);
      Ps[pb + ((2 + hb) ^ px) * 8 + lo] = f2bf(p1);
      Ps[pb + ((4 + hb) ^ px) * 8 + lo] = f2bf(p2);
      Ps[pb + ((6 + hb) ^ px) * 8 + lo] = f2bf(p3);
    }
    __builtin_amdgcn_s_setprio(1);
#pragma unroll
    for (int ks2 = 0; ks2 < 2; ++ks2) {
      int rsl = (((ks2 * 4 + quad) ^ (l16 & 7)) * 8);
      short8 pa = *(const short8*)&Ps[(wave * 16 + l16) * 64 + rsl];
#pragma unroll
      for (int c2 = 0; c2 < 8; ++c2) {
        short8 vb2 = *(const short8*)&Vs[buf][(c2 * 16 + l16) * 64 + rsl];
        of[c2] = mfma16(pa, vb2, of[c2]);
      }
    }
    __builtin_amdgcn_s_setprio(0);
  };

  STAGE(0, 0);
  WAIT_ALL();
  __builtin_amdgcn_s_barrier();
  int cur = 0;
  for (int t = 0; t < 31; ++t) {
    STAGE(t + 1, cur ^ 1);
    COMPUTE(cur);
    WAIT_ALL();
    __builtin_amdgcn_s_barrier();
    cur ^= 1;
  }
  COMPUTE(cur);

#pragma unroll
  for (int r = 0; r < 4; ++r) {
    float ls = lpart[r];
    ls += __shfl_xor(ls, 1);
    ls += __shfl_xor(ls, 2);
    ls += __shfl_xor(ls, 4);
    ls += __shfl_xor(ls, 8);
    float inv = 1.0f / ls;
    int qrow = q0 + wave * 16 + quad * 4 + r;
#pragma unroll
    for (int c2 = 0; c2 < 8; ++c2)
      O[((size_t)b * 2048 + qrow) * 2048 + h * 128 + c2 * 16 + l16] =
          f2bf(of[c2][r] * inv);
  }
}

// ---------------------------------------------------------------------------
// 6) 128x128-tile GEMM with fused residual epilogue (WO GEMM).
//   3-buffer LDS (48 KB), counted vmcnt(4), one barrier per K-step.
__global__ __launch_bounds__(256) void k_gemm(
    const u16* __restrict__ A, const u16* __restrict__ Bt, float* __restrict__ C,
    const float* __restrict__ hid, const float* __restrict__ mod, int N, int K) {
  __shared__ u16 As[3][128 * 32];
  __shared__ u16 Bs[3][128 * 32];
  int tid = threadIdx.x;
  int wave = tid >> 6, lane = tid & 63, quad = lane >> 4, l16 = lane & 15;
  int gx = gridDim.x;
  int nwg = gx * gridDim.y;
  int lin = blockIdx.y * gx + blockIdx.x;
  int cpx = nwg >> 3;
  int swz = (lin & 7) * cpx + (lin >> 3);
  int m0 = (swz / gx) * 128, n0 = (swz % gx) * 128;
  int wm = (wave >> 1) * 64, wn = (wave & 1) * 64;
  fx4 acc[4][4] = {};
  int rowa = tid >> 2;
  int chunk = (tid & 3) ^ ((rowa >> 1) & 3);
  int cola = chunk * 8;
  const u16* Ag = A + (size_t)(m0 + rowa) * K + cola;
  const u16* Bg = Bt + (size_t)(n0 + rowa) * K + cola;
  int sl = (quad ^ ((l16 >> 1) & 3)) * 8;

  auto STAGE = [&](int k0, int buf) {
    u16* AsW = &As[buf][wave * 512];
    u16* BsW = &Bs[buf][wave * 512];
    GLD16(Ag + k0, AsW);
    GLD16(Ag + k0 + (size_t)64 * K, AsW + 2048);
    GLD16(Bg + k0, BsW);
    GLD16(Bg + k0 + (size_t)64 * K, BsW + 2048);
  };
  auto COMPUTE = [&](int buf) {
    short8 af[4], bfr[4];
#pragma unroll
    for (int i = 0; i < 4; ++i) {
      af[i] = *(const short8*)&As[buf][(wm + i * 16 + l16) * 32 + sl];
      bfr[i] = *(const short8*)&Bs[buf][(wn + i * 16 + l16) * 32 + sl];
    }
#pragma unroll
    for (int i = 0; i < 4; ++i)
#pragma unroll
      for (int j = 0; j < 4; ++j) acc[i][j] = mfma16(af[i], bfr[j], acc[i][j]);
  };

  STAGE(0, 0);
  STAGE(32, 1);
  int nk = K >> 5;  // 64
  for (int t = 0; t < nk - 2; ++t) {
    WAIT_VM4();
    __builtin_amdgcn_s_barrier();
    STAGE((t + 2) * 32, (t + 2) % 3);
    COMPUTE(t % 3);
  }
  WAIT_VM4();
  __builtin_amdgcn_s_barrier();
  COMPUTE((nk - 2) % 3);
  WAIT_VM0();
  __builtin_amdgcn_s_barrier();
  COMPUTE((nk - 1) % 3);

#pragma unroll
  for (int i = 0; i < 4; ++i) {
    int row = m0 + wm + i * 16 + quad * 4;
#pragma unroll
    for (int j = 0; j < 4; ++j) {
      int col = n0 + wn + j * 16 + l16;
      int b = row >> 11;
      float g = mod[(size_t)b * 6144 + 4096 + col];
#pragma unroll
      for (int r = 0; r < 4; ++r)
        C[(size_t)(row + r) * N + col] =
            hid[(size_t)(row + r) * N + col] + g * acc[i][j][r];
    }
  }
}

// ---------------------------------------------------------------------------
extern "C" void kernel_launch(void* const* d_in, const int* in_sizes, int n_in,
                              void* d_out, int out_size, void* d_ws, size_t ws_size,
                              hipStream_t stream) {
  (void)in_sizes; (void)n_in; (void)out_size; (void)ws_size;
  const float* hid  = (const float*)d_in[0];
  const float* temb = (const float*)d_in[1];
  const float* wln  = (const float*)d_in[2];
  const float* wmod = (const float*)d_in[3];
  const float* bmod = (const float*)d_in[4];
  const float* wq   = (const float*)d_in[5];
  const float* wk   = (const float*)d_in[6];
  const float* wv   = (const float*)d_in[7];
  const float* wo   = (const float*)d_in[8];
  const float* qn   = (const float*)d_in[9];
  const float* kn   = (const float*)d_in[10];
  const float* cos1 = (const float*)d_in[11];
  const float* sin1 = (const float*)d_in[12];
  const float* r3   = (const float*)d_in[13];
  const int*   mpos = (const int*)d_in[14];

  char* ws = (char*)d_ws;
  float* mod = (float*)(ws + 0);                 //  49,152 B
  u16* xm  = (u16*)(ws + 49152);                 //  16 MiB
  u16* wT  = (u16*)(ws + 16826368);              //  16 MiB (wq|wk|wv)^T bf16
  u16* woT = wT;                                 //  overlay after QKV GEMM
  u16* qkv = (u16*)(ws + 33603584);              //  32 MiB bf16 (B*L, 4096)
  u16* Qb  = (u16*)(ws + 67158016);              //  16 MiB (B,H,L,Dh)
  u16* Kv  = (u16*)(ws + 83935232);              //   8 MiB (B,KVH,L,Dh)
  u16* VT  = (u16*)(ws + 92323840);              //   8 MiB (B,KVH,Dh,L)
  u16* Ob  = qkv;                                //  overlay (qkv dead by then)

  k_pre<<<4192, 512, 0, stream>>>(temb, wmod, bmod, mod, wq, wk, wv, wT);
  k_xm<<<4096, 256, 0, stream>>>(hid, wln, mod, xm);
  k_gemm256<<<dim3(16, 16), 512, 0, stream>>>(xm, wT, qkv, 4096, 2048);
  k_mid<<<9216, 256, 0, stream>>>(wo, woT, qkv, qn, kn, cos1, sin1, r3, mpos,
                                  Qb, Kv, VT);
  k_attn<<<dim3(16, 32), 512, 0, stream>>>(Qb, Kv, VT, Ob);
  k_gemm<<<dim3(16, 32), 256, 0, stream>>>(Ob, woT, (float*)d_out, hid, mod,
                                           2048, 2048);
}

// Round 8
// 464.359 us; speedup vs baseline: 1.2315x; 1.0097x over previous
//
#include <hip/hip_runtime.h>
#include <hip/hip_bf16.h>
#include <stdint.h>
#include <math.h>

typedef unsigned short u16;
typedef __attribute__((ext_vector_type(8))) short short8;
typedef __attribute__((ext_vector_type(4))) float fx4;
typedef __attribute__((ext_vector_type(4))) unsigned short u16x4;

#define DEV __device__ __forceinline__

DEV u16 f2bf(float f) {  // hardware v_cvt bf16 (RTNE)
  return __builtin_bit_cast(u16, __float2bfloat16(f));
}
DEV float bf2f(u16 h) { return __builtin_bit_cast(float, ((unsigned)h) << 16); }

DEV fx4 mfma16(short8 a, short8 b, fx4 c) {
  return __builtin_amdgcn_mfma_f32_16x16x32_bf16(a, b, c, 0, 0, 0);
}

#if __has_builtin(__builtin_amdgcn_exp2f)
DEV float exp2v(float x) { return __builtin_amdgcn_exp2f(x); }
#else
DEV float exp2v(float x) { return exp2f(x); }
#endif

// async global->LDS, 16B per lane. LDS dst = wave-uniform base + lane*16.
#define GLD16(g, l)                                                            \
  __builtin_amdgcn_global_load_lds(                                            \
      (const __attribute__((address_space(1))) void*)(g),                      \
      (__attribute__((address_space(3))) void*)(l), 16, 0, 0)

#define WAIT_ALL() asm volatile("s_waitcnt vmcnt(0) lgkmcnt(0)" ::: "memory")
#define WAIT_VM4() asm volatile("s_waitcnt vmcnt(4)" ::: "memory")
#define WAIT_VM0() asm volatile("s_waitcnt vmcnt(0)" ::: "memory")

// ---------------------------------------------------------------------------
// 1) k_pre: fused [silu_mod | tconv wq | tconv wk | tconv wv]
__global__ __launch_bounds__(512) void k_pre(
    const float* __restrict__ temb, const float* __restrict__ wmod,
    const float* __restrict__ bmod, float* __restrict__ mod,
    const float* __restrict__ wq, const float* __restrict__ wk,
    const float* __restrict__ wv, u16* __restrict__ wT) {
  __shared__ float st[4096];
  __shared__ float red[8][2][64];
  __shared__ float t2[2][32][33];
  int bid = blockIdx.x;
  int tid = threadIdx.x;
  if (bid < 96) {
    for (int i = tid; i < 4096; i += 512) {
      float t = temb[i];
      st[i] = t / (1.0f + __expf(-t));
    }
    __syncthreads();
    int j = bid * 64 + (tid & 63);
    int ks = tid >> 6;
    float a0 = 0.f, a1 = 0.f;
    for (int d = ks * 256; d < ks * 256 + 256; ++d) {
      float w = wmod[(size_t)d * 6144 + j];
      a0 += st[d] * w;
      a1 += st[2048 + d] * w;
    }
    red[ks][0][tid & 63] = a0;
    red[ks][1][tid & 63] = a1;
    __syncthreads();
    if (tid < 64) {
      float s0 = 0.f, s1 = 0.f;
#pragma unroll
      for (int i = 0; i < 8; ++i) {
        s0 += red[i][0][tid];
        s1 += red[i][1][tid];
      }
      mod[j] = s0 + bmod[j];
      mod[6144 + j] = s1 + bmod[j];
    }
  } else {
    int half = tid >> 8;
    int sub = tid & 255;
    int tx = sub & 31, ty = sub >> 5;
    int tt = (bid - 96) * 2 + half;  // 0..8191
    const float* src;
    u16* dst;
    int cols, kb, nb;
    if (tt < 4096) {
      src = wq; dst = wT; cols = 2048;
      kb = (tt & 63) * 32; nb = (tt >> 6) * 32;
    } else if (tt < 6144) {
      int u = tt - 4096;
      src = wk; dst = wT + (size_t)2048 * 2048; cols = 1024;
      kb = (u & 63) * 32; nb = (u >> 6) * 32;
    } else {
      int u = tt - 6144;
      src = wv; dst = wT + (size_t)3072 * 2048; cols = 1024;
      kb = (u & 63) * 32; nb = (u >> 6) * 32;
    }
    float (*t)[33] = t2[half];
#pragma unroll
    for (int i = 0; i < 4; ++i)
      t[ty + i * 8][tx] = src[(size_t)(kb + ty + i * 8) * cols + nb + tx];
    __syncthreads();
    int nl = ty * 4 + (tx >> 3);
    int k4 = (tx & 7) * 4;
    u16x4 v;
#pragma unroll
    for (int j = 0; j < 4; ++j) v[j] = f2bf(t[k4 + j][nl]);
    *(u16x4*)(dst + (size_t)(nb + nl) * 2048 + kb + k4) = v;
  }
}

// ---------------------------------------------------------------------------
// 2) xm = bf16( rmsnorm(hidden)*w_ln * (1+scale[b]) + shift[b] )
__global__ __launch_bounds__(256) void k_xm(
    const float* __restrict__ x, const float* __restrict__ wln,
    const float* __restrict__ mod, u16* __restrict__ xm) {
  int row = blockIdx.x;
  int b = row >> 11;
  const float* xr = x + (size_t)row * 2048;
  int tid = threadIdx.x;
  float4 v0 = ((const float4*)xr)[tid];
  float4 v1 = ((const float4*)xr)[tid + 256];
  float ss = v0.x * v0.x + v0.y * v0.y + v0.z * v0.z + v0.w * v0.w +
             v1.x * v1.x + v1.y * v1.y + v1.z * v1.z + v1.w * v1.w;
  for (int m = 1; m < 64; m <<= 1) ss += __shfl_xor(ss, m);
  __shared__ float red[4];
  if ((tid & 63) == 0) red[tid >> 6] = ss;
  __syncthreads();
  ss = red[0] + red[1] + red[2] + red[3];
  float r = rsqrtf(ss * (1.0f / 2048.0f) + 1e-5f);
  const float* mb = mod + (size_t)b * 6144;
#pragma unroll
  for (int c = 0; c < 2; ++c) {
    int j0 = (tid + c * 256) * 4;
    float4 xv = c ? v1 : v0;
    float4 sh = *(const float4*)(mb + j0);
    float4 sc = *(const float4*)(mb + 2048 + j0);
    float4 wl = *(const float4*)(wln + j0);
    u16x4 o;
    o.x = f2bf(xv.x * r * wl.x * (1.f + sc.x) + sh.x);
    o.y = f2bf(xv.y * r * wl.y * (1.f + sc.y) + sh.y);
    o.z = f2bf(xv.z * r * wl.z * (1.f + sc.z) + sh.z);
    o.w = f2bf(xv.w * r * wl.w * (1.f + sc.w) + sh.w);
    *(u16x4*)(xm + (size_t)row * 2048 + j0) = o;
  }
}

// ---------------------------------------------------------------------------
// 3) 256x256-tile GEMM for the QKV projection (C = bf16).
__global__ __launch_bounds__(512, 1) void k_gemm256(
    const u16* __restrict__ A, const u16* __restrict__ Bt, u16* __restrict__ C,
    int N, int K) {
  __shared__ u16 As[3][256 * 32];
  __shared__ u16 Bs[3][256 * 32];
  int tid = threadIdx.x;
  int wave = tid >> 6, lane = tid & 63, quad = lane >> 4, l16 = lane & 15;
  int gx = gridDim.x;
  int nwg = gx * gridDim.y;
  int lin = blockIdx.y * gx + blockIdx.x;
  int cpx = nwg >> 3;
  int swz = (lin & 7) * cpx + (lin >> 3);
  int m0 = (swz / gx) * 256, n0 = (swz % gx) * 256;
  int wm = (wave >> 2) * 128, wn = (wave & 3) * 64;
  fx4 acc[8][4] = {};
  int rowa = tid >> 2;
  int chunk = (tid & 3) ^ ((rowa >> 1) & 3);
  int cola = chunk * 8;
  const u16* Ag = A + (size_t)(m0 + rowa) * K + cola;
  const u16* Bg = Bt + (size_t)(n0 + rowa) * K + cola;
  int sl = (quad ^ ((l16 >> 1) & 3)) * 8;

  auto STAGE = [&](int k0, int buf) {
    u16* AsW = &As[buf][wave * 512];
    u16* BsW = &Bs[buf][wave * 512];
    GLD16(Ag + k0, AsW);
    GLD16(Ag + k0 + (size_t)128 * K, AsW + 4096);
    GLD16(Bg + k0, BsW);
    GLD16(Bg + k0 + (size_t)128 * K, BsW + 4096);
  };
  auto COMPUTE = [&](int buf) {
    short8 af[8], bfr[4];
#pragma unroll
    for (int i = 0; i < 8; ++i)
      af[i] = *(const short8*)&As[buf][(wm + i * 16 + l16) * 32 + sl];
#pragma unroll
    for (int j = 0; j < 4; ++j)
      bfr[j] = *(const short8*)&Bs[buf][(wn + j * 16 + l16) * 32 + sl];
#pragma unroll
    for (int i = 0; i < 8; ++i)
#pragma unroll
      for (int j = 0; j < 4; ++j) acc[i][j] = mfma16(af[i], bfr[j], acc[i][j]);
  };

  STAGE(0, 0);
  STAGE(32, 1);
  for (int t = 0; t < 62; ++t) {
    WAIT_VM4();
    __builtin_amdgcn_s_barrier();
    STAGE((t + 2) * 32, (t + 2) % 3);
    COMPUTE(t % 3);
  }
  WAIT_VM4();
  __builtin_amdgcn_s_barrier();
  COMPUTE(2);
  WAIT_VM0();
  __builtin_amdgcn_s_barrier();
  COMPUTE(0);

#pragma unroll
  for (int i = 0; i < 8; ++i) {
    int row = m0 + wm + i * 16 + quad * 4;
#pragma unroll
    for (int j = 0; j < 4; ++j) {
      int col = n0 + wn + j * 16 + l16;
#pragma unroll
      for (int r = 0; r < 4; ++r)
        C[(size_t)(row + r) * N + col] = f2bf(acc[i][j][r]);
    }
  }
}

// ---------------------------------------------------------------------------
// 4) k_mid: fused [tconv wo | qknorm | vtrans], role by blockIdx.x.
__global__ __launch_bounds__(256) void k_mid(
    const float* __restrict__ wo, u16* __restrict__ woT,
    const u16* __restrict__ qkv, const float* __restrict__ qn,
    const float* __restrict__ kn, const float* __restrict__ cos1,
    const float* __restrict__ sin1, const float* __restrict__ r3,
    const int* __restrict__ mpos, u16* __restrict__ Q, u16* __restrict__ Kb,
    u16* __restrict__ VT) {
  __shared__ float tc[32][33];
  __shared__ u16 tv[64][65];
  int bid = blockIdx.x;
  int tid = threadIdx.x;
  if (bid < 4096) {
    int kb = (bid & 63) * 32, nb = (bid >> 6) * 32;
    int tx = tid & 31, ty = tid >> 5;
#pragma unroll
    for (int i = 0; i < 4; ++i)
      tc[ty + i * 8][tx] = wo[(size_t)(kb + ty + i * 8) * 2048 + nb + tx];
    __syncthreads();
    int nl = ty * 4 + (tx >> 3);
    int k4 = (tx & 7) * 4;
    u16x4 v;
#pragma unroll
    for (int j = 0; j < 4; ++j) v[j] = f2bf(tc[k4 + j][nl]);
    *(u16x4*)(woT + (size_t)(nb + nl) * 2048 + kb + k4) = v;
  } else if (bid < 8192) {
    int bx = bid - 4096;
    int b = bx >> 11, l = bx & 2047;
    int slot = tid >> 3, sub = tid & 7;
    if (slot >= 24) return;
    bool isq = slot < 16;
    int head = isq ? slot : slot - 16;
    const u16* base =
        qkv + (size_t)bx * 4096 + (isq ? slot * 128 : 2048 + head * 128);
    int d0 = sub * 16;
    short8 sx0 = *(const short8*)(base + d0);
    short8 sx1 = *(const short8*)(base + d0 + 8);
    float xv[16];
#pragma unroll
    for (int i = 0; i < 8; ++i) {
      xv[i] = bf2f((u16)sx0[i]);
      xv[8 + i] = bf2f((u16)sx1[i]);
    }
    float ss = 0.f;
#pragma unroll
    for (int i = 0; i < 16; ++i) ss += xv[i] * xv[i];
    ss += __shfl_xor(ss, 1);
    ss += __shfl_xor(ss, 2);
    ss += __shfl_xor(ss, 4);
    float r = rsqrtf(ss * (1.0f / 128.0f) + 1e-5f);
    int mp[8];
    {
      bool is64 =
          (mpos[1] == 0) & (mpos[3] == 0) & (mpos[5] == 0) & (mpos[7] == 0);
#pragma unroll
      for (int i = 0; i < 8; ++i) mp[i] = is64 ? mpos[2 * i] : mpos[i];
    }
    bool infull = false, inimg = false;
    int rel = 0;
#pragma unroll
    for (int s = 0; s < 2; ++s) {
      int off = mp[b * 4 + s * 2], ln = mp[b * 4 + s * 2 + 1];
      int mx = ln > 1 ? ln : 1;
      infull |= (l >= off) && (l < off + mx);
      bool ii = (l >= off + 1) && (l < off + ln);
      inimg |= ii;
      rel += ii ? (l - (off + 1)) : 0;
    }
    bool text = !infull;
    bool img = inimg && (rel < 1024);
    const float* w = isq ? qn : kn;
    fx4 wv4[4];
#pragma unroll
    for (int q = 0; q < 4; ++q) wv4[q] = *(const fx4*)(w + d0 + q * 4);
    float out[16];
    if (text) {
      int dp0 = d0 ^ 64;
      float sgn = (d0 < 64) ? -1.f : 1.f;
      short8 sp0 = *(const short8*)(base + dp0);
      short8 sp1 = *(const short8*)(base + dp0 + 8);
      fx4 cv[4], sv[4], wp[4];
#pragma unroll
      for (int q = 0; q < 4; ++q) {
        cv[q] = *(const fx4*)(cos1 + (size_t)l * 128 + d0 + q * 4);
        sv[q] = *(const fx4*)(sin1 + (size_t)l * 128 + d0 + q * 4);
        wp[q] = *(const fx4*)(w + dp0 + q * 4);
      }
#pragma unroll
      for (int i = 0; i < 16; ++i) {
        float xp = bf2f((u16)(i < 8 ? sp0[i & 7] : sp1[i & 7]));
        out[i] = r * (xv[i] * wv4[i >> 2][i & 3] * cv[i >> 2][i & 3] +
                      sgn * xp * wp[i >> 2][i & 3] * sv[i >> 2][i & 3]);
      }
    } else if (img) {
      const fx4* Rv = (const fx4*)(r3 + ((size_t)rel * 64 + (d0 >> 1)) * 4);
#pragma unroll
      for (int p = 0; p < 8; ++p) {
        fx4 R = Rv[p];
        float a = xv[2 * p] * wv4[(2 * p) >> 2][(2 * p) & 3] * r;
        float c2 = xv[2 * p + 1] * wv4[(2 * p + 1) >> 2][(2 * p + 1) & 3] * r;
        out[2 * p] = a * R[0] + c2 * R[2];
        out[2 * p + 1] = a * R[1] + c2 * R[3];
      }
    } else {
#pragma unroll
      for (int i = 0; i < 16; ++i) out[i] = xv[i] * wv4[i >> 2][i & 3] * r;
    }
    float qs = isq ? (0.08838834764831845f * 1.4426950408889634f) : 1.0f;
    short8 o0, o1;
#pragma unroll
    for (int i = 0; i < 8; ++i) {
      o0[i] = (short)f2bf(out[i] * qs);
      o1[i] = (short)f2bf(out[8 + i] * qs);
    }
    u16* dst = isq ? (Q + ((size_t)(b * 16 + head) * 2048 + l) * 128 + d0)
                   : (Kb + ((size_t)(b * 8 + head) * 2048 + l) * 128 + d0);
    *(short8*)dst = o0;
    *(short8*)(dst + 8) = o1;
  } else {
    int v = bid - 8192;
    int bh = v & 15;
    int l0 = ((v >> 4) & 31) * 64, d0 = (v >> 9) * 64;
    int b = bh >> 3, kvh = bh & 7;
    int lr = tid >> 4;
    int c4 = (tid & 15) * 4;
#pragma unroll
    for (int i = 0; i < 4; ++i) {
      int li = lr + i * 16;
      *(u16x4*)&tv[li][c4] = *(const u16x4*)(
          qkv + (size_t)(b * 2048 + l0 + li) * 4096 + 3072 + kvh * 128 + d0 + c4);
    }
    __syncthreads();
#pragma unroll
    for (int i = 0; i < 4; ++i) {
      int di = lr + i * 16;
      u16x4 vv;
      vv[0] = tv[c4 + 0][di];
      vv[1] = tv[c4 + 1][di];
      vv[2] = tv[c4 + 2][di];
      vv[3] = tv[c4 + 3][di];
      *(u16x4*)(VT + ((size_t)bh * 128 + d0 + di) * 2048 + l0 + c4) = vv;
    }
  }
}

// ---------------------------------------------------------------------------
// 5) flash attention v2, BQ=256: each wave owns TWO 16-row q-tiles so every
//   K/V LDS fragment read feeds 2 MFMAs (K/V LDS traffic per q-row halves —
//   the kernel is LDS-BW-bound, FETCH dropped 4.5x in R7 with no dur change).
//   grid (8, 32) = 256 blocks = 1/CU; 8 waves; LDS 96 KB (1 block/CU).
//   Depth-1 pipelined staging, shuffle-free softmax, defer-max, XCD swizzle.
__global__ __launch_bounds__(512, 2) void k_attn(
    const u16* __restrict__ Q, const u16* __restrict__ Kb,
    const u16* __restrict__ VT, u16* __restrict__ O) {
  __shared__ u16 Ks[2][64 * 128];  // kv x dh, swizzled
  __shared__ u16 Vs[2][128 * 64];  // dh x kv, swizzled
  __shared__ u16 Ps[256 * 64];     // q x kv, swizzled (wave-private stripes)
  int tid = threadIdx.x;
  int wave = tid >> 6, lane = tid & 63, quad = lane >> 4, l16 = lane & 15;
  int lin = blockIdx.y * gridDim.x + blockIdx.x;  // 256 blocks
  int vb = (lin & 7) * 32 + (lin >> 3);           // bijective XCD chunk
  int q0 = (vb & 7) * 256;
  int bh = vb >> 3;
  int b = bh >> 4, h = bh & 15, kvh = h >> 1;
  const u16* Qb = Q + ((size_t)bh * 2048 + q0 + wave * 16) * 128;
  short8 qf[2][4];
#pragma unroll
  for (int qt = 0; qt < 2; ++qt)
#pragma unroll
    for (int ks = 0; ks < 4; ++ks)
      qf[qt][ks] =
          *(const short8*)(Qb + ((size_t)qt * 128 + l16) * 128 + ks * 32 + quad * 8);
  const u16* Kg = Kb + (size_t)(b * 8 + kvh) * 2048 * 128;
  const u16* Vg = VT + (size_t)(b * 8 + kvh) * 128 * 2048;
  float mrow[2][4], lpart[2][4];
  fx4 of[2][8] = {};
#pragma unroll
  for (int qt = 0; qt < 2; ++qt)
#pragma unroll
    for (int r = 0; r < 4; ++r) {
      mrow[qt][r] = -INFINITY;
      lpart[qt][r] = 0.f;
    }
  size_t kgo[2], vgo[2];
#pragma unroll
  for (int i = 0; i < 2; ++i) {
    int kr = i * 32 + wave * 4 + (lane >> 4);
    kgo[i] = (size_t)kr * 128 + (((lane & 15) ^ (kr & 15)) * 8);
    int vr = i * 64 + wave * 8 + (lane >> 3);
    vgo[i] = (size_t)vr * 2048 + (((lane & 7) ^ (vr & 7)) * 8);
  }

  auto STAGE = [&](int t, int buf) {
    size_t ko = (size_t)t * 8192;
    size_t vo = (size_t)t * 64;
#pragma unroll
    for (int i = 0; i < 2; ++i) {
      GLD16(Kg + ko + kgo[i], &Ks[buf][i * 4096 + wave * 512]);
      GLD16(Vg + vo + vgo[i], &Vs[buf][i * 4096 + wave * 512]);
    }
  };

  auto COMPUTE = [&](int buf) {
    fx4 sf[2][4] = {};
    __builtin_amdgcn_s_setprio(1);
#pragma unroll
    for (int ct = 0; ct < 4; ++ct) {
#pragma unroll
      for (int ks = 0; ks < 4; ++ks) {
        short8 kf = *(const short8*)&Ks[buf][(ct * 16 + l16) * 128 +
                                            (((ks * 4 + quad) ^ l16) * 8)];
        sf[0][ct] = mfma16(qf[0][ks], kf, sf[0][ct]);  // one K read,
        sf[1][ct] = mfma16(qf[1][ks], kf, sf[1][ct]);  // two MFMAs
      }
    }
    __builtin_amdgcn_s_setprio(0);
    float cmv[2][4];
    bool need = false;
#pragma unroll
    for (int qt = 0; qt < 2; ++qt)
#pragma unroll
      for (int r = 0; r < 4; ++r) {
        cmv[qt][r] = fmaxf(fmaxf(sf[qt][0][r], sf[qt][1][r]),
                           fmaxf(sf[qt][2][r], sf[qt][3][r]));
        need |= (cmv[qt][r] > mrow[qt][r] + 8.0f);
      }
    if (__any(need)) {  // T13 defer-max: P bounded by 2^8
#pragma unroll
      for (int qt = 0; qt < 2; ++qt)
#pragma unroll
        for (int r = 0; r < 4; ++r) {
          float cm = cmv[qt][r];
          cm = fmaxf(cm, __shfl_xor(cm, 1));
          cm = fmaxf(cm, __shfl_xor(cm, 2));
          cm = fmaxf(cm, __shfl_xor(cm, 4));
          cm = fmaxf(cm, __shfl_xor(cm, 8));
          float mn = fmaxf(mrow[qt][r], cm);
          float al = exp2v(mrow[qt][r] - mn);
          mrow[qt][r] = mn;
          lpart[qt][r] *= al;
#pragma unroll
          for (int c2 = 0; c2 < 8; ++c2) of[qt][c2][r] *= al;
        }
    }
    int hb = l16 >> 3;
#pragma unroll
    for (int qt = 0; qt < 2; ++qt)
#pragma unroll
      for (int r = 0; r < 4; ++r) {
        float p0 = exp2v(sf[qt][0][r] - mrow[qt][r]);
        float p1 = exp2v(sf[qt][1][r] - mrow[qt][r]);
        float p2 = exp2v(sf[qt][2][r] - mrow[qt][r]);
        float p3 = exp2v(sf[qt][3][r] - mrow[qt][r]);
        lpart[qt][r] += (p0 + p1) + (p2 + p3);
        int prow = qt * 128 + wave * 16 + quad * 4 + r;
        int pb = prow * 64, px = prow & 7, lo = l16 & 7;
        Ps[pb + ((0 + hb) ^ px) * 8 + lo] = f2bf(p0);
        Ps[pb + ((2 + hb) ^ px) * 8 + lo] = f2bf(p1);
        Ps[pb + ((4 + hb) ^ px) * 8 + lo] = f2bf(p2);
        Ps[pb + ((6 + hb) ^ px) * 8 + lo] = f2bf(p3);
      }
    __builtin_amdgcn_s_setprio(1);
#pragma unroll
    for (int ks2 = 0; ks2 < 2; ++ks2) {
      int rsl = (((ks2 * 4 + quad) ^ (l16 & 7)) * 8);
      short8 pa0 = *(const short8*)&Ps[(wave * 16 + l16) * 64 + rsl];
      short8 pa1 = *(const short8*)&Ps[(128 + wave * 16 + l16) * 64 + rsl];
#pragma unroll
      for (int c2 = 0; c2 < 8; ++c2) {
        short8 vb2 = *(const short8*)&Vs[buf][(c2 * 16 + l16) * 64 + rsl];
        of[0][c2] = mfma16(pa0, vb2, of[0][c2]);  // one V read,
        of[1][c2] = mfma16(pa1, vb2, of[1][c2]);  // two MFMAs
      }
    }
    __builtin_amdgcn_s_setprio(0);
  };

  STAGE(0, 0);
  WAIT_ALL();
  __builtin_amdgcn_s_barrier();
  int cur = 0;
  for (int t = 0; t < 31; ++t) {
    STAGE(t + 1, cur ^ 1);
    COMPUTE(cur);
    WAIT_ALL();
    __builtin_amdgcn_s_barrier();
    cur ^= 1;
  }
  COMPUTE(cur);

#pragma unroll
  for (int qt = 0; qt < 2; ++qt)
#pragma unroll
    for (int r = 0; r < 4; ++r) {
      float ls = lpart[qt][r];
      ls += __shfl_xor(ls, 1);
      ls += __shfl_xor(ls, 2);
      ls += __shfl_xor(ls, 4);
      ls += __shfl_xor(ls, 8);
      float inv = 1.0f / ls;
      int qrow = q0 + qt * 128 + wave * 16 + quad * 4 + r;
#pragma unroll
      for (int c2 = 0; c2 < 8; ++c2)
        O[((size_t)b * 2048 + qrow) * 2048 + h * 128 + c2 * 16 + l16] =
            f2bf(of[qt][c2][r] * inv);
    }
}

// ---------------------------------------------------------------------------
// 6) 128x128-tile GEMM with fused residual epilogue (WO GEMM).
__global__ __launch_bounds__(256) void k_gemm(
    const u16* __restrict__ A, const u16* __restrict__ Bt, float* __restrict__ C,
    const float* __restrict__ hid, const float* __restrict__ mod, int N, int K) {
  __shared__ u16 As[3][128 * 32];
  __shared__ u16 Bs[3][128 * 32];
  int tid = threadIdx.x;
  int wave = tid >> 6, lane = tid & 63, quad = lane >> 4, l16 = lane & 15;
  int gx = gridDim.x;
  int nwg = gx * gridDim.y;
  int lin = blockIdx.y * gx + blockIdx.x;
  int cpx = nwg >> 3;
  int swz = (lin & 7) * cpx + (lin >> 3);
  int m0 = (swz / gx) * 128, n0 = (swz % gx) * 128;
  int wm = (wave >> 1) * 64, wn = (wave & 1) * 64;
  fx4 acc[4][4] = {};
  int rowa = tid >> 2;
  int chunk = (tid & 3) ^ ((rowa >> 1) & 3);
  int cola = chunk * 8;
  const u16* Ag = A + (size_t)(m0 + rowa) * K + cola;
  const u16* Bg = Bt + (size_t)(n0 + rowa) * K + cola;
  int sl = (quad ^ ((l16 >> 1) & 3)) * 8;

  auto STAGE = [&](int k0, int buf) {
    u16* AsW = &As[buf][wave * 512];
    u16* BsW = &Bs[buf][wave * 512];
    GLD16(Ag + k0, AsW);
    GLD16(Ag + k0 + (size_t)64 * K, AsW + 2048);
    GLD16(Bg + k0, BsW);
    GLD16(Bg + k0 + (size_t)64 * K, BsW + 2048);
  };
  auto COMPUTE = [&](int buf) {
    short8 af[4], bfr[4];
#pragma unroll
    for (int i = 0; i < 4; ++i) {
      af[i] = *(const short8*)&As[buf][(wm + i * 16 + l16) * 32 + sl];
      bfr[i] = *(const short8*)&Bs[buf][(wn + i * 16 + l16) * 32 + sl];
    }
#pragma unroll
    for (int i = 0; i < 4; ++i)
#pragma unroll
      for (int j = 0; j < 4; ++j) acc[i][j] = mfma16(af[i], bfr[j], acc[i][j]);
  };

  STAGE(0, 0);
  STAGE(32, 1);
  int nk = K >> 5;  // 64
  for (int t = 0; t < nk - 2; ++t) {
    WAIT_VM4();
    __builtin_amdgcn_s_barrier();
    STAGE((t + 2) * 32, (t + 2) % 3);
    COMPUTE(t % 3);
  }
  WAIT_VM4();
  __builtin_amdgcn_s_barrier();
  COMPUTE((nk - 2) % 3);
  WAIT_VM0();
  __builtin_amdgcn_s_barrier();
  COMPUTE((nk - 1) % 3);

#pragma unroll
  for (int i = 0; i < 4; ++i) {
    int row = m0 + wm + i * 16 + quad * 4;
#pragma unroll
    for (int j = 0; j < 4; ++j) {
      int col = n0 + wn + j * 16 + l16;
      int b = row >> 11;
      float g = mod[(size_t)b * 6144 + 4096 + col];
#pragma unroll
      for (int r = 0; r < 4; ++r)
        C[(size_t)(row + r) * N + col] =
            hid[(size_t)(row + r) * N + col] + g * acc[i][j][r];
    }
  }
}

// ---------------------------------------------------------------------------
extern "C" void kernel_launch(void* const* d_in, const int* in_sizes, int n_in,
                              void* d_out, int out_size, void* d_ws, size_t ws_size,
                              hipStream_t stream) {
  (void)in_sizes; (void)n_in; (void)out_size; (void)ws_size;
  const float* hid  = (const float*)d_in[0];
  const float* temb = (const float*)d_in[1];
  const float* wln  = (const float*)d_in[2];
  const float* wmod = (const float*)d_in[3];
  const float* bmod = (const float*)d_in[4];
  const float* wq   = (const float*)d_in[5];
  const float* wk   = (const float*)d_in[6];
  const float* wv   = (const float*)d_in[7];
  const float* wo   = (const float*)d_in[8];
  const float* qn   = (const float*)d_in[9];
  const float* kn   = (const float*)d_in[10];
  const float* cos1 = (const float*)d_in[11];
  const float* sin1 = (const float*)d_in[12];
  const float* r3   = (const float*)d_in[13];
  const int*   mpos = (const int*)d_in[14];

  char* ws = (char*)d_ws;
  float* mod = (float*)(ws + 0);                 //  49,152 B
  u16* xm  = (u16*)(ws + 49152);                 //  16 MiB
  u16* wT  = (u16*)(ws + 16826368);              //  16 MiB (wq|wk|wv)^T bf16
  u16* woT = wT;                                 //  overlay after QKV GEMM
  u16* qkv = (u16*)(ws + 33603584);              //  32 MiB bf16 (B*L, 4096)
  u16* Qb  = (u16*)(ws + 67158016);              //  16 MiB (B,H,L,Dh)
  u16* Kv  = (u16*)(ws + 83935232);              //   8 MiB (B,KVH,L,Dh)
  u16* VT  = (u16*)(ws + 92323840);              //   8 MiB (B,KVH,Dh,L)
  u16* Ob  = qkv;                                //  overlay (qkv dead by then)

  k_pre<<<4192, 512, 0, stream>>>(temb, wmod, bmod, mod, wq, wk, wv, wT);
  k_xm<<<4096, 256, 0, stream>>>(hid, wln, mod, xm);
  k_gemm256<<<dim3(16, 16), 512, 0, stream>>>(xm, wT, qkv, 4096, 2048);
  k_mid<<<9216, 256, 0, stream>>>(wo, woT, qkv, qn, kn, cos1, sin1, r3, mpos,
                                  Qb, Kv, VT);
  k_attn<<<dim3(8, 32), 512, 0, stream>>>(Qb, Kv, VT, Ob);
  k_gemm<<<dim3(16, 32), 256, 0, stream>>>(Ob, woT, (float*)d_out, hid, mod,
                                           2048, 2048);
}

// Round 9
// 453.509 us; speedup vs baseline: 1.2610x; 1.0239x over previous
//
#include <hip/hip_runtime.h>
#include <hip/hip_bf16.h>
#include <stdint.h>
#include <math.h>

typedef unsigned short u16;
typedef __attribute__((ext_vector_type(8))) short short8;
typedef __attribute__((ext_vector_type(4))) float fx4;
typedef __attribute__((ext_vector_type(4))) unsigned short u16x4;

#define DEV __device__ __forceinline__

DEV u16 f2bf(float f) {  // hardware v_cvt bf16 (RTNE)
  return __builtin_bit_cast(u16, __float2bfloat16(f));
}
DEV float bf2f(u16 h) { return __builtin_bit_cast(float, ((unsigned)h) << 16); }

DEV fx4 mfma16(short8 a, short8 b, fx4 c) {
  return __builtin_amdgcn_mfma_f32_16x16x32_bf16(a, b, c, 0, 0, 0);
}

#if __has_builtin(__builtin_amdgcn_exp2f)
DEV float exp2v(float x) { return __builtin_amdgcn_exp2f(x); }
#else
DEV float exp2v(float x) { return exp2f(x); }
#endif

// async global->LDS, 16B per lane. LDS dst = wave-uniform base + lane*16.
#define GLD16(g, l)                                                            \
  __builtin_amdgcn_global_load_lds(                                            \
      (const __attribute__((address_space(1))) void*)(g),                      \
      (__attribute__((address_space(3))) void*)(l), 16, 0, 0)

#define WAIT_ALL() asm volatile("s_waitcnt vmcnt(0) lgkmcnt(0)" ::: "memory")
#define WAIT_VM4() asm volatile("s_waitcnt vmcnt(4)" ::: "memory")
#define WAIT_VM0() asm volatile("s_waitcnt vmcnt(0)" ::: "memory")

// ---------------------------------------------------------------------------
// 1) k_pre: fused [silu_mod | tconv wq | tconv wk | tconv wv]
__global__ __launch_bounds__(512) void k_pre(
    const float* __restrict__ temb, const float* __restrict__ wmod,
    const float* __restrict__ bmod, float* __restrict__ mod,
    const float* __restrict__ wq, const float* __restrict__ wk,
    const float* __restrict__ wv, u16* __restrict__ wT) {
  __shared__ float st[4096];
  __shared__ float red[8][2][64];
  __shared__ float t2[2][32][33];
  int bid = blockIdx.x;
  int tid = threadIdx.x;
  if (bid < 96) {
    for (int i = tid; i < 4096; i += 512) {
      float t = temb[i];
      st[i] = t / (1.0f + __expf(-t));
    }
    __syncthreads();
    int j = bid * 64 + (tid & 63);
    int ks = tid >> 6;
    float a0 = 0.f, a1 = 0.f;
    for (int d = ks * 256; d < ks * 256 + 256; ++d) {
      float w = wmod[(size_t)d * 6144 + j];
      a0 += st[d] * w;
      a1 += st[2048 + d] * w;
    }
    red[ks][0][tid & 63] = a0;
    red[ks][1][tid & 63] = a1;
    __syncthreads();
    if (tid < 64) {
      float s0 = 0.f, s1 = 0.f;
#pragma unroll
      for (int i = 0; i < 8; ++i) {
        s0 += red[i][0][tid];
        s1 += red[i][1][tid];
      }
      mod[j] = s0 + bmod[j];
      mod[6144 + j] = s1 + bmod[j];
    }
  } else {
    int half = tid >> 8;
    int sub = tid & 255;
    int tx = sub & 31, ty = sub >> 5;
    int tt = (bid - 96) * 2 + half;  // 0..8191
    const float* src;
    u16* dst;
    int cols, kb, nb;
    if (tt < 4096) {
      src = wq; dst = wT; cols = 2048;
      kb = (tt & 63) * 32; nb = (tt >> 6) * 32;
    } else if (tt < 6144) {
      int u = tt - 4096;
      src = wk; dst = wT + (size_t)2048 * 2048; cols = 1024;
      kb = (u & 63) * 32; nb = (u >> 6) * 32;
    } else {
      int u = tt - 6144;
      src = wv; dst = wT + (size_t)3072 * 2048; cols = 1024;
      kb = (u & 63) * 32; nb = (u >> 6) * 32;
    }
    float (*t)[33] = t2[half];
#pragma unroll
    for (int i = 0; i < 4; ++i)
      t[ty + i * 8][tx] = src[(size_t)(kb + ty + i * 8) * cols + nb + tx];
    __syncthreads();
    int nl = ty * 4 + (tx >> 3);
    int k4 = (tx & 7) * 4;
    u16x4 v;
#pragma unroll
    for (int j = 0; j < 4; ++j) v[j] = f2bf(t[k4 + j][nl]);
    *(u16x4*)(dst + (size_t)(nb + nl) * 2048 + kb + k4) = v;
  }
}

// ---------------------------------------------------------------------------
// 2) xm = bf16( rmsnorm(hidden)*w_ln * (1+scale[b]) + shift[b] )
__global__ __launch_bounds__(256) void k_xm(
    const float* __restrict__ x, const float* __restrict__ wln,
    const float* __restrict__ mod, u16* __restrict__ xm) {
  int row = blockIdx.x;
  int b = row >> 11;
  const float* xr = x + (size_t)row * 2048;
  int tid = threadIdx.x;
  float4 v0 = ((const float4*)xr)[tid];
  float4 v1 = ((const float4*)xr)[tid + 256];
  float ss = v0.x * v0.x + v0.y * v0.y + v0.z * v0.z + v0.w * v0.w +
             v1.x * v1.x + v1.y * v1.y + v1.z * v1.z + v1.w * v1.w;
  for (int m = 1; m < 64; m <<= 1) ss += __shfl_xor(ss, m);
  __shared__ float red[4];
  if ((tid & 63) == 0) red[tid >> 6] = ss;
  __syncthreads();
  ss = red[0] + red[1] + red[2] + red[3];
  float r = rsqrtf(ss * (1.0f / 2048.0f) + 1e-5f);
  const float* mb = mod + (size_t)b * 6144;
#pragma unroll
  for (int c = 0; c < 2; ++c) {
    int j0 = (tid + c * 256) * 4;
    float4 xv = c ? v1 : v0;
    float4 sh = *(const float4*)(mb + j0);
    float4 sc = *(const float4*)(mb + 2048 + j0);
    float4 wl = *(const float4*)(wln + j0);
    u16x4 o;
    o.x = f2bf(xv.x * r * wl.x * (1.f + sc.x) + sh.x);
    o.y = f2bf(xv.y * r * wl.y * (1.f + sc.y) + sh.y);
    o.z = f2bf(xv.z * r * wl.z * (1.f + sc.z) + sh.z);
    o.w = f2bf(xv.w * r * wl.w * (1.f + sc.w) + sh.w);
    *(u16x4*)(xm + (size_t)row * 2048 + j0) = o;
  }
}

// ---------------------------------------------------------------------------
// 3) 256x256-tile GEMM for the QKV projection (C = bf16).
__global__ __launch_bounds__(512, 1) void k_gemm256(
    const u16* __restrict__ A, const u16* __restrict__ Bt, u16* __restrict__ C,
    int N, int K) {
  __shared__ u16 As[3][256 * 32];
  __shared__ u16 Bs[3][256 * 32];
  int tid = threadIdx.x;
  int wave = tid >> 6, lane = tid & 63, quad = lane >> 4, l16 = lane & 15;
  int gx = gridDim.x;
  int nwg = gx * gridDim.y;
  int lin = blockIdx.y * gx + blockIdx.x;
  int cpx = nwg >> 3;
  int swz = (lin & 7) * cpx + (lin >> 3);
  int m0 = (swz / gx) * 256, n0 = (swz % gx) * 256;
  int wm = (wave >> 2) * 128, wn = (wave & 3) * 64;
  fx4 acc[8][4] = {};
  int rowa = tid >> 2;
  int chunk = (tid & 3) ^ ((rowa >> 1) & 3);
  int cola = chunk * 8;
  const u16* Ag = A + (size_t)(m0 + rowa) * K + cola;
  const u16* Bg = Bt + (size_t)(n0 + rowa) * K + cola;
  int sl = (quad ^ ((l16 >> 1) & 3)) * 8;

  auto STAGE = [&](int k0, int buf) {
    u16* AsW = &As[buf][wave * 512];
    u16* BsW = &Bs[buf][wave * 512];
    GLD16(Ag + k0, AsW);
    GLD16(Ag + k0 + (size_t)128 * K, AsW + 4096);
    GLD16(Bg + k0, BsW);
    GLD16(Bg + k0 + (size_t)128 * K, BsW + 4096);
  };
  auto COMPUTE = [&](int buf) {
    short8 af[8], bfr[4];
#pragma unroll
    for (int i = 0; i < 8; ++i)
      af[i] = *(const short8*)&As[buf][(wm + i * 16 + l16) * 32 + sl];
#pragma unroll
    for (int j = 0; j < 4; ++j)
      bfr[j] = *(const short8*)&Bs[buf][(wn + j * 16 + l16) * 32 + sl];
#pragma unroll
    for (int i = 0; i < 8; ++i)
#pragma unroll
      for (int j = 0; j < 4; ++j) acc[i][j] = mfma16(af[i], bfr[j], acc[i][j]);
  };

  STAGE(0, 0);
  STAGE(32, 1);
  for (int t = 0; t < 62; ++t) {
    WAIT_VM4();
    __builtin_amdgcn_s_barrier();
    STAGE((t + 2) * 32, (t + 2) % 3);
    COMPUTE(t % 3);
  }
  WAIT_VM4();
  __builtin_amdgcn_s_barrier();
  COMPUTE(2);
  WAIT_VM0();
  __builtin_amdgcn_s_barrier();
  COMPUTE(0);

#pragma unroll
  for (int i = 0; i < 8; ++i) {
    int row = m0 + wm + i * 16 + quad * 4;
#pragma unroll
    for (int j = 0; j < 4; ++j) {
      int col = n0 + wn + j * 16 + l16;
#pragma unroll
      for (int r = 0; r < 4; ++r)
        C[(size_t)(row + r) * N + col] = f2bf(acc[i][j][r]);
    }
  }
}

// ---------------------------------------------------------------------------
// 4) k_mid: fused [tconv wo | qknorm | vtrans], role by blockIdx.x.
__global__ __launch_bounds__(256) void k_mid(
    const float* __restrict__ wo, u16* __restrict__ woT,
    const u16* __restrict__ qkv, const float* __restrict__ qn,
    const float* __restrict__ kn, const float* __restrict__ cos1,
    const float* __restrict__ sin1, const float* __restrict__ r3,
    const int* __restrict__ mpos, u16* __restrict__ Q, u16* __restrict__ Kb,
    u16* __restrict__ VT) {
  __shared__ float tc[32][33];
  __shared__ u16 tv[64][65];
  int bid = blockIdx.x;
  int tid = threadIdx.x;
  if (bid < 4096) {
    int kb = (bid & 63) * 32, nb = (bid >> 6) * 32;
    int tx = tid & 31, ty = tid >> 5;
#pragma unroll
    for (int i = 0; i < 4; ++i)
      tc[ty + i * 8][tx] = wo[(size_t)(kb + ty + i * 8) * 2048 + nb + tx];
    __syncthreads();
    int nl = ty * 4 + (tx >> 3);
    int k4 = (tx & 7) * 4;
    u16x4 v;
#pragma unroll
    for (int j = 0; j < 4; ++j) v[j] = f2bf(tc[k4 + j][nl]);
    *(u16x4*)(woT + (size_t)(nb + nl) * 2048 + kb + k4) = v;
  } else if (bid < 8192) {
    int bx = bid - 4096;
    int b = bx >> 11, l = bx & 2047;
    int slot = tid >> 3, sub = tid & 7;
    if (slot >= 24) return;
    bool isq = slot < 16;
    int head = isq ? slot : slot - 16;
    const u16* base =
        qkv + (size_t)bx * 4096 + (isq ? slot * 128 : 2048 + head * 128);
    int d0 = sub * 16;
    short8 sx0 = *(const short8*)(base + d0);
    short8 sx1 = *(const short8*)(base + d0 + 8);
    float xv[16];
#pragma unroll
    for (int i = 0; i < 8; ++i) {
      xv[i] = bf2f((u16)sx0[i]);
      xv[8 + i] = bf2f((u16)sx1[i]);
    }
    float ss = 0.f;
#pragma unroll
    for (int i = 0; i < 16; ++i) ss += xv[i] * xv[i];
    ss += __shfl_xor(ss, 1);
    ss += __shfl_xor(ss, 2);
    ss += __shfl_xor(ss, 4);
    float r = rsqrtf(ss * (1.0f / 128.0f) + 1e-5f);
    int mp[8];
    {
      bool is64 =
          (mpos[1] == 0) & (mpos[3] == 0) & (mpos[5] == 0) & (mpos[7] == 0);
#pragma unroll
      for (int i = 0; i < 8; ++i) mp[i] = is64 ? mpos[2 * i] : mpos[i];
    }
    bool infull = false, inimg = false;
    int rel = 0;
#pragma unroll
    for (int s = 0; s < 2; ++s) {
      int off = mp[b * 4 + s * 2], ln = mp[b * 4 + s * 2 + 1];
      int mx = ln > 1 ? ln : 1;
      infull |= (l >= off) && (l < off + mx);
      bool ii = (l >= off + 1) && (l < off + ln);
      inimg |= ii;
      rel += ii ? (l - (off + 1)) : 0;
    }
    bool text = !infull;
    bool img = inimg && (rel < 1024);
    const float* w = isq ? qn : kn;
    fx4 wv4[4];
#pragma unroll
    for (int q = 0; q < 4; ++q) wv4[q] = *(const fx4*)(w + d0 + q * 4);
    float out[16];
    if (text) {
      int dp0 = d0 ^ 64;
      float sgn = (d0 < 64) ? -1.f : 1.f;
      short8 sp0 = *(const short8*)(base + dp0);
      short8 sp1 = *(const short8*)(base + dp0 + 8);
      fx4 cv[4], sv[4], wp[4];
#pragma unroll
      for (int q = 0; q < 4; ++q) {
        cv[q] = *(const fx4*)(cos1 + (size_t)l * 128 + d0 + q * 4);
        sv[q] = *(const fx4*)(sin1 + (size_t)l * 128 + d0 + q * 4);
        wp[q] = *(const fx4*)(w + dp0 + q * 4);
      }
#pragma unroll
      for (int i = 0; i < 16; ++i) {
        float xp = bf2f((u16)(i < 8 ? sp0[i & 7] : sp1[i & 7]));
        out[i] = r * (xv[i] * wv4[i >> 2][i & 3] * cv[i >> 2][i & 3] +
                      sgn * xp * wp[i >> 2][i & 3] * sv[i >> 2][i & 3]);
      }
    } else if (img) {
      const fx4* Rv = (const fx4*)(r3 + ((size_t)rel * 64 + (d0 >> 1)) * 4);
#pragma unroll
      for (int p = 0; p < 8; ++p) {
        fx4 R = Rv[p];
        float a = xv[2 * p] * wv4[(2 * p) >> 2][(2 * p) & 3] * r;
        float c2 = xv[2 * p + 1] * wv4[(2 * p + 1) >> 2][(2 * p + 1) & 3] * r;
        out[2 * p] = a * R[0] + c2 * R[2];
        out[2 * p + 1] = a * R[1] + c2 * R[3];
      }
    } else {
#pragma unroll
      for (int i = 0; i < 16; ++i) out[i] = xv[i] * wv4[i >> 2][i & 3] * r;
    }
    float qs = isq ? (0.08838834764831845f * 1.4426950408889634f) : 1.0f;
    short8 o0, o1;
#pragma unroll
    for (int i = 0; i < 8; ++i) {
      o0[i] = (short)f2bf(out[i] * qs);
      o1[i] = (short)f2bf(out[8 + i] * qs);
    }
    u16* dst = isq ? (Q + ((size_t)(b * 16 + head) * 2048 + l) * 128 + d0)
                   : (Kb + ((size_t)(b * 8 + head) * 2048 + l) * 128 + d0);
    *(short8*)dst = o0;
    *(short8*)(dst + 8) = o1;
  } else {
    int v = bid - 8192;
    int bh = v & 15;
    int l0 = ((v >> 4) & 31) * 64, d0 = (v >> 9) * 64;
    int b = bh >> 3, kvh = bh & 7;
    int lr = tid >> 4;
    int c4 = (tid & 15) * 4;
#pragma unroll
    for (int i = 0; i < 4; ++i) {
      int li = lr + i * 16;
      *(u16x4*)&tv[li][c4] = *(const u16x4*)(
          qkv + (size_t)(b * 2048 + l0 + li) * 4096 + 3072 + kvh * 128 + d0 + c4);
    }
    __syncthreads();
#pragma unroll
    for (int i = 0; i < 4; ++i) {
      int di = lr + i * 16;
      u16x4 vv;
      vv[0] = tv[c4 + 0][di];
      vv[1] = tv[c4 + 1][di];
      vv[2] = tv[c4 + 2][di];
      vv[3] = tv[c4 + 3][di];
      *(u16x4*)(VT + ((size_t)bh * 128 + d0 + di) * 2048 + l0 + c4) = vv;
    }
  }
}

// ---------------------------------------------------------------------------
// 5) flash attention v2 — R7 configuration (best measured: 97.4 µs).
//   BQ=128, 512 blocks (2 blocks/CU, 16 waves/CU: TLP hides drain stalls —
//   R8 proved occupancy > LDS-traffic here). Depth-1 pipelined staging,
//   shuffle-free softmax, defer-max, XCD swizzle (FETCH 74->16 MB).
__global__ __launch_bounds__(512, 4) void k_attn(
    const u16* __restrict__ Q, const u16* __restrict__ Kb,
    const u16* __restrict__ VT, u16* __restrict__ O) {
  __shared__ u16 Ks[2][64 * 128];
  __shared__ u16 Vs[2][128 * 64];
  __shared__ u16 Ps[128 * 64];
  int tid = threadIdx.x;
  int wave = tid >> 6, lane = tid & 63, quad = lane >> 4, l16 = lane & 15;
  int lin = blockIdx.y * gridDim.x + blockIdx.x;  // 512 blocks
  int vb = (lin & 7) * 64 + (lin >> 3);           // bijective XCD chunk
  int q0 = (vb & 15) * 128;
  int bh = vb >> 4;
  int b = bh >> 4, h = bh & 15, kvh = h >> 1;
  const u16* Qb = Q + ((size_t)bh * 2048 + q0 + wave * 16) * 128;
  short8 qf[4];
#pragma unroll
  for (int ks = 0; ks < 4; ++ks)
    qf[ks] = *(const short8*)(Qb + l16 * 128 + ks * 32 + quad * 8);
  const u16* Kg = Kb + (size_t)(b * 8 + kvh) * 2048 * 128;
  const u16* Vg = VT + (size_t)(b * 8 + kvh) * 128 * 2048;
  float mrow[4], lpart[4];
  fx4 of[8] = {};
#pragma unroll
  for (int r = 0; r < 4; ++r) {
    mrow[r] = -INFINITY;
    lpart[r] = 0.f;
  }
  size_t kgo[2], vgo[2];
#pragma unroll
  for (int i = 0; i < 2; ++i) {
    int kr = i * 32 + wave * 4 + (lane >> 4);
    kgo[i] = (size_t)kr * 128 + (((lane & 15) ^ (kr & 15)) * 8);
    int vr = i * 64 + wave * 8 + (lane >> 3);
    vgo[i] = (size_t)vr * 2048 + (((lane & 7) ^ (vr & 7)) * 8);
  }

  auto STAGE = [&](int t, int buf) {
    size_t ko = (size_t)t * 8192;
    size_t vo = (size_t)t * 64;
#pragma unroll
    for (int i = 0; i < 2; ++i) {
      GLD16(Kg + ko + kgo[i], &Ks[buf][i * 4096 + wave * 512]);
      GLD16(Vg + vo + vgo[i], &Vs[buf][i * 4096 + wave * 512]);
    }
  };

  auto COMPUTE = [&](int buf) {
    fx4 sf[4] = {};
    __builtin_amdgcn_s_setprio(1);
#pragma unroll
    for (int ct = 0; ct < 4; ++ct) {
#pragma unroll
      for (int ks = 0; ks < 4; ++ks) {
        short8 kf = *(const short8*)&Ks[buf][(ct * 16 + l16) * 128 +
                                            (((ks * 4 + quad) ^ l16) * 8)];
        sf[ct] = mfma16(qf[ks], kf, sf[ct]);
      }
    }
    __builtin_amdgcn_s_setprio(0);
    float cmv[4];
    bool need = false;
#pragma unroll
    for (int r = 0; r < 4; ++r) {
      cmv[r] = fmaxf(fmaxf(sf[0][r], sf[1][r]), fmaxf(sf[2][r], sf[3][r]));
      need |= (cmv[r] > mrow[r] + 8.0f);
    }
    if (__any(need)) {  // T13 defer-max: P bounded by 2^8
#pragma unroll
      for (int r = 0; r < 4; ++r) {
        float cm = cmv[r];
        cm = fmaxf(cm, __shfl_xor(cm, 1));
        cm = fmaxf(cm, __shfl_xor(cm, 2));
        cm = fmaxf(cm, __shfl_xor(cm, 4));
        cm = fmaxf(cm, __shfl_xor(cm, 8));
        float mn = fmaxf(mrow[r], cm);
        float al = exp2v(mrow[r] - mn);
        mrow[r] = mn;
        lpart[r] *= al;
#pragma unroll
        for (int c2 = 0; c2 < 8; ++c2) of[c2][r] *= al;
      }
    }
    int hb = l16 >> 3;
#pragma unroll
    for (int r = 0; r < 4; ++r) {
      float p0 = exp2v(sf[0][r] - mrow[r]);
      float p1 = exp2v(sf[1][r] - mrow[r]);
      float p2 = exp2v(sf[2][r] - mrow[r]);
      float p3 = exp2v(sf[3][r] - mrow[r]);
      lpart[r] += (p0 + p1) + (p2 + p3);
      int prow = wave * 16 + quad * 4 + r;
      int pb = prow * 64, px = prow & 7, lo = l16 & 7;
      Ps[pb + ((0 + hb) ^ px) * 8 + lo] = f2bf(p0);
      Ps[pb + ((2 + hb) ^ px) * 8 + lo] = f2bf(p1);
      Ps[pb + ((4 + hb) ^ px) * 8 + lo] = f2bf(p2);
      Ps[pb + ((6 + hb) ^ px) * 8 + lo] = f2bf(p3);
    }
    __builtin_amdgcn_s_setprio(1);
#pragma unroll
    for (int ks2 = 0; ks2 < 2; ++ks2) {
      int rsl = (((ks2 * 4 + quad) ^ (l16 & 7)) * 8);
      short8 pa = *(const short8*)&Ps[(wave * 16 + l16) * 64 + rsl];
#pragma unroll
      for (int c2 = 0; c2 < 8; ++c2) {
        short8 vb2 = *(const short8*)&Vs[buf][(c2 * 16 + l16) * 64 + rsl];
        of[c2] = mfma16(pa, vb2, of[c2]);
      }
    }
    __builtin_amdgcn_s_setprio(0);
  };

  STAGE(0, 0);
  WAIT_ALL();
  __builtin_amdgcn_s_barrier();
  int cur = 0;
  for (int t = 0; t < 31; ++t) {
    STAGE(t + 1, cur ^ 1);
    COMPUTE(cur);
    WAIT_ALL();
    __builtin_amdgcn_s_barrier();
    cur ^= 1;
  }
  COMPUTE(cur);

#pragma unroll
  for (int r = 0; r < 4; ++r) {
    float ls = lpart[r];
    ls += __shfl_xor(ls, 1);
    ls += __shfl_xor(ls, 2);
    ls += __shfl_xor(ls, 4);
    ls += __shfl_xor(ls, 8);
    float inv = 1.0f / ls;
    int qrow = q0 + wave * 16 + quad * 4 + r;
#pragma unroll
    for (int c2 = 0; c2 < 8; ++c2)
      O[((size_t)b * 2048 + qrow) * 2048 + h * 128 + c2 * 16 + l16] =
          f2bf(of[c2][r] * inv);
  }
}

// ---------------------------------------------------------------------------
// 6) 128x128-tile GEMM with fused residual epilogue (WO GEMM).
__global__ __launch_bounds__(256) void k_gemm(
    const u16* __restrict__ A, const u16* __restrict__ Bt, float* __restrict__ C,
    const float* __restrict__ hid, const float* __restrict__ mod, int N, int K) {
  __shared__ u16 As[3][128 * 32];
  __shared__ u16 Bs[3][128 * 32];
  int tid = threadIdx.x;
  int wave = tid >> 6, lane = tid & 63, quad = lane >> 4, l16 = lane & 15;
  int gx = gridDim.x;
  int nwg = gx * gridDim.y;
  int lin = blockIdx.y * gx + blockIdx.x;
  int cpx = nwg >> 3;
  int swz = (lin & 7) * cpx + (lin >> 3);
  int m0 = (swz / gx) * 128, n0 = (swz % gx) * 128;
  int wm = (wave >> 1) * 64, wn = (wave & 1) * 64;
  fx4 acc[4][4] = {};
  int rowa = tid >> 2;
  int chunk = (tid & 3) ^ ((rowa >> 1) & 3);
  int cola = chunk * 8;
  const u16* Ag = A + (size_t)(m0 + rowa) * K + cola;
  const u16* Bg = Bt + (size_t)(n0 + rowa) * K + cola;
  int sl = (quad ^ ((l16 >> 1) & 3)) * 8;

  auto STAGE = [&](int k0, int buf) {
    u16* AsW = &As[buf][wave * 512];
    u16* BsW = &Bs[buf][wave * 512];
    GLD16(Ag + k0, AsW);
    GLD16(Ag + k0 + (size_t)64 * K, AsW + 2048);
    GLD16(Bg + k0, BsW);
    GLD16(Bg + k0 + (size_t)64 * K, BsW + 2048);
  };
  auto COMPUTE = [&](int buf) {
    short8 af[4], bfr[4];
#pragma unroll
    for (int i = 0; i < 4; ++i) {
      af[i] = *(const short8*)&As[buf][(wm + i * 16 + l16) * 32 + sl];
      bfr[i] = *(const short8*)&Bs[buf][(wn + i * 16 + l16) * 32 + sl];
    }
#pragma unroll
    for (int i = 0; i < 4; ++i)
#pragma unroll
      for (int j = 0; j < 4; ++j) acc[i][j] = mfma16(af[i], bfr[j], acc[i][j]);
  };

  STAGE(0, 0);
  STAGE(32, 1);
  int nk = K >> 5;  // 64
  for (int t = 0; t < nk - 2; ++t) {
    WAIT_VM4();
    __builtin_amdgcn_s_barrier();
    STAGE((t + 2) * 32, (t + 2) % 3);
    COMPUTE(t % 3);
  }
  WAIT_VM4();
  __builtin_amdgcn_s_barrier();
  COMPUTE((nk - 2) % 3);
  WAIT_VM0();
  __builtin_amdgcn_s_barrier();
  COMPUTE((nk - 1) % 3);

#pragma unroll
  for (int i = 0; i < 4; ++i) {
    int row = m0 + wm + i * 16 + quad * 4;
#pragma unroll
    for (int j = 0; j < 4; ++j) {
      int col = n0 + wn + j * 16 + l16;
      int b = row >> 11;
      float g = mod[(size_t)b * 6144 + 4096 + col];
#pragma unroll
      for (int r = 0; r < 4; ++r)
        C[(size_t)(row + r) * N + col] =
            hid[(size_t)(row + r) * N + col] + g * acc[i][j][r];
    }
  }
}

// ---------------------------------------------------------------------------
extern "C" void kernel_launch(void* const* d_in, const int* in_sizes, int n_in,
                              void* d_out, int out_size, void* d_ws, size_t ws_size,
                              hipStream_t stream) {
  (void)in_sizes; (void)n_in; (void)out_size; (void)ws_size;
  const float* hid  = (const float*)d_in[0];
  const float* temb = (const float*)d_in[1];
  const float* wln  = (const float*)d_in[2];
  const float* wmod = (const float*)d_in[3];
  const float* bmod = (const float*)d_in[4];
  const float* wq   = (const float*)d_in[5];
  const float* wk   = (const float*)d_in[6];
  const float* wv   = (const float*)d_in[7];
  const float* wo   = (const float*)d_in[8];
  const float* qn   = (const float*)d_in[9];
  const float* kn   = (const float*)d_in[10];
  const float* cos1 = (const float*)d_in[11];
  const float* sin1 = (const float*)d_in[12];
  const float* r3   = (const float*)d_in[13];
  const int*   mpos = (const int*)d_in[14];

  char* ws = (char*)d_ws;
  float* mod = (float*)(ws + 0);                 //  49,152 B
  u16* xm  = (u16*)(ws + 49152);                 //  16 MiB
  u16* wT  = (u16*)(ws + 16826368);              //  16 MiB (wq|wk|wv)^T bf16
  u16* woT = wT;                                 //  overlay after QKV GEMM
  u16* qkv = (u16*)(ws + 33603584);              //  32 MiB bf16 (B*L, 4096)
  u16* Qb  = (u16*)(ws + 67158016);              //  16 MiB (B,H,L,Dh)
  u16* Kv  = (u16*)(ws + 83935232);              //   8 MiB (B,KVH,L,Dh)
  u16* VT  = (u16*)(ws + 92323840);              //   8 MiB (B,KVH,Dh,L)
  u16* Ob  = qkv;                                //  overlay (qkv dead by then)

  k_pre<<<4192, 512, 0, stream>>>(temb, wmod, bmod, mod, wq, wk, wv, wT);
  k_xm<<<4096, 256, 0, stream>>>(hid, wln, mod, xm);
  k_gemm256<<<dim3(16, 16), 512, 0, stream>>>(xm, wT, qkv, 4096, 2048);
  k_mid<<<9216, 256, 0, stream>>>(wo, woT, qkv, qn, kn, cos1, sin1, r3, mpos,
                                  Qb, Kv, VT);
  k_attn<<<dim3(16, 32), 512, 0, stream>>>(Qb, Kv, VT, Ob);
  k_gemm<<<dim3(16, 32), 256, 0, stream>>>(Ob, woT, (float*)d_out, hid, mod,
                                           2048, 2048);
}